// Round 3
// baseline (3121.404 us; speedup 1.0000x reference)
//
#include <hip/hip_runtime.h>
#include <hip/hip_bf16.h>
#include <math.h>

// ---------------- types / helpers ----------------
typedef __attribute__((ext_vector_type(8))) short bf16x8;
typedef __attribute__((ext_vector_type(4))) float f32x4;

#define DEV static __device__ __forceinline__

DEV float bf2f(__hip_bfloat16 v) { return __bfloat162float(v); }
DEV __hip_bfloat16 f2bf(float f) { return __float2bfloat16(f); }
DEV float us2f(unsigned short u) { return __uint_as_float(((unsigned int)u) << 16); }
DEV unsigned short f2us(float f) {
    __hip_bfloat16 b = __float2bfloat16(f);
    return *(unsigned short*)&b;
}

// load 8 consecutive floats from an input tensor that is either f32 or bf16
DEV void load8(const void* p, size_t off, int f32m, float* o) {
    if (f32m) {
        const float4* r = (const float4*)((const float*)p + off);
        float4 A = r[0], B = r[1];
        o[0] = A.x; o[1] = A.y; o[2] = A.z; o[3] = A.w;
        o[4] = B.x; o[5] = B.y; o[6] = B.z; o[7] = B.w;
    } else {
        const ushort4* r = (const ushort4*)((const __hip_bfloat16*)p + off);
        ushort4 A = r[0], B = r[1];
        o[0] = us2f(A.x); o[1] = us2f(A.y); o[2] = us2f(A.z); o[3] = us2f(A.w);
        o[4] = us2f(B.x); o[5] = us2f(B.y); o[6] = us2f(B.z); o[7] = us2f(B.w);
    }
}

DEV float loadElem(const void* p, size_t idx, int f32m) {
    return f32m ? ((const float*)p)[idx] : bf2f(((const __hip_bfloat16*)p)[idx]);
}

// ---------------- problem constants ----------------
// B=8 S=8192 D=512 H=8 HK=2 DH=64 M=64 DFF=2048 NCLS=2 G=4
constexpr int NTOK = 65536;   // 8*8192

// ---------------- persistent ws layout (bytes) ----------------
constexpr size_t OFF_WQPT = 0;                       // bf16 [512][512]  (Wq@Wphi)^T
constexpr size_t OFF_WKPT = OFF_WQPT + 524288ull;    // bf16 [128][512]  (Wk@Wphi)^T
constexpr size_t OFF_WVT  = OFF_WKPT + 131072ull;    // bf16 [128][512]  Wv^T
constexpr size_t OFF_WOT  = OFF_WVT  + 131072ull;    // bf16 [512][512]  Wo^T
constexpr size_t OFF_WGT  = OFF_WOT  + 524288ull;    // bf16 [2048][512] Wg^T
constexpr size_t OFF_WUT  = OFF_WGT  + 2097152ull;   // bf16 [2048][512] Wu^T
constexpr size_t OFF_WDT  = OFF_WUT  + 2097152ull;   // bf16 [512][2048] Wd^T
constexpr size_t OFF_KV   = OFF_WDT  + 2097152ull;   // f32  [8][2][64][64]
constexpr size_t OFF_Z    = OFF_KV   + 262144ull;    // f32  [8][2][64]
constexpr size_t OFF_POOL = OFF_Z    + 4096ull;      // f32  [8][512]
constexpr size_t OFF_FLAG = OFF_POOL + 16384ull;     // int  dtype flag (1 = f32 inputs)
constexpr size_t PERSIST  = OFF_FLAG + 256ull;       // 7,885,056 B
constexpr int    ZERO_FLOATS = (262144 + 4096 + 16384) / 4;  // kv+z+pooled
// per-token chunk bytes: xf 2048 + h 1024 + pq 1024 + pk 256 + v 256 + attn 1024
//                        + gbuf 4096 + tbuf 4096 = 13824
constexpr size_t PERTOK = 13824ull;

// ---------------- dtype detection ----------------
// Inspect 128 32-bit words of Wphi (N(0,1) data). If inputs are bf16-packed,
// the low 16 bits are bf16 values with |v| mostly in [1/16, 8]. If inputs are
// f32, the low 16 bits are mantissa noise (hit rate ~3%). flag=1 -> f32.
__global__ __launch_bounds__(128) void detect_kernel(
    const unsigned int* __restrict__ w, int* __restrict__ flag)
{
    __shared__ int cnt;
    if (threadIdx.x == 0) cnt = 0;
    __syncthreads();
    unsigned int v = w[threadIdx.x];
    float a = fabsf(us2f((unsigned short)(v & 0xFFFFu)));
    if (a >= 0.0625f && a <= 8.0f) atomicAdd(&cnt, 1);
    __syncthreads();
    if (threadIdx.x == 0) *flag = (cnt < 64) ? 1 : 0;
}

// ---------------- tiny init ----------------
__global__ __launch_bounds__(256) void zero_kernel(float* __restrict__ p, int n)
{
    int i = blockIdx.x * 256 + threadIdx.x;
    if (i < n) p[i] = 0.0f;
}

// ---------------- weight prep ----------------
// outT[hm][d] = sum_dh W[d][h*64+dh] * Wphi[dh][m]   (hm = h*64+m), row-major [nh*64][512]
__global__ __launch_bounds__(256) void fuse_phi_kernel(
    const void* __restrict__ W, const void* __restrict__ Wphi,
    __hip_bfloat16* __restrict__ outT, int wld, const int* __restrict__ flag)
{
    const int f = *flag;
    int o = blockIdx.x * 256 + threadIdx.x;   // o = hm*512 + d
    int hm = o >> 9, d = o & 511;
    int h = hm >> 6, m = hm & 63;
    float acc = 0.f;
    if (f) {
        const float* Wf = (const float*)W;
        const float* Pf = (const float*)Wphi;
        #pragma unroll 8
        for (int dh = 0; dh < 64; ++dh)
            acc += Wf[(size_t)d * wld + h * 64 + dh] * Pf[dh * 64 + m];
    } else {
        const __hip_bfloat16* Wb = (const __hip_bfloat16*)W;
        const __hip_bfloat16* Pb = (const __hip_bfloat16*)Wphi;
        #pragma unroll 8
        for (int dh = 0; dh < 64; ++dh)
            acc += bf2f(Wb[(size_t)d * wld + h * 64 + dh]) * bf2f(Pb[dh * 64 + m]);
    }
    outT[o] = f2bf(acc);
}

// dst[C][R] = src[R][C]^T  (src f32 or bf16; dst bf16)
__global__ __launch_bounds__(256) void transpose_kernel(
    const void* __restrict__ src, __hip_bfloat16* __restrict__ dst, int R, int C,
    const int* __restrict__ flag)
{
    const int f = *flag;
    int o = blockIdx.x * 256 + threadIdx.x;
    if (o >= R * C) return;
    int c = o / R, r = o - c * R;
    dst[o] = f2bf(loadElem(src, (size_t)r * C + c, f));
}

// ---------------- embedding gather + rmsnorm (wave per row; chunk-local) ----------------
__global__ __launch_bounds__(256) void embed_rms_kernel(
    const int* __restrict__ ids, const void* __restrict__ emb,
    const void* __restrict__ g1, float* __restrict__ xf,
    __hip_bfloat16* __restrict__ h, const int* __restrict__ flag, int write_xf)
{
    const int f = *flag;
    const int n = blockIdx.x * 4 + (threadIdx.x >> 6);   // local row in chunk
    const int lane = threadIdx.x & 63;
    const int id = ids[n];
    float x[8];
    load8(emb, (size_t)id * 512 + lane * 8, f, x);
    float ss = 0.f;
    #pragma unroll
    for (int i = 0; i < 8; ++i) ss += x[i] * x[i];
    #pragma unroll
    for (int off = 32; off; off >>= 1) ss += __shfl_xor(ss, off, 64);
    const float scale = rsqrtf(ss * (1.0f / 512.0f) + 1e-6f);

    if (write_xf) {
        float4* xo = (float4*)(xf + (size_t)n * 512 + lane * 8);
        xo[0] = make_float4(x[0], x[1], x[2], x[3]);
        xo[1] = make_float4(x[4], x[5], x[6], x[7]);
    }

    float gv[8];
    load8(g1, (size_t)lane * 8, f, gv);
    ushort4 h0, h1;
    h0.x = f2us(x[0] * scale * gv[0]); h0.y = f2us(x[1] * scale * gv[1]);
    h0.z = f2us(x[2] * scale * gv[2]); h0.w = f2us(x[3] * scale * gv[3]);
    h1.x = f2us(x[4] * scale * gv[4]); h1.y = f2us(x[5] * scale * gv[5]);
    h1.z = f2us(x[6] * scale * gv[6]); h1.w = f2us(x[7] * scale * gv[7]);
    ushort4* ho = (ushort4*)(h + (size_t)n * 512 + lane * 8);
    ho[0] = h0; ho[1] = h1;
}

// ---------------- rmsnorm from f32 residual (chunk-local) ----------------
__global__ __launch_bounds__(256) void rms2_kernel(
    const float* __restrict__ xf, const void* __restrict__ g2,
    __hip_bfloat16* __restrict__ h, const int* __restrict__ flag)
{
    const int f = *flag;
    const int n = blockIdx.x * 4 + (threadIdx.x >> 6);
    const int lane = threadIdx.x & 63;
    const float4* xr = (const float4*)(xf + (size_t)n * 512);
    float4 a = xr[lane * 2], b = xr[lane * 2 + 1];
    float x[8] = { a.x, a.y, a.z, a.w, b.x, b.y, b.z, b.w };
    float ss = 0.f;
    #pragma unroll
    for (int i = 0; i < 8; ++i) ss += x[i] * x[i];
    #pragma unroll
    for (int off = 32; off; off >>= 1) ss += __shfl_xor(ss, off, 64);
    const float scale = rsqrtf(ss * (1.0f / 512.0f) + 1e-6f);

    float gv[8];
    load8(g2, (size_t)lane * 8, f, gv);
    ushort4 h0, h1;
    h0.x = f2us(x[0] * scale * gv[0]); h0.y = f2us(x[1] * scale * gv[1]);
    h0.z = f2us(x[2] * scale * gv[2]); h0.w = f2us(x[3] * scale * gv[3]);
    h1.x = f2us(x[4] * scale * gv[4]); h1.y = f2us(x[5] * scale * gv[5]);
    h1.z = f2us(x[6] * scale * gv[6]); h1.w = f2us(x[7] * scale * gv[7]);
    ushort4* ho = (ushort4*)(h + (size_t)n * 512 + lane * 8);
    ho[0] = h0; ho[1] = h1;
}

// ---------------- MFMA GEMM: C[M,N] = A[M,K] @ Bt[N,K]^T ----------------
// 128x128 tile, BK=32, 4 waves (2x2), wave tile 64x64 = 4x4 mfma 16x16x32.
// MODE 0: C=bf16(acc)  1: C=bf16(exp(-|acc|))  2: Cf32[idx] += acc  3: C=bf16(silu(aux)*acc)
template<int MODE>
__global__ __launch_bounds__(256) void gemm128_kernel(
    const __hip_bfloat16* __restrict__ A, const __hip_bfloat16* __restrict__ Bt,
    void* __restrict__ Cout, const void* __restrict__ aux, int K, int Ncols)
{
    __shared__ __align__(16) __hip_bfloat16 As[128][40];   // +8 pad
    __shared__ __align__(16) __hip_bfloat16 Bs[128][40];

    const int tid = threadIdx.x;
    const int bm = blockIdx.x, bn = blockIdx.y;
    const int ldr = tid >> 1, ldc = (tid & 1) << 4;
    const int wave = tid >> 6, lane = tid & 63;
    const int quad = lane >> 4, lr = lane & 15;
    const int wm = (wave >> 1) << 6, wn = (wave & 1) << 6;

    const __hip_bfloat16* ga = A  + (size_t)(bm * 128 + ldr) * K + ldc;
    const __hip_bfloat16* gb = Bt + (size_t)(bn * 128 + ldr) * K + ldc;

    f32x4 acc[4][4];
    #pragma unroll
    for (int i = 0; i < 4; ++i)
        #pragma unroll
        for (int j = 0; j < 4; ++j)
            #pragma unroll
            for (int r = 0; r < 4; ++r) acc[i][j][r] = 0.0f;

    for (int k0 = 0; k0 < K; k0 += 32) {
        float4 a0 = ((const float4*)(ga + k0))[0];
        float4 a1 = ((const float4*)(ga + k0))[1];
        float4 b0 = ((const float4*)(gb + k0))[0];
        float4 b1 = ((const float4*)(gb + k0))[1];
        __syncthreads();
        *((float4*)&As[ldr][ldc])     = a0;
        *((float4*)&As[ldr][ldc + 8]) = a1;
        *((float4*)&Bs[ldr][ldc])     = b0;
        *((float4*)&Bs[ldr][ldc + 8]) = b1;
        __syncthreads();

        bf16x8 af[4], bfr[4];
        #pragma unroll
        for (int i = 0; i < 4; ++i)
            af[i] = *(const bf16x8*)&As[wm + i * 16 + lr][quad * 8];
        #pragma unroll
        for (int j = 0; j < 4; ++j)
            bfr[j] = *(const bf16x8*)&Bs[wn + j * 16 + lr][quad * 8];
        #pragma unroll
        for (int i = 0; i < 4; ++i)
            #pragma unroll
            for (int j = 0; j < 4; ++j)
                acc[i][j] = __builtin_amdgcn_mfma_f32_16x16x32_bf16(af[i], bfr[j], acc[i][j], 0, 0, 0);
    }

    // C/D layout: col = lane&15, row = quad*4 + reg  [m89/m91]
    const int col0 = bn * 128 + wn + lr;
    const int row0 = bm * 128 + wm + quad * 4;
    #pragma unroll
    for (int i = 0; i < 4; ++i)
        #pragma unroll
        for (int j = 0; j < 4; ++j) {
            const int col = col0 + j * 16;
            #pragma unroll
            for (int r = 0; r < 4; ++r) {
                const int row = row0 + i * 16 + r;
                const size_t idx = (size_t)row * Ncols + col;
                const float v = acc[i][j][r];
                if (MODE == 0) {
                    ((__hip_bfloat16*)Cout)[idx] = f2bf(v);
                } else if (MODE == 1) {
                    ((__hip_bfloat16*)Cout)[idx] = f2bf(expf(-fabsf(v)));
                } else if (MODE == 2) {
                    ((float*)Cout)[idx] += v;
                } else {
                    const float g = bf2f(((const __hip_bfloat16*)aux)[idx]);
                    const float s = g / (1.0f + expf(-g));   // silu(g)
                    ((__hip_bfloat16*)Cout)[idx] = f2bf(s * v);
                }
            }
        }
}

// ---------------- kv / z global-state reduction (chunk-local inputs) ----------------
__global__ __launch_bounds__(256) void kv_z_kernel(
    const __hip_bfloat16* __restrict__ pk, const __hip_bfloat16* __restrict__ vv,
    float* __restrict__ kv, float* __restrict__ z, int gbase, int nrows)
{
    __shared__ float pks[8][64], vs[8][64];
    const int slab = blockIdx.x, kh = blockIdx.y;
    const int b = (gbase + slab * nrows) >> 13;   // nrows | 8192 -> uniform per block
    const int tid = threadIdx.x;
    const int tm = (tid & 15) << 2, tdh = (tid >> 4) << 2;
    const int lss = tid >> 5, lmm = (tid & 31) << 1;

    float acc[4][4] = {};
    float zacc[4] = {};
    for (int sb = 0; sb < nrows; sb += 8) {
        __syncthreads();
        {
            const size_t n = (size_t)slab * nrows + sb + lss;   // local row
            const __hip_bfloat16* pr = pk + n * 128 + kh * 64 + lmm;
            const __hip_bfloat16* vr = vv + n * 128 + kh * 64 + lmm;
            pks[lss][lmm]     = bf2f(pr[0]);
            pks[lss][lmm + 1] = bf2f(pr[1]);
            vs[lss][lmm]      = bf2f(vr[0]);
            vs[lss][lmm + 1]  = bf2f(vr[1]);
        }
        __syncthreads();
        #pragma unroll
        for (int ss = 0; ss < 8; ++ss) {
            f32x4 p = *(const f32x4*)&pks[ss][tm];
            f32x4 w = *(const f32x4*)&vs[ss][tdh];
            #pragma unroll
            for (int i = 0; i < 4; ++i)
                #pragma unroll
                for (int j = 0; j < 4; ++j)
                    acc[i][j] += p[i] * w[j];
            if ((tid >> 4) == 0) {
                #pragma unroll
                for (int i = 0; i < 4; ++i) zacc[i] += p[i];
            }
        }
    }
    #pragma unroll
    for (int i = 0; i < 4; ++i)
        #pragma unroll
        for (int j = 0; j < 4; ++j)
            atomicAdd(&kv[(((size_t)b * 2 + kh) * 64 + tm + i) * 64 + tdh + j], acc[i][j]);
    if ((tid >> 4) == 0) {
        #pragma unroll
        for (int i = 0; i < 4; ++i)
            atomicAdd(&z[((size_t)b * 2 + kh) * 64 + tm + i], zacc[i]);
    }
}

// ---------------- attention mix: attn = (pq @ kv) / (pq @ z + eps) ----------------
__global__ __launch_bounds__(256) void attn_mix_kernel(
    const __hip_bfloat16* __restrict__ pq, const float* __restrict__ kv,
    const float* __restrict__ z, __hip_bfloat16* __restrict__ attn, int gbase)
{
    __shared__ float kvs[2][64][64];
    __shared__ float zs[2][64];
    const int n0 = blockIdx.x * 16;
    const int b = (gbase + n0) >> 13;
    const int tid = threadIdx.x;
    const float* kvsrc = kv + (size_t)b * 8192;
    for (int i = tid; i < 2048; i += 256)
        ((float4*)kvs)[i] = ((const float4*)kvsrc)[i];
    for (int i = tid; i < 128; i += 256)
        ((float*)zs)[i] = z[(size_t)b * 128 + i];
    __syncthreads();

    const int wave = tid >> 6, lane = tid & 63;
    for (int rr = 0; rr < 4; ++rr) {
        const int n = n0 + wave * 4 + rr;
        const __hip_bfloat16* pqr = pq + (size_t)n * 512;
        #pragma unroll
        for (int h = 0; h < 8; ++h) {
            const int kh = h >> 2;
            const float pval = bf2f(pqr[h * 64 + lane]);
            float num = 0.f, den = 0.f;
            for (int m = 0; m < 64; ++m) {
                const float p = __shfl(pval, m, 64);
                num += p * kvs[kh][m][lane];
                den += p * zs[kh][m];
            }
            attn[(size_t)n * 512 + h * 64 + lane] = f2bf(num / (den + 1e-6f));
        }
    }
}

// ---------------- mean pool accumulate ----------------
__global__ __launch_bounds__(256) void pool_kernel(
    const float* __restrict__ xf, float* __restrict__ pooled, int gbase)
{
    const int row0 = blockIdx.x * 256;
    const int b = (gbase + row0) >> 13;
    const int t = threadIdx.x;
    float a0 = 0.f, a1 = 0.f;
    const size_t base = (size_t)row0 * 512;
    for (int s = 0; s < 256; ++s) {
        a0 += xf[base + (size_t)s * 512 + t];
        a1 += xf[base + (size_t)s * 512 + t + 256];
    }
    atomicAdd(&pooled[b * 512 + t], a0);
    atomicAdd(&pooled[b * 512 + t + 256], a1);
}

// ---------------- classifier head ----------------
__global__ __launch_bounds__(256) void head_kernel(
    const float* __restrict__ pooled, const void* __restrict__ Wc,
    const void* __restrict__ bc, void* __restrict__ out, const int* __restrict__ flag)
{
    const int f = *flag;
    const int t = threadIdx.x;
    const int grp = t >> 4, ln = t & 15;
    const int b = grp >> 1, c = grp & 1;
    float p = 0.f;
    for (int d = ln; d < 512; d += 16)
        p += pooled[b * 512 + d] * loadElem(Wc, (size_t)d * 2 + c, f);
    #pragma unroll
    for (int off = 8; off; off >>= 1) p += __shfl_xor(p, off, 64);
    if (ln == 0) {
        const float val = p * (1.0f / 8192.0f) + loadElem(bc, c, f);
        if (f) ((float*)out)[b * 2 + c] = val;
        else   ((__hip_bfloat16*)out)[b * 2 + c] = f2bf(val);
    }
}

// ---------------- launch ----------------
extern "C" void kernel_launch(void* const* d_in, const int* in_sizes, int n_in,
                              void* d_out, int out_size, void* d_ws, size_t ws_size,
                              hipStream_t stream)
{
    const int* ids   = (const int*)d_in[0];
    const void* emb  = d_in[1];
    const void* Wq   = d_in[2];
    const void* Wk   = d_in[3];
    const void* Wv   = d_in[4];
    const void* Wph  = d_in[5];
    const void* Wo   = d_in[6];
    const void* g1   = d_in[7];
    const void* g2   = d_in[8];
    const void* Wg   = d_in[9];
    const void* Wu   = d_in[10];
    const void* Wd   = d_in[11];
    const void* Wc   = d_in[12];
    const void* bc   = d_in[13];

    char* ws = (char*)d_ws;
    __hip_bfloat16* WQPt  = (__hip_bfloat16*)(ws + OFF_WQPT);
    __hip_bfloat16* WKPt  = (__hip_bfloat16*)(ws + OFF_WKPT);
    __hip_bfloat16* WvT   = (__hip_bfloat16*)(ws + OFF_WVT);
    __hip_bfloat16* WoT   = (__hip_bfloat16*)(ws + OFF_WOT);
    __hip_bfloat16* WgT   = (__hip_bfloat16*)(ws + OFF_WGT);
    __hip_bfloat16* WuT   = (__hip_bfloat16*)(ws + OFF_WUT);
    __hip_bfloat16* WdT   = (__hip_bfloat16*)(ws + OFF_WDT);
    float*          kv    = (float*)(ws + OFF_KV);
    float*          z     = (float*)(ws + OFF_Z);
    float*          pooled= (float*)(ws + OFF_POOL);
    int*            flag  = (int*)(ws + OFF_FLAG);

    // ---- adaptive chunk: largest power-of-2 C in [256, 16384] that fits ws ----
    int C = 16384;
    while (C > 256 && PERSIST + PERTOK * (size_t)C > ws_size) C >>= 1;
    const int NC = NTOK / C;
    const int slabR = (C >= 512) ? 512 : C;      // kv_z rows per block

    char* cb = ws + PERSIST;
    float*          xf   = (float*)cb;                                  // f32  [C][512]
    __hip_bfloat16* h    = (__hip_bfloat16*)(cb + (size_t)C * 2048);    // bf16 [C][512]
    __hip_bfloat16* pq   = (__hip_bfloat16*)(cb + (size_t)C * 3072);    // bf16 [C][512]
    __hip_bfloat16* pkb  = (__hip_bfloat16*)(cb + (size_t)C * 4096);    // bf16 [C][128]
    __hip_bfloat16* vb   = (__hip_bfloat16*)(cb + (size_t)C * 4352);    // bf16 [C][128]
    __hip_bfloat16* attn = (__hip_bfloat16*)(cb + (size_t)C * 4608);    // bf16 [C][512]
    __hip_bfloat16* gbuf = (__hip_bfloat16*)(cb + (size_t)C * 5632);    // bf16 [C][2048]
    __hip_bfloat16* tbuf = (__hip_bfloat16*)(cb + (size_t)C * 9728);    // bf16 [C][2048]

    detect_kernel<<<1, 128, 0, stream>>>((const unsigned int*)Wph, flag);
    zero_kernel<<<(ZERO_FLOATS + 255) / 256, 256, 0, stream>>>(kv, ZERO_FLOATS);

    // weight prep
    fuse_phi_kernel<<<1024, 256, 0, stream>>>(Wq, Wph, WQPt, 512, flag);
    fuse_phi_kernel<<<256, 256, 0, stream>>>(Wk, Wph, WKPt, 128, flag);
    transpose_kernel<<<(512 * 128) / 256, 256, 0, stream>>>(Wv, WvT, 512, 128, flag);
    transpose_kernel<<<(512 * 512) / 256, 256, 0, stream>>>(Wo, WoT, 512, 512, flag);
    transpose_kernel<<<(512 * 2048) / 256, 256, 0, stream>>>(Wg, WgT, 512, 2048, flag);
    transpose_kernel<<<(512 * 2048) / 256, 256, 0, stream>>>(Wu, WuT, 512, 2048, flag);
    transpose_kernel<<<(2048 * 512) / 256, 256, 0, stream>>>(Wd, WdT, 2048, 512, flag);

    // ---- pass A: accumulate global kv / z over all token chunks ----
    for (int c = 0; c < NC; ++c) {
        const int g0 = c * C;
        embed_rms_kernel<<<C / 4, 256, 0, stream>>>(ids + g0, emb, g1, xf, h, flag, 0);
        dim3 g2d(C / 128, 1);
        gemm128_kernel<1><<<g2d, 256, 0, stream>>>(h, WKPt, pkb, nullptr, 512, 128);
        gemm128_kernel<0><<<g2d, 256, 0, stream>>>(h, WvT, vb, nullptr, 512, 128);
        kv_z_kernel<<<dim3(C / slabR, 2), 256, 0, stream>>>(pkb, vb, kv, z, g0, slabR);
    }

    // ---- pass B: per chunk -> pq, mix, +Wo, rms, SwiGLU FFN, +Wd, pool ----
    for (int c = 0; c < NC; ++c) {
        const int g0 = c * C;
        embed_rms_kernel<<<C / 4, 256, 0, stream>>>(ids + g0, emb, g1, xf, h, flag, 1);
        dim3 gq(C / 128, 4);
        gemm128_kernel<1><<<gq, 256, 0, stream>>>(h, WQPt, pq, nullptr, 512, 512);
        attn_mix_kernel<<<C / 16, 256, 0, stream>>>(pq, kv, z, attn, g0);
        gemm128_kernel<2><<<gq, 256, 0, stream>>>(attn, WoT, xf, nullptr, 512, 512);
        rms2_kernel<<<C / 4, 256, 0, stream>>>(xf, g2, h, flag);
        dim3 gg(C / 128, 16);
        gemm128_kernel<0><<<gg, 256, 0, stream>>>(h, WgT, gbuf, nullptr, 512, 2048);
        gemm128_kernel<3><<<gg, 256, 0, stream>>>(h, WuT, tbuf, gbuf, 512, 2048);
        dim3 gd(C / 128, 4);
        gemm128_kernel<2><<<gd, 256, 0, stream>>>(tbuf, WdT, xf, nullptr, 2048, 512);
        pool_kernel<<<C / 256, 256, 0, stream>>>(xf, pooled, g0);
    }

    head_kernel<<<1, 256, 0, stream>>>(pooled, Wc, bc, d_out, flag);
}

// Round 4
// 1756.811 us; speedup vs baseline: 1.7767x; 1.7767x over previous
//
#include <hip/hip_runtime.h>
#include <hip/hip_bf16.h>
#include <math.h>

// ---------------- types / helpers ----------------
typedef __attribute__((ext_vector_type(8))) short bf16x8;
typedef __attribute__((ext_vector_type(4))) float f32x4;

#define DEV static __device__ __forceinline__

DEV float bf2f(__hip_bfloat16 v) { return __bfloat162float(v); }
DEV __hip_bfloat16 f2bf(float f) { return __float2bfloat16(f); }
DEV float us2f(unsigned short u) { return __uint_as_float(((unsigned int)u) << 16); }
DEV unsigned short f2us(float f) {
    __hip_bfloat16 b = __float2bfloat16(f);
    return *(unsigned short*)&b;
}

// load 8 consecutive floats from an input tensor that is either f32 or bf16
DEV void load8(const void* p, size_t off, int f32m, float* o) {
    if (f32m) {
        const float4* r = (const float4*)((const float*)p + off);
        float4 A = r[0], B = r[1];
        o[0] = A.x; o[1] = A.y; o[2] = A.z; o[3] = A.w;
        o[4] = B.x; o[5] = B.y; o[6] = B.z; o[7] = B.w;
    } else {
        const ushort4* r = (const ushort4*)((const __hip_bfloat16*)p + off);
        ushort4 A = r[0], B = r[1];
        o[0] = us2f(A.x); o[1] = us2f(A.y); o[2] = us2f(A.z); o[3] = us2f(A.w);
        o[4] = us2f(B.x); o[5] = us2f(B.y); o[6] = us2f(B.z); o[7] = us2f(B.w);
    }
}

DEV float loadElem(const void* p, size_t idx, int f32m) {
    return f32m ? ((const float*)p)[idx] : bf2f(((const __hip_bfloat16*)p)[idx]);
}

// ---------------- problem constants ----------------
// B=8 S=8192 D=512 H=8 HK=2 DH=64 M=64 DFF=2048 NCLS=2 G=4
constexpr int NTOK = 65536;   // 8*8192

// ---------------- persistent ws layout (bytes) ----------------
constexpr size_t OFF_WQPT = 0;                       // bf16 [512][512]  (Wq@Wphi)^T
constexpr size_t OFF_WKPT = OFF_WQPT + 524288ull;    // bf16 [128][512]  (Wk@Wphi)^T
constexpr size_t OFF_WVT  = OFF_WKPT + 131072ull;    // bf16 [128][512]  Wv^T
constexpr size_t OFF_WOT  = OFF_WVT  + 131072ull;    // bf16 [512][512]  Wo^T
constexpr size_t OFF_WGT  = OFF_WOT  + 524288ull;    // bf16 [2048][512] Wg^T
constexpr size_t OFF_WUT  = OFF_WGT  + 2097152ull;   // bf16 [2048][512] Wu^T
constexpr size_t OFF_WDT  = OFF_WUT  + 2097152ull;   // bf16 [512][2048] Wd^T
constexpr size_t OFF_KV   = OFF_WDT  + 2097152ull;   // f32  [8][2][64][64]
constexpr size_t OFF_Z    = OFF_KV   + 262144ull;    // f32  [8][2][64]
constexpr size_t OFF_POOL = OFF_Z    + 4096ull;      // f32  [8][512]
constexpr size_t OFF_FLAG = OFF_POOL + 16384ull;     // int  dtype flag (1 = f32 inputs)
constexpr size_t PERSIST  = OFF_FLAG + 256ull;       // 7,885,056 B
constexpr int    ZERO_FLOATS = (262144 + 4096 + 16384) / 4;  // kv+z+pooled
// per-token chunk bytes: xf 2048 + h 1024 + pq 1024 + pk 256 + v 256 + attn 1024
//                        + gbuf 4096 + tbuf 4096 = 13824
constexpr size_t PERTOK = 13824ull;

// ---------------- dtype detection ----------------
__global__ __launch_bounds__(128) void detect_kernel(
    const unsigned int* __restrict__ w, int* __restrict__ flag)
{
    __shared__ int cnt;
    if (threadIdx.x == 0) cnt = 0;
    __syncthreads();
    unsigned int v = w[threadIdx.x];
    float a = fabsf(us2f((unsigned short)(v & 0xFFFFu)));
    if (a >= 0.0625f && a <= 8.0f) atomicAdd(&cnt, 1);
    __syncthreads();
    if (threadIdx.x == 0) *flag = (cnt < 64) ? 1 : 0;
}

// ---------------- tiny init ----------------
__global__ __launch_bounds__(256) void zero_kernel(float* __restrict__ p, int n)
{
    int i = blockIdx.x * 256 + threadIdx.x;
    if (i < n) p[i] = 0.0f;
}

// ---------------- weight prep ----------------
// outT[hm][d] = sum_dh W[d][h*64+dh] * Wphi[dh][m]   (hm = h*64+m), row-major [nh*64][512]
__global__ __launch_bounds__(256) void fuse_phi_kernel(
    const void* __restrict__ W, const void* __restrict__ Wphi,
    __hip_bfloat16* __restrict__ outT, int wld, const int* __restrict__ flag)
{
    const int f = *flag;
    int o = blockIdx.x * 256 + threadIdx.x;   // o = hm*512 + d
    int hm = o >> 9, d = o & 511;
    int h = hm >> 6, m = hm & 63;
    float acc = 0.f;
    if (f) {
        const float* Wf = (const float*)W;
        const float* Pf = (const float*)Wphi;
        #pragma unroll 8
        for (int dh = 0; dh < 64; ++dh)
            acc += Wf[(size_t)d * wld + h * 64 + dh] * Pf[dh * 64 + m];
    } else {
        const __hip_bfloat16* Wb = (const __hip_bfloat16*)W;
        const __hip_bfloat16* Pb = (const __hip_bfloat16*)Wphi;
        #pragma unroll 8
        for (int dh = 0; dh < 64; ++dh)
            acc += bf2f(Wb[(size_t)d * wld + h * 64 + dh]) * bf2f(Pb[dh * 64 + m]);
    }
    outT[o] = f2bf(acc);
}

// dst[C][R] = src[R][C]^T  (src f32 or bf16; dst bf16)
__global__ __launch_bounds__(256) void transpose_kernel(
    const void* __restrict__ src, __hip_bfloat16* __restrict__ dst, int R, int C,
    const int* __restrict__ flag)
{
    const int f = *flag;
    int o = blockIdx.x * 256 + threadIdx.x;
    if (o >= R * C) return;
    int c = o / R, r = o - c * R;
    dst[o] = f2bf(loadElem(src, (size_t)r * C + c, f));
}

// ---------------- embedding gather + rmsnorm (wave per row; chunk-local) ----------------
__global__ __launch_bounds__(256) void embed_rms_kernel(
    const int* __restrict__ ids, const void* __restrict__ emb,
    const void* __restrict__ g1, float* __restrict__ xf,
    __hip_bfloat16* __restrict__ h, const int* __restrict__ flag, int write_xf)
{
    const int f = *flag;
    const int n = blockIdx.x * 4 + (threadIdx.x >> 6);   // local row in chunk
    const int lane = threadIdx.x & 63;
    const int id = ids[n];
    float x[8];
    load8(emb, (size_t)id * 512 + lane * 8, f, x);
    float ss = 0.f;
    #pragma unroll
    for (int i = 0; i < 8; ++i) ss += x[i] * x[i];
    #pragma unroll
    for (int off = 32; off; off >>= 1) ss += __shfl_xor(ss, off, 64);
    const float scale = rsqrtf(ss * (1.0f / 512.0f) + 1e-6f);

    if (write_xf) {
        float4* xo = (float4*)(xf + (size_t)n * 512 + lane * 8);
        xo[0] = make_float4(x[0], x[1], x[2], x[3]);
        xo[1] = make_float4(x[4], x[5], x[6], x[7]);
    }

    float gv[8];
    load8(g1, (size_t)lane * 8, f, gv);
    ushort4 h0, h1;
    h0.x = f2us(x[0] * scale * gv[0]); h0.y = f2us(x[1] * scale * gv[1]);
    h0.z = f2us(x[2] * scale * gv[2]); h0.w = f2us(x[3] * scale * gv[3]);
    h1.x = f2us(x[4] * scale * gv[4]); h1.y = f2us(x[5] * scale * gv[5]);
    h1.z = f2us(x[6] * scale * gv[6]); h1.w = f2us(x[7] * scale * gv[7]);
    ushort4* ho = (ushort4*)(h + (size_t)n * 512 + lane * 8);
    ho[0] = h0; ho[1] = h1;
}

// ---------------- rmsnorm from f32 residual (chunk-local) ----------------
__global__ __launch_bounds__(256) void rms2_kernel(
    const float* __restrict__ xf, const void* __restrict__ g2,
    __hip_bfloat16* __restrict__ h, const int* __restrict__ flag)
{
    const int f = *flag;
    const int n = blockIdx.x * 4 + (threadIdx.x >> 6);
    const int lane = threadIdx.x & 63;
    const float4* xr = (const float4*)(xf + (size_t)n * 512);
    float4 a = xr[lane * 2], b = xr[lane * 2 + 1];
    float x[8] = { a.x, a.y, a.z, a.w, b.x, b.y, b.z, b.w };
    float ss = 0.f;
    #pragma unroll
    for (int i = 0; i < 8; ++i) ss += x[i] * x[i];
    #pragma unroll
    for (int off = 32; off; off >>= 1) ss += __shfl_xor(ss, off, 64);
    const float scale = rsqrtf(ss * (1.0f / 512.0f) + 1e-6f);

    float gv[8];
    load8(g2, (size_t)lane * 8, f, gv);
    ushort4 h0, h1;
    h0.x = f2us(x[0] * scale * gv[0]); h0.y = f2us(x[1] * scale * gv[1]);
    h0.z = f2us(x[2] * scale * gv[2]); h0.w = f2us(x[3] * scale * gv[3]);
    h1.x = f2us(x[4] * scale * gv[4]); h1.y = f2us(x[5] * scale * gv[5]);
    h1.z = f2us(x[6] * scale * gv[6]); h1.w = f2us(x[7] * scale * gv[7]);
    ushort4* ho = (ushort4*)(h + (size_t)n * 512 + lane * 8);
    ho[0] = h0; ho[1] = h1;
}

// ---------------- MFMA GEMM: C[M,N] = A[M,K] @ Bt[N,K]^T ----------------
// 128x128 tile, BK=32, 4 waves (2x2), wave tile 64x64 = 4x4 mfma 16x16x32.
// MODE 0: C=bf16(acc)  1: C=bf16(exp(-|acc|))  2: Cf32[idx] += acc  3: C=bf16(silu(aux)*acc)
template<int MODE>
__global__ __launch_bounds__(256) void gemm128_kernel(
    const __hip_bfloat16* __restrict__ A, const __hip_bfloat16* __restrict__ Bt,
    void* __restrict__ Cout, const void* __restrict__ aux, int K, int Ncols)
{
    __shared__ __align__(16) __hip_bfloat16 As[128][40];   // +8 pad
    __shared__ __align__(16) __hip_bfloat16 Bs[128][40];

    const int tid = threadIdx.x;
    const int bm = blockIdx.x, bn = blockIdx.y;
    const int ldr = tid >> 1, ldc = (tid & 1) << 4;
    const int wave = tid >> 6, lane = tid & 63;
    const int quad = lane >> 4, lr = lane & 15;
    const int wm = (wave >> 1) << 6, wn = (wave & 1) << 6;

    const __hip_bfloat16* ga = A  + (size_t)(bm * 128 + ldr) * K + ldc;
    const __hip_bfloat16* gb = Bt + (size_t)(bn * 128 + ldr) * K + ldc;

    f32x4 acc[4][4];
    #pragma unroll
    for (int i = 0; i < 4; ++i)
        #pragma unroll
        for (int j = 0; j < 4; ++j)
            #pragma unroll
            for (int r = 0; r < 4; ++r) acc[i][j][r] = 0.0f;

    for (int k0 = 0; k0 < K; k0 += 32) {
        float4 a0 = ((const float4*)(ga + k0))[0];
        float4 a1 = ((const float4*)(ga + k0))[1];
        float4 b0 = ((const float4*)(gb + k0))[0];
        float4 b1 = ((const float4*)(gb + k0))[1];
        __syncthreads();
        *((float4*)&As[ldr][ldc])     = a0;
        *((float4*)&As[ldr][ldc + 8]) = a1;
        *((float4*)&Bs[ldr][ldc])     = b0;
        *((float4*)&Bs[ldr][ldc + 8]) = b1;
        __syncthreads();

        bf16x8 af[4], bfr[4];
        #pragma unroll
        for (int i = 0; i < 4; ++i)
            af[i] = *(const bf16x8*)&As[wm + i * 16 + lr][quad * 8];
        #pragma unroll
        for (int j = 0; j < 4; ++j)
            bfr[j] = *(const bf16x8*)&Bs[wn + j * 16 + lr][quad * 8];
        #pragma unroll
        for (int i = 0; i < 4; ++i)
            #pragma unroll
            for (int j = 0; j < 4; ++j)
                acc[i][j] = __builtin_amdgcn_mfma_f32_16x16x32_bf16(af[i], bfr[j], acc[i][j], 0, 0, 0);
    }

    // C/D layout: col = lane&15, row = quad*4 + reg  [m89/m91]
    const int col0 = bn * 128 + wn + lr;
    const int row0 = bm * 128 + wm + quad * 4;
    #pragma unroll
    for (int i = 0; i < 4; ++i)
        #pragma unroll
        for (int j = 0; j < 4; ++j) {
            const int col = col0 + j * 16;
            #pragma unroll
            for (int r = 0; r < 4; ++r) {
                const int row = row0 + i * 16 + r;
                const size_t idx = (size_t)row * Ncols + col;
                const float v = acc[i][j][r];
                if (MODE == 0) {
                    ((__hip_bfloat16*)Cout)[idx] = f2bf(v);
                } else if (MODE == 1) {
                    ((__hip_bfloat16*)Cout)[idx] = f2bf(expf(-fabsf(v)));
                } else if (MODE == 2) {
                    ((float*)Cout)[idx] += v;
                } else {
                    const float g = bf2f(((const __hip_bfloat16*)aux)[idx]);
                    const float s = g / (1.0f + expf(-g));   // silu(g)
                    ((__hip_bfloat16*)Cout)[idx] = f2bf(s * v);
                }
            }
        }
}

// ---------------- kv / z global-state reduction (chunk-local inputs) ----------------
__global__ __launch_bounds__(256) void kv_z_kernel(
    const __hip_bfloat16* __restrict__ pk, const __hip_bfloat16* __restrict__ vv,
    float* __restrict__ kv, float* __restrict__ z, int gbase, int nrows)
{
    __shared__ float pks[8][64], vs[8][64];
    const int slab = blockIdx.x, kh = blockIdx.y;
    const int b = (gbase + slab * nrows) >> 13;   // nrows | 8192 -> uniform per block
    const int tid = threadIdx.x;
    const int tm = (tid & 15) << 2, tdh = (tid >> 4) << 2;
    const int lss = tid >> 5, lmm = (tid & 31) << 1;

    float acc[4][4] = {};
    float zacc[4] = {};
    for (int sb = 0; sb < nrows; sb += 8) {
        __syncthreads();
        {
            const size_t n = (size_t)slab * nrows + sb + lss;   // local row
            const __hip_bfloat16* pr = pk + n * 128 + kh * 64 + lmm;
            const __hip_bfloat16* vr = vv + n * 128 + kh * 64 + lmm;
            pks[lss][lmm]     = bf2f(pr[0]);
            pks[lss][lmm + 1] = bf2f(pr[1]);
            vs[lss][lmm]      = bf2f(vr[0]);
            vs[lss][lmm + 1]  = bf2f(vr[1]);
        }
        __syncthreads();
        #pragma unroll
        for (int ss = 0; ss < 8; ++ss) {
            f32x4 p = *(const f32x4*)&pks[ss][tm];
            f32x4 w = *(const f32x4*)&vs[ss][tdh];
            #pragma unroll
            for (int i = 0; i < 4; ++i)
                #pragma unroll
                for (int j = 0; j < 4; ++j)
                    acc[i][j] += p[i] * w[j];
            if ((tid >> 4) == 0) {
                #pragma unroll
                for (int i = 0; i < 4; ++i) zacc[i] += p[i];
            }
        }
    }
    #pragma unroll
    for (int i = 0; i < 4; ++i)
        #pragma unroll
        for (int j = 0; j < 4; ++j)
            atomicAdd(&kv[(((size_t)b * 2 + kh) * 64 + tm + i) * 64 + tdh + j], acc[i][j]);
    if ((tid >> 4) == 0) {
        #pragma unroll
        for (int i = 0; i < 4; ++i)
            atomicAdd(&z[((size_t)b * 2 + kh) * 64 + tm + i], zacc[i]);
    }
}

// ---------------- attention mix (MFMA): attn = (pq @ kv) / (pq @ z + eps) ----------------
// Block: 128 rows x one kv-head (kh). 4 waves: wave tile 64 rows x 2 heads.
// kv^T staged to LDS bf16 [80][72]: rows 0..63 = kv^T[dh][m], row 64 = z[m],
// rows 65..79 = 0 (den computed as 5th B-tile, col lr=0).
__global__ __launch_bounds__(256) void attn_mix_kernel(
    const __hip_bfloat16* __restrict__ pq, const float* __restrict__ kvf,
    const float* __restrict__ zf, __hip_bfloat16* __restrict__ attn, int gbase)
{
    __shared__ __align__(16) __hip_bfloat16 kvT[80][72];
    const int kh = blockIdx.y;
    const int row0b = blockIdx.x * 128;
    const int b = (gbase + row0b) >> 13;          // 128 | 8192 -> uniform per block
    const int tid = threadIdx.x;

    const float* kvsrc = kvf + ((size_t)b * 2 + kh) * 4096;
    for (int i = tid; i < 4096; i += 256) {
        const int m = i >> 6, dh = i & 63;
        kvT[dh][m] = f2bf(kvsrc[i]);
    }
    if (tid < 64) kvT[64][tid] = f2bf(zf[((size_t)b * 2 + kh) * 64 + tid]);
    for (int i = tid; i < 15 * 64; i += 256) {
        const int rr = 65 + (i >> 6), m = i & 63;
        kvT[rr][m] = f2bf(0.0f);
    }
    __syncthreads();

    const int wave = tid >> 6, lane = tid & 63;
    const int quad = lane >> 4, lr = lane & 15;
    const int wm = (wave >> 1) << 6;              // row half: 0 / 64
    const int whead = (wave & 1) << 1;            // head pair base: 0 / 2

    #pragma unroll
    for (int g2 = 0; g2 < 2; ++g2) {
        const int hh = kh * 4 + whead + g2;       // global head 0..7
        f32x4 acc[4][5];
        #pragma unroll
        for (int i = 0; i < 4; ++i)
            #pragma unroll
            for (int j = 0; j < 5; ++j)
                #pragma unroll
                for (int r = 0; r < 4; ++r) acc[i][j][r] = 0.0f;

        #pragma unroll
        for (int kk = 0; kk < 2; ++kk) {
            const int kofs = kk * 32 + quad * 8;
            bf16x8 af[4], bfr[5];
            #pragma unroll
            for (int i = 0; i < 4; ++i)
                af[i] = *(const bf16x8*)(pq + (size_t)(row0b + wm + i * 16 + lr) * 512
                                            + hh * 64 + kofs);
            #pragma unroll
            for (int j = 0; j < 5; ++j)
                bfr[j] = *(const bf16x8*)&kvT[j * 16 + lr][kofs];
            #pragma unroll
            for (int i = 0; i < 4; ++i)
                #pragma unroll
                for (int j = 0; j < 5; ++j)
                    acc[i][j] = __builtin_amdgcn_mfma_f32_16x16x32_bf16(af[i], bfr[j], acc[i][j], 0, 0, 0);
        }

        // C/D layout: col = lane&15, row = quad*4 + reg; den lives in tile j=4, col 0.
        const int colb = hh * 64;
        #pragma unroll
        for (int i = 0; i < 4; ++i) {
            const int rowb = row0b + wm + i * 16 + quad * 4;
            #pragma unroll
            for (int r = 0; r < 4; ++r) {
                const float den = __shfl(acc[i][4][r], lane & 48, 64);
                const float inv = 1.0f / (den + 1e-6f);
                const size_t base = (size_t)(rowb + r) * 512 + colb;
                #pragma unroll
                for (int j = 0; j < 4; ++j)
                    attn[base + j * 16 + lr] = f2bf(acc[i][j][r] * inv);
            }
        }
    }
}

// ---------------- mean pool accumulate ----------------
__global__ __launch_bounds__(256) void pool_kernel(
    const float* __restrict__ xf, float* __restrict__ pooled, int gbase)
{
    const int row0 = blockIdx.x * 256;
    const int b = (gbase + row0) >> 13;
    const int t = threadIdx.x;
    float a0 = 0.f, a1 = 0.f;
    const size_t base = (size_t)row0 * 512;
    for (int s = 0; s < 256; ++s) {
        a0 += xf[base + (size_t)s * 512 + t];
        a1 += xf[base + (size_t)s * 512 + t + 256];
    }
    atomicAdd(&pooled[b * 512 + t], a0);
    atomicAdd(&pooled[b * 512 + t + 256], a1);
}

// ---------------- classifier head ----------------
__global__ __launch_bounds__(256) void head_kernel(
    const float* __restrict__ pooled, const void* __restrict__ Wc,
    const void* __restrict__ bc, void* __restrict__ out, const int* __restrict__ flag)
{
    const int f = *flag;
    const int t = threadIdx.x;
    const int grp = t >> 4, ln = t & 15;
    const int b = grp >> 1, c = grp & 1;
    float p = 0.f;
    for (int d = ln; d < 512; d += 16)
        p += pooled[b * 512 + d] * loadElem(Wc, (size_t)d * 2 + c, f);
    #pragma unroll
    for (int off = 8; off; off >>= 1) p += __shfl_xor(p, off, 64);
    if (ln == 0) {
        const float val = p * (1.0f / 8192.0f) + loadElem(bc, c, f);
        if (f) ((float*)out)[b * 2 + c] = val;
        else   ((__hip_bfloat16*)out)[b * 2 + c] = f2bf(val);
    }
}

// ---------------- launch ----------------
extern "C" void kernel_launch(void* const* d_in, const int* in_sizes, int n_in,
                              void* d_out, int out_size, void* d_ws, size_t ws_size,
                              hipStream_t stream)
{
    const int* ids   = (const int*)d_in[0];
    const void* emb  = d_in[1];
    const void* Wq   = d_in[2];
    const void* Wk   = d_in[3];
    const void* Wv   = d_in[4];
    const void* Wph  = d_in[5];
    const void* Wo   = d_in[6];
    const void* g1   = d_in[7];
    const void* g2   = d_in[8];
    const void* Wg   = d_in[9];
    const void* Wu   = d_in[10];
    const void* Wd   = d_in[11];
    const void* Wc   = d_in[12];
    const void* bc   = d_in[13];

    char* ws = (char*)d_ws;
    __hip_bfloat16* WQPt  = (__hip_bfloat16*)(ws + OFF_WQPT);
    __hip_bfloat16* WKPt  = (__hip_bfloat16*)(ws + OFF_WKPT);
    __hip_bfloat16* WvT   = (__hip_bfloat16*)(ws + OFF_WVT);
    __hip_bfloat16* WoT   = (__hip_bfloat16*)(ws + OFF_WOT);
    __hip_bfloat16* WgT   = (__hip_bfloat16*)(ws + OFF_WGT);
    __hip_bfloat16* WuT   = (__hip_bfloat16*)(ws + OFF_WUT);
    __hip_bfloat16* WdT   = (__hip_bfloat16*)(ws + OFF_WDT);
    float*          kv    = (float*)(ws + OFF_KV);
    float*          z     = (float*)(ws + OFF_Z);
    float*          pooled= (float*)(ws + OFF_POOL);
    int*            flag  = (int*)(ws + OFF_FLAG);

    // ---- adaptive chunk: largest power-of-2 C in [256, 16384] that fits ws ----
    int C = 16384;
    while (C > 256 && PERSIST + PERTOK * (size_t)C > ws_size) C >>= 1;
    const int NC = NTOK / C;

    char* cb = ws + PERSIST;
    float*          xf   = (float*)cb;                                  // f32  [C][512]
    __hip_bfloat16* h    = (__hip_bfloat16*)(cb + (size_t)C * 2048);    // bf16 [C][512]
    __hip_bfloat16* pq   = (__hip_bfloat16*)(cb + (size_t)C * 3072);    // bf16 [C][512]
    __hip_bfloat16* pkb  = (__hip_bfloat16*)(cb + (size_t)C * 4096);    // bf16 [C][128]
    __hip_bfloat16* vb   = (__hip_bfloat16*)(cb + (size_t)C * 4352);    // bf16 [C][128]
    __hip_bfloat16* attn = (__hip_bfloat16*)(cb + (size_t)C * 4608);    // bf16 [C][512]
    __hip_bfloat16* gbuf = (__hip_bfloat16*)(cb + (size_t)C * 5632);    // bf16 [C][2048]
    __hip_bfloat16* tbuf = (__hip_bfloat16*)(cb + (size_t)C * 9728);    // bf16 [C][2048]

    detect_kernel<<<1, 128, 0, stream>>>((const unsigned int*)Wph, flag);
    zero_kernel<<<(ZERO_FLOATS + 255) / 256, 256, 0, stream>>>(kv, ZERO_FLOATS);

    // weight prep
    fuse_phi_kernel<<<1024, 256, 0, stream>>>(Wq, Wph, WQPt, 512, flag);
    fuse_phi_kernel<<<256, 256, 0, stream>>>(Wk, Wph, WKPt, 128, flag);
    transpose_kernel<<<(512 * 128) / 256, 256, 0, stream>>>(Wv, WvT, 512, 128, flag);
    transpose_kernel<<<(512 * 512) / 256, 256, 0, stream>>>(Wo, WoT, 512, 512, flag);
    transpose_kernel<<<(512 * 2048) / 256, 256, 0, stream>>>(Wg, WgT, 512, 2048, flag);
    transpose_kernel<<<(512 * 2048) / 256, 256, 0, stream>>>(Wu, WuT, 512, 2048, flag);
    transpose_kernel<<<(2048 * 512) / 256, 256, 0, stream>>>(Wd, WdT, 2048, 512, flag);

    // ---- pass A: accumulate global kv / z over all token chunks ----
    for (int c = 0; c < NC; ++c) {
        const int g0 = c * C;
        embed_rms_kernel<<<C / 4, 256, 0, stream>>>(ids + g0, emb, g1, xf, h, flag, 0);
        dim3 g2d(C / 128, 1);
        gemm128_kernel<1><<<g2d, 256, 0, stream>>>(h, WKPt, pkb, nullptr, 512, 128);
        gemm128_kernel<0><<<g2d, 256, 0, stream>>>(h, WvT, vb, nullptr, 512, 128);
        kv_z_kernel<<<dim3(C / 128, 2), 256, 0, stream>>>(pkb, vb, kv, z, g0, 128);
    }

    // ---- pass B: per chunk -> pq, mix, +Wo, rms, SwiGLU FFN, +Wd, pool ----
    for (int c = 0; c < NC; ++c) {
        const int g0 = c * C;
        embed_rms_kernel<<<C / 4, 256, 0, stream>>>(ids + g0, emb, g1, xf, h, flag, 1);
        dim3 gq(C / 128, 4);
        gemm128_kernel<1><<<gq, 256, 0, stream>>>(h, WQPt, pq, nullptr, 512, 512);
        attn_mix_kernel<<<dim3(C / 128, 2), 256, 0, stream>>>(pq, kv, z, attn, g0);
        gemm128_kernel<2><<<gq, 256, 0, stream>>>(attn, WoT, xf, nullptr, 512, 512);
        rms2_kernel<<<C / 4, 256, 0, stream>>>(xf, g2, h, flag);
        dim3 gg(C / 128, 16);
        gemm128_kernel<0><<<gg, 256, 0, stream>>>(h, WgT, gbuf, nullptr, 512, 2048);
        gemm128_kernel<3><<<gg, 256, 0, stream>>>(h, WuT, tbuf, gbuf, 512, 2048);
        dim3 gd(C / 128, 4);
        gemm128_kernel<2><<<gd, 256, 0, stream>>>(tbuf, WdT, xf, nullptr, 2048, 512);
        pool_kernel<<<C / 256, 256, 0, stream>>>(xf, pooled, g0);
    }

    head_kernel<<<1, 256, 0, stream>>>(pooled, Wc, bc, d_out, flag);
}

// Round 5
// 1723.065 us; speedup vs baseline: 1.8115x; 1.0196x over previous
//
#include <hip/hip_runtime.h>
#include <hip/hip_bf16.h>
#include <math.h>

// ---------------- types / helpers ----------------
typedef __attribute__((ext_vector_type(8))) short bf16x8;
typedef __attribute__((ext_vector_type(4))) float f32x4;

#define DEV static __device__ __forceinline__
#define AS1 __attribute__((address_space(1)))
#define AS3 __attribute__((address_space(3)))

DEV float bf2f(__hip_bfloat16 v) { return __bfloat162float(v); }
DEV __hip_bfloat16 f2bf(float f) { return __float2bfloat16(f); }
DEV float us2f(unsigned short u) { return __uint_as_float(((unsigned int)u) << 16); }
DEV unsigned short f2us(float f) {
    __hip_bfloat16 b = __float2bfloat16(f);
    return *(unsigned short*)&b;
}

// async global->LDS, 16 B per lane (LDS dst = wave-uniform base + lane*16)
DEV void gload_lds16(const void* g, void* l) {
    __builtin_amdgcn_global_load_lds((const AS1 unsigned int*)g,
                                     (AS3 unsigned int*)l, 16, 0, 0);
}

// load 8 consecutive floats from an input tensor that is either f32 or bf16
DEV void load8(const void* p, size_t off, int f32m, float* o) {
    if (f32m) {
        const float4* r = (const float4*)((const float*)p + off);
        float4 A = r[0], B = r[1];
        o[0] = A.x; o[1] = A.y; o[2] = A.z; o[3] = A.w;
        o[4] = B.x; o[5] = B.y; o[6] = B.z; o[7] = B.w;
    } else {
        const ushort4* r = (const ushort4*)((const __hip_bfloat16*)p + off);
        ushort4 A = r[0], B = r[1];
        o[0] = us2f(A.x); o[1] = us2f(A.y); o[2] = us2f(A.z); o[3] = us2f(A.w);
        o[4] = us2f(B.x); o[5] = us2f(B.y); o[6] = us2f(B.z); o[7] = us2f(B.w);
    }
}

DEV float loadElem(const void* p, size_t idx, int f32m) {
    return f32m ? ((const float*)p)[idx] : bf2f(((const __hip_bfloat16*)p)[idx]);
}

// ---------------- problem constants ----------------
// B=8 S=8192 D=512 H=8 HK=2 DH=64 M=64 DFF=2048 NCLS=2 G=4
constexpr int NTOK = 65536;   // 8*8192

// ---------------- persistent ws layout (bytes) ----------------
constexpr size_t OFF_WQPT = 0;                       // bf16 [512][512]  (Wq@Wphi)^T
constexpr size_t OFF_WKPT = OFF_WQPT + 524288ull;    // bf16 [128][512]  (Wk@Wphi)^T
constexpr size_t OFF_WVT  = OFF_WKPT + 131072ull;    // bf16 [128][512]  Wv^T
constexpr size_t OFF_WOT  = OFF_WVT  + 131072ull;    // bf16 [512][512]  Wo^T
constexpr size_t OFF_WGT  = OFF_WOT  + 524288ull;    // bf16 [2048][512] Wg^T
constexpr size_t OFF_WUT  = OFF_WGT  + 2097152ull;   // bf16 [2048][512] Wu^T
constexpr size_t OFF_WDT  = OFF_WUT  + 2097152ull;   // bf16 [512][2048] Wd^T
constexpr size_t OFF_KV   = OFF_WDT  + 2097152ull;   // f32  [8][2][64][64]
constexpr size_t OFF_Z    = OFF_KV   + 262144ull;    // f32  [8][2][64]
constexpr size_t OFF_POOL = OFF_Z    + 4096ull;      // f32  [8][512]
constexpr size_t OFF_FLAG = OFF_POOL + 16384ull;     // int  dtype flag (1 = f32 inputs)
constexpr size_t PERSIST  = OFF_FLAG + 256ull;       // 7,885,056 B
constexpr int    ZERO_FLOATS = (262144 + 4096 + 16384) / 4;  // kv+z+pooled
// per-token chunk bytes: xf 2048 + h 1024 + pq 1024 + pk 256 + v 256 + attn 1024
//                        + gbuf 4096 + tbuf 4096 = 13824
constexpr size_t PERTOK = 13824ull;

// ---------------- dtype detection ----------------
__global__ __launch_bounds__(128) void detect_kernel(
    const unsigned int* __restrict__ w, int* __restrict__ flag)
{
    __shared__ int cnt;
    if (threadIdx.x == 0) cnt = 0;
    __syncthreads();
    unsigned int v = w[threadIdx.x];
    float a = fabsf(us2f((unsigned short)(v & 0xFFFFu)));
    if (a >= 0.0625f && a <= 8.0f) atomicAdd(&cnt, 1);
    __syncthreads();
    if (threadIdx.x == 0) *flag = (cnt < 64) ? 1 : 0;
}

// ---------------- tiny init ----------------
__global__ __launch_bounds__(256) void zero_kernel(float* __restrict__ p, int n)
{
    int i = blockIdx.x * 256 + threadIdx.x;
    if (i < n) p[i] = 0.0f;
}

// ---------------- weight prep ----------------
// outT[hm][d] = sum_dh W[d][h*64+dh] * Wphi[dh][m]   (hm = h*64+m), row-major [nh*64][512]
__global__ __launch_bounds__(256) void fuse_phi_kernel(
    const void* __restrict__ W, const void* __restrict__ Wphi,
    __hip_bfloat16* __restrict__ outT, int wld, const int* __restrict__ flag)
{
    const int f = *flag;
    int o = blockIdx.x * 256 + threadIdx.x;   // o = hm*512 + d
    int hm = o >> 9, d = o & 511;
    int h = hm >> 6, m = hm & 63;
    float acc = 0.f;
    if (f) {
        const float* Wf = (const float*)W;
        const float* Pf = (const float*)Wphi;
        #pragma unroll 8
        for (int dh = 0; dh < 64; ++dh)
            acc += Wf[(size_t)d * wld + h * 64 + dh] * Pf[dh * 64 + m];
    } else {
        const __hip_bfloat16* Wb = (const __hip_bfloat16*)W;
        const __hip_bfloat16* Pb = (const __hip_bfloat16*)Wphi;
        #pragma unroll 8
        for (int dh = 0; dh < 64; ++dh)
            acc += bf2f(Wb[(size_t)d * wld + h * 64 + dh]) * bf2f(Pb[dh * 64 + m]);
    }
    outT[o] = f2bf(acc);
}

// dst[C][R] = src[R][C]^T  (src f32 or bf16; dst bf16)
__global__ __launch_bounds__(256) void transpose_kernel(
    const void* __restrict__ src, __hip_bfloat16* __restrict__ dst, int R, int C,
    const int* __restrict__ flag)
{
    const int f = *flag;
    int o = blockIdx.x * 256 + threadIdx.x;
    if (o >= R * C) return;
    int c = o / R, r = o - c * R;
    dst[o] = f2bf(loadElem(src, (size_t)r * C + c, f));
}

// ---------------- embedding gather + rmsnorm (wave per row; chunk-local) ----------------
__global__ __launch_bounds__(256) void embed_rms_kernel(
    const int* __restrict__ ids, const void* __restrict__ emb,
    const void* __restrict__ g1, float* __restrict__ xf,
    __hip_bfloat16* __restrict__ h, const int* __restrict__ flag, int write_xf)
{
    const int f = *flag;
    const int n = blockIdx.x * 4 + (threadIdx.x >> 6);   // local row in chunk
    const int lane = threadIdx.x & 63;
    const int id = ids[n];
    float x[8];
    load8(emb, (size_t)id * 512 + lane * 8, f, x);
    float ss = 0.f;
    #pragma unroll
    for (int i = 0; i < 8; ++i) ss += x[i] * x[i];
    #pragma unroll
    for (int off = 32; off; off >>= 1) ss += __shfl_xor(ss, off, 64);
    const float scale = rsqrtf(ss * (1.0f / 512.0f) + 1e-6f);

    if (write_xf) {
        float4* xo = (float4*)(xf + (size_t)n * 512 + lane * 8);
        xo[0] = make_float4(x[0], x[1], x[2], x[3]);
        xo[1] = make_float4(x[4], x[5], x[6], x[7]);
    }

    float gv[8];
    load8(g1, (size_t)lane * 8, f, gv);
    ushort4 h0, h1;
    h0.x = f2us(x[0] * scale * gv[0]); h0.y = f2us(x[1] * scale * gv[1]);
    h0.z = f2us(x[2] * scale * gv[2]); h0.w = f2us(x[3] * scale * gv[3]);
    h1.x = f2us(x[4] * scale * gv[4]); h1.y = f2us(x[5] * scale * gv[5]);
    h1.z = f2us(x[6] * scale * gv[6]); h1.w = f2us(x[7] * scale * gv[7]);
    ushort4* ho = (ushort4*)(h + (size_t)n * 512 + lane * 8);
    ho[0] = h0; ho[1] = h1;
}

// ---------------- rmsnorm from f32 residual (chunk-local) ----------------
__global__ __launch_bounds__(256) void rms2_kernel(
    const float* __restrict__ xf, const void* __restrict__ g2,
    __hip_bfloat16* __restrict__ h, const int* __restrict__ flag)
{
    const int f = *flag;
    const int n = blockIdx.x * 4 + (threadIdx.x >> 6);
    const int lane = threadIdx.x & 63;
    const float4* xr = (const float4*)(xf + (size_t)n * 512);
    float4 a = xr[lane * 2], b = xr[lane * 2 + 1];
    float x[8] = { a.x, a.y, a.z, a.w, b.x, b.y, b.z, b.w };
    float ss = 0.f;
    #pragma unroll
    for (int i = 0; i < 8; ++i) ss += x[i] * x[i];
    #pragma unroll
    for (int off = 32; off; off >>= 1) ss += __shfl_xor(ss, off, 64);
    const float scale = rsqrtf(ss * (1.0f / 512.0f) + 1e-6f);

    float gv[8];
    load8(g2, (size_t)lane * 8, f, gv);
    ushort4 h0, h1;
    h0.x = f2us(x[0] * scale * gv[0]); h0.y = f2us(x[1] * scale * gv[1]);
    h0.z = f2us(x[2] * scale * gv[2]); h0.w = f2us(x[3] * scale * gv[3]);
    h1.x = f2us(x[4] * scale * gv[4]); h1.y = f2us(x[5] * scale * gv[5]);
    h1.z = f2us(x[6] * scale * gv[6]); h1.w = f2us(x[7] * scale * gv[7]);
    ushort4* ho = (ushort4*)(h + (size_t)n * 512 + lane * 8);
    ho[0] = h0; ho[1] = h1;
}

// ---------------- MFMA GEMM: C[M,N] = A[M,K] @ Bt[N,K]^T ----------------
// m97 structure: 128x128 tile, BK=32, global_load_lds width-16 staging into
// flat [128][32] LDS tiles with XOR bank swizzle; 4 waves (2x2), wave tile
// 64x64 = 4x4 mfma_f32_16x16x32_bf16.
// Swizzle: 16-B chunk c of row holds global colgroup g = c ^ fr, fr=(row+(row>>2))&3.
// MODE 0: C=bf16(acc)  1: C=bf16(exp(-|acc|))  2: Cf32[idx] += acc  3: C=bf16(silu(aux)*acc)
template<int MODE>
__global__ __launch_bounds__(256) void gemm128_kernel(
    const __hip_bfloat16* __restrict__ A, const __hip_bfloat16* __restrict__ Bt,
    void* __restrict__ Cout, const void* __restrict__ aux, int K, int Ncols)
{
    __shared__ __align__(16) char As[8192];   // bf16 [128 rows][32 k], swizzled chunks
    __shared__ __align__(16) char Bs[8192];

    const int tid = threadIdx.x;
    const int bm = blockIdx.x, bn = blockIdx.y;
    const int wave = tid >> 6, lane = tid & 63;
    const int quad = lane >> 4, lr = lane & 15;
    const int wm = (wave >> 1) << 6, wn = (wave & 1) << 6;

    // ---- staging setup: wave w, instr t in {0,1}; LDS chunk idx = w*128+t*64+lane ----
    const int srow = (wave << 5) + (lane >> 2);          // row for t=0 (t=1: +16)
    const int scol = lane & 3;                           // LDS chunk within row
    const int sfr  = (srow + (srow >> 2)) & 3;           // == f(srow+16)
    const int sofs = ((scol ^ sfr) << 3);                // global col offset (elements)

    const __hip_bfloat16* ga0 = A  + (size_t)(bm * 128 + srow) * K + sofs;
    const __hip_bfloat16* gb0 = Bt + (size_t)(bn * 128 + srow) * K + sofs;
    const __hip_bfloat16* ga1 = ga0 + (size_t)16 * K;
    const __hip_bfloat16* gb1 = gb0 + (size_t)16 * K;
    char* lA0 = As + (wave << 11);                       // + lane*16 implicit
    char* lA1 = lA0 + 1024;
    char* lB0 = Bs + (wave << 11);
    char* lB1 = lB0 + 1024;

    // ---- fragment read setup ----
    const int fl  = (lr + (lr >> 2)) & 3;                // f(row) for row = wm+i*16+lr
    const int ac  = (quad ^ fl) << 4;                    // chunk byte offset in row
    const char* arp = As + ((wm + lr) << 6) + ac;        // + i*1024
    const char* brp = Bs + ((wn + lr) << 6) + ac;        // + j*1024

    f32x4 acc[4][4];
    #pragma unroll
    for (int i = 0; i < 4; ++i)
        #pragma unroll
        for (int j = 0; j < 4; ++j)
            #pragma unroll
            for (int r = 0; r < 4; ++r) acc[i][j][r] = 0.0f;

    for (int k0 = 0; k0 < K; k0 += 32) {
        __syncthreads();                                  // prior-iter reads done
        gload_lds16(ga0 + k0, lA0);
        gload_lds16(ga1 + k0, lA1);
        gload_lds16(gb0 + k0, lB0);
        gload_lds16(gb1 + k0, lB1);
        __syncthreads();                                  // drains vmcnt -> LDS ready

        bf16x8 af[4], bfr[4];
        #pragma unroll
        for (int i = 0; i < 4; ++i)
            af[i] = *(const bf16x8*)(arp + i * 1024);
        #pragma unroll
        for (int j = 0; j < 4; ++j)
            bfr[j] = *(const bf16x8*)(brp + j * 1024);
        #pragma unroll
        for (int i = 0; i < 4; ++i)
            #pragma unroll
            for (int j = 0; j < 4; ++j)
                acc[i][j] = __builtin_amdgcn_mfma_f32_16x16x32_bf16(af[i], bfr[j], acc[i][j], 0, 0, 0);
    }

    // C/D layout: col = lane&15, row = quad*4 + reg  [m89/m91]
    const int col0 = bn * 128 + wn + lr;
    const int row0 = bm * 128 + wm + quad * 4;
    #pragma unroll
    for (int i = 0; i < 4; ++i)
        #pragma unroll
        for (int j = 0; j < 4; ++j) {
            const int col = col0 + j * 16;
            #pragma unroll
            for (int r = 0; r < 4; ++r) {
                const int row = row0 + i * 16 + r;
                const size_t idx = (size_t)row * Ncols + col;
                const float v = acc[i][j][r];
                if (MODE == 0) {
                    ((__hip_bfloat16*)Cout)[idx] = f2bf(v);
                } else if (MODE == 1) {
                    ((__hip_bfloat16*)Cout)[idx] = f2bf(expf(-fabsf(v)));
                } else if (MODE == 2) {
                    ((float*)Cout)[idx] += v;
                } else {
                    const float g = bf2f(((const __hip_bfloat16*)aux)[idx]);
                    const float s = g / (1.0f + expf(-g));   // silu(g)
                    ((__hip_bfloat16*)Cout)[idx] = f2bf(s * v);
                }
            }
        }
}

// ---------------- kv / z global-state reduction (chunk-local inputs) ----------------
__global__ __launch_bounds__(256) void kv_z_kernel(
    const __hip_bfloat16* __restrict__ pk, const __hip_bfloat16* __restrict__ vv,
    float* __restrict__ kv, float* __restrict__ z, int gbase, int nrows)
{
    __shared__ float pks[8][64], vs[8][64];
    const int slab = blockIdx.x, kh = blockIdx.y;
    const int b = (gbase + slab * nrows) >> 13;   // nrows | 8192 -> uniform per block
    const int tid = threadIdx.x;
    const int tm = (tid & 15) << 2, tdh = (tid >> 4) << 2;
    const int lss = tid >> 5, lmm = (tid & 31) << 1;

    float acc[4][4] = {};
    float zacc[4] = {};
    for (int sb = 0; sb < nrows; sb += 8) {
        __syncthreads();
        {
            const size_t n = (size_t)slab * nrows + sb + lss;   // local row
            const __hip_bfloat16* pr = pk + n * 128 + kh * 64 + lmm;
            const __hip_bfloat16* vr = vv + n * 128 + kh * 64 + lmm;
            pks[lss][lmm]     = bf2f(pr[0]);
            pks[lss][lmm + 1] = bf2f(pr[1]);
            vs[lss][lmm]      = bf2f(vr[0]);
            vs[lss][lmm + 1]  = bf2f(vr[1]);
        }
        __syncthreads();
        #pragma unroll
        for (int ss = 0; ss < 8; ++ss) {
            f32x4 p = *(const f32x4*)&pks[ss][tm];
            f32x4 w = *(const f32x4*)&vs[ss][tdh];
            #pragma unroll
            for (int i = 0; i < 4; ++i)
                #pragma unroll
                for (int j = 0; j < 4; ++j)
                    acc[i][j] += p[i] * w[j];
            if ((tid >> 4) == 0) {
                #pragma unroll
                for (int i = 0; i < 4; ++i) zacc[i] += p[i];
            }
        }
    }
    #pragma unroll
    for (int i = 0; i < 4; ++i)
        #pragma unroll
        for (int j = 0; j < 4; ++j)
            atomicAdd(&kv[(((size_t)b * 2 + kh) * 64 + tm + i) * 64 + tdh + j], acc[i][j]);
    if ((tid >> 4) == 0) {
        #pragma unroll
        for (int i = 0; i < 4; ++i)
            atomicAdd(&z[((size_t)b * 2 + kh) * 64 + tm + i], zacc[i]);
    }
}

// ---------------- attention mix (MFMA): attn = (pq @ kv) / (pq @ z + eps) ----------------
// Block: 128 rows x one kv-head (kh). 4 waves: wave tile 64 rows x 2 heads.
// kv^T staged to LDS bf16 [80][72]: rows 0..63 = kv^T[dh][m], row 64 = z[m],
// rows 65..79 = 0 (den computed as 5th B-tile, col lr=0).
__global__ __launch_bounds__(256) void attn_mix_kernel(
    const __hip_bfloat16* __restrict__ pq, const float* __restrict__ kvf,
    const float* __restrict__ zf, __hip_bfloat16* __restrict__ attn, int gbase)
{
    __shared__ __align__(16) __hip_bfloat16 kvT[80][72];
    const int kh = blockIdx.y;
    const int row0b = blockIdx.x * 128;
    const int b = (gbase + row0b) >> 13;          // 128 | 8192 -> uniform per block
    const int tid = threadIdx.x;

    const float* kvsrc = kvf + ((size_t)b * 2 + kh) * 4096;
    for (int i = tid; i < 4096; i += 256) {
        const int m = i >> 6, dh = i & 63;
        kvT[dh][m] = f2bf(kvsrc[i]);
    }
    if (tid < 64) kvT[64][tid] = f2bf(zf[((size_t)b * 2 + kh) * 64 + tid]);
    for (int i = tid; i < 15 * 64; i += 256) {
        const int rr = 65 + (i >> 6), m = i & 63;
        kvT[rr][m] = f2bf(0.0f);
    }
    __syncthreads();

    const int wave = tid >> 6, lane = tid & 63;
    const int quad = lane >> 4, lr = lane & 15;
    const int wm = (wave >> 1) << 6;              // row half: 0 / 64
    const int whead = (wave & 1) << 1;            // head pair base: 0 / 2

    #pragma unroll
    for (int g2 = 0; g2 < 2; ++g2) {
        const int hh = kh * 4 + whead + g2;       // global head 0..7
        f32x4 acc[4][5];
        #pragma unroll
        for (int i = 0; i < 4; ++i)
            #pragma unroll
            for (int j = 0; j < 5; ++j)
                #pragma unroll
                for (int r = 0; r < 4; ++r) acc[i][j][r] = 0.0f;

        #pragma unroll
        for (int kk = 0; kk < 2; ++kk) {
            const int kofs = kk * 32 + quad * 8;
            bf16x8 af[4], bfr[5];
            #pragma unroll
            for (int i = 0; i < 4; ++i)
                af[i] = *(const bf16x8*)(pq + (size_t)(row0b + wm + i * 16 + lr) * 512
                                            + hh * 64 + kofs);
            #pragma unroll
            for (int j = 0; j < 5; ++j)
                bfr[j] = *(const bf16x8*)&kvT[j * 16 + lr][kofs];
            #pragma unroll
            for (int i = 0; i < 4; ++i)
                #pragma unroll
                for (int j = 0; j < 5; ++j)
                    acc[i][j] = __builtin_amdgcn_mfma_f32_16x16x32_bf16(af[i], bfr[j], acc[i][j], 0, 0, 0);
        }

        // C/D layout: col = lane&15, row = quad*4 + reg; den lives in tile j=4, col 0.
        const int colb = hh * 64;
        #pragma unroll
        for (int i = 0; i < 4; ++i) {
            const int rowb = row0b + wm + i * 16 + quad * 4;
            #pragma unroll
            for (int r = 0; r < 4; ++r) {
                const float den = __shfl(acc[i][4][r], lane & 48, 64);
                const float inv = 1.0f / (den + 1e-6f);
                const size_t base = (size_t)(rowb + r) * 512 + colb;
                #pragma unroll
                for (int j = 0; j < 4; ++j)
                    attn[base + j * 16 + lr] = f2bf(acc[i][j][r] * inv);
            }
        }
    }
}

// ---------------- mean pool accumulate ----------------
__global__ __launch_bounds__(256) void pool_kernel(
    const float* __restrict__ xf, float* __restrict__ pooled, int gbase)
{
    const int row0 = blockIdx.x * 256;
    const int b = (gbase + row0) >> 13;
    const int t = threadIdx.x;
    float a0 = 0.f, a1 = 0.f;
    const size_t base = (size_t)row0 * 512;
    for (int s = 0; s < 256; ++s) {
        a0 += xf[base + (size_t)s * 512 + t];
        a1 += xf[base + (size_t)s * 512 + t + 256];
    }
    atomicAdd(&pooled[b * 512 + t], a0);
    atomicAdd(&pooled[b * 512 + t + 256], a1);
}

// ---------------- classifier head ----------------
__global__ __launch_bounds__(256) void head_kernel(
    const float* __restrict__ pooled, const void* __restrict__ Wc,
    const void* __restrict__ bc, void* __restrict__ out, const int* __restrict__ flag)
{
    const int f = *flag;
    const int t = threadIdx.x;
    const int grp = t >> 4, ln = t & 15;
    const int b = grp >> 1, c = grp & 1;
    float p = 0.f;
    for (int d = ln; d < 512; d += 16)
        p += pooled[b * 512 + d] * loadElem(Wc, (size_t)d * 2 + c, f);
    #pragma unroll
    for (int off = 8; off; off >>= 1) p += __shfl_xor(p, off, 64);
    if (ln == 0) {
        const float val = p * (1.0f / 8192.0f) + loadElem(bc, c, f);
        if (f) ((float*)out)[b * 2 + c] = val;
        else   ((__hip_bfloat16*)out)[b * 2 + c] = f2bf(val);
    }
}

// ---------------- launch ----------------
extern "C" void kernel_launch(void* const* d_in, const int* in_sizes, int n_in,
                              void* d_out, int out_size, void* d_ws, size_t ws_size,
                              hipStream_t stream)
{
    const int* ids   = (const int*)d_in[0];
    const void* emb  = d_in[1];
    const void* Wq   = d_in[2];
    const void* Wk   = d_in[3];
    const void* Wv   = d_in[4];
    const void* Wph  = d_in[5];
    const void* Wo   = d_in[6];
    const void* g1   = d_in[7];
    const void* g2   = d_in[8];
    const void* Wg   = d_in[9];
    const void* Wu   = d_in[10];
    const void* Wd   = d_in[11];
    const void* Wc   = d_in[12];
    const void* bc   = d_in[13];

    char* ws = (char*)d_ws;
    __hip_bfloat16* WQPt  = (__hip_bfloat16*)(ws + OFF_WQPT);
    __hip_bfloat16* WKPt  = (__hip_bfloat16*)(ws + OFF_WKPT);
    __hip_bfloat16* WvT   = (__hip_bfloat16*)(ws + OFF_WVT);
    __hip_bfloat16* WoT   = (__hip_bfloat16*)(ws + OFF_WOT);
    __hip_bfloat16* WgT   = (__hip_bfloat16*)(ws + OFF_WGT);
    __hip_bfloat16* WuT   = (__hip_bfloat16*)(ws + OFF_WUT);
    __hip_bfloat16* WdT   = (__hip_bfloat16*)(ws + OFF_WDT);
    float*          kv    = (float*)(ws + OFF_KV);
    float*          z     = (float*)(ws + OFF_Z);
    float*          pooled= (float*)(ws + OFF_POOL);
    int*            flag  = (int*)(ws + OFF_FLAG);

    // ---- adaptive chunk: largest power-of-2 C in [256, 16384] that fits ws ----
    int C = 16384;
    while (C > 256 && PERSIST + PERTOK * (size_t)C > ws_size) C >>= 1;
    const int NC = NTOK / C;

    char* cb = ws + PERSIST;
    float*          xf   = (float*)cb;                                  // f32  [C][512]
    __hip_bfloat16* h    = (__hip_bfloat16*)(cb + (size_t)C * 2048);    // bf16 [C][512]
    __hip_bfloat16* pq   = (__hip_bfloat16*)(cb + (size_t)C * 3072);    // bf16 [C][512]
    __hip_bfloat16* pkb  = (__hip_bfloat16*)(cb + (size_t)C * 4096);    // bf16 [C][128]
    __hip_bfloat16* vb   = (__hip_bfloat16*)(cb + (size_t)C * 4352);    // bf16 [C][128]
    __hip_bfloat16* attn = (__hip_bfloat16*)(cb + (size_t)C * 4608);    // bf16 [C][512]
    __hip_bfloat16* gbuf = (__hip_bfloat16*)(cb + (size_t)C * 5632);    // bf16 [C][2048]
    __hip_bfloat16* tbuf = (__hip_bfloat16*)(cb + (size_t)C * 9728);    // bf16 [C][2048]

    detect_kernel<<<1, 128, 0, stream>>>((const unsigned int*)Wph, flag);
    zero_kernel<<<(ZERO_FLOATS + 255) / 256, 256, 0, stream>>>(kv, ZERO_FLOATS);

    // weight prep
    fuse_phi_kernel<<<1024, 256, 0, stream>>>(Wq, Wph, WQPt, 512, flag);
    fuse_phi_kernel<<<256, 256, 0, stream>>>(Wk, Wph, WKPt, 128, flag);
    transpose_kernel<<<(512 * 128) / 256, 256, 0, stream>>>(Wv, WvT, 512, 128, flag);
    transpose_kernel<<<(512 * 512) / 256, 256, 0, stream>>>(Wo, WoT, 512, 512, flag);
    transpose_kernel<<<(512 * 2048) / 256, 256, 0, stream>>>(Wg, WgT, 512, 2048, flag);
    transpose_kernel<<<(512 * 2048) / 256, 256, 0, stream>>>(Wu, WuT, 512, 2048, flag);
    transpose_kernel<<<(2048 * 512) / 256, 256, 0, stream>>>(Wd, WdT, 2048, 512, flag);

    // ---- pass A: accumulate global kv / z over all token chunks ----
    for (int c = 0; c < NC; ++c) {
        const int g0 = c * C;
        embed_rms_kernel<<<C / 4, 256, 0, stream>>>(ids + g0, emb, g1, xf, h, flag, 0);
        dim3 g2d(C / 128, 1);
        gemm128_kernel<1><<<g2d, 256, 0, stream>>>(h, WKPt, pkb, nullptr, 512, 128);
        gemm128_kernel<0><<<g2d, 256, 0, stream>>>(h, WvT, vb, nullptr, 512, 128);
        kv_z_kernel<<<dim3(C / 128, 2), 256, 0, stream>>>(pkb, vb, kv, z, g0, 128);
    }

    // ---- pass B: per chunk -> pq, mix, +Wo, rms, SwiGLU FFN, +Wd, pool ----
    for (int c = 0; c < NC; ++c) {
        const int g0 = c * C;
        embed_rms_kernel<<<C / 4, 256, 0, stream>>>(ids + g0, emb, g1, xf, h, flag, 1);
        dim3 gq(C / 128, 4);
        gemm128_kernel<1><<<gq, 256, 0, stream>>>(h, WQPt, pq, nullptr, 512, 512);
        attn_mix_kernel<<<dim3(C / 128, 2), 256, 0, stream>>>(pq, kv, z, attn, g0);
        gemm128_kernel<2><<<gq, 256, 0, stream>>>(attn, WoT, xf, nullptr, 512, 512);
        rms2_kernel<<<C / 4, 256, 0, stream>>>(xf, g2, h, flag);
        dim3 gg(C / 128, 16);
        gemm128_kernel<0><<<gg, 256, 0, stream>>>(h, WgT, gbuf, nullptr, 512, 2048);
        gemm128_kernel<3><<<gg, 256, 0, stream>>>(h, WuT, tbuf, gbuf, 512, 2048);
        dim3 gd(C / 128, 4);
        gemm128_kernel<2><<<gd, 256, 0, stream>>>(tbuf, WdT, xf, nullptr, 2048, 512);
        pool_kernel<<<C / 256, 256, 0, stream>>>(xf, pooled, g0);
    }

    head_kernel<<<1, 256, 0, stream>>>(pooled, Wc, bc, d_out, flag);
}

// Round 6
// 1418.591 us; speedup vs baseline: 2.2004x; 1.2146x over previous
//
#include <hip/hip_runtime.h>
#include <hip/hip_bf16.h>
#include <math.h>

// ---------------- types / helpers ----------------
typedef __attribute__((ext_vector_type(8))) short bf16x8;
typedef __attribute__((ext_vector_type(4))) float f32x4;

#define DEV static __device__ __forceinline__
#define AS1 __attribute__((address_space(1)))
#define AS3 __attribute__((address_space(3)))

DEV float bf2f(__hip_bfloat16 v) { return __bfloat162float(v); }
DEV __hip_bfloat16 f2bf(float f) { return __float2bfloat16(f); }
DEV float us2f(unsigned short u) { return __uint_as_float(((unsigned int)u) << 16); }
DEV unsigned short f2us(float f) {
    __hip_bfloat16 b = __float2bfloat16(f);
    return *(unsigned short*)&b;
}

// async global->LDS, 16 B per lane (LDS dst = wave-uniform base + lane*16)
DEV void gload_lds16(const void* g, void* l) {
    __builtin_amdgcn_global_load_lds((const AS1 unsigned int*)g,
                                     (AS3 unsigned int*)l, 16, 0, 0);
}

// load 8 consecutive floats from an input tensor that is either f32 or bf16
DEV void load8(const void* p, size_t off, int f32m, float* o) {
    if (f32m) {
        const float4* r = (const float4*)((const float*)p + off);
        float4 A = r[0], B = r[1];
        o[0] = A.x; o[1] = A.y; o[2] = A.z; o[3] = A.w;
        o[4] = B.x; o[5] = B.y; o[6] = B.z; o[7] = B.w;
    } else {
        const ushort4* r = (const ushort4*)((const __hip_bfloat16*)p + off);
        ushort4 A = r[0], B = r[1];
        o[0] = us2f(A.x); o[1] = us2f(A.y); o[2] = us2f(A.z); o[3] = us2f(A.w);
        o[4] = us2f(B.x); o[5] = us2f(B.y); o[6] = us2f(B.z); o[7] = us2f(B.w);
    }
}

DEV float loadElem(const void* p, size_t idx, int f32m) {
    return f32m ? ((const float*)p)[idx] : bf2f(((const __hip_bfloat16*)p)[idx]);
}

// ---------------- problem constants ----------------
// B=8 S=8192 D=512 H=8 HK=2 DH=64 M=64 DFF=2048 NCLS=2 G=4
constexpr int NTOK = 65536;   // 8*8192

// ---------------- persistent ws layout (bytes) ----------------
constexpr size_t OFF_WQPT = 0;                       // bf16 [512][512]  (Wq@Wphi)^T
constexpr size_t OFF_WKPT = OFF_WQPT + 524288ull;    // bf16 [128][512]  (Wk@Wphi)^T
constexpr size_t OFF_WVT  = OFF_WKPT + 131072ull;    // bf16 [128][512]  Wv^T  (contiguous after WKPT!)
constexpr size_t OFF_WOT  = OFF_WVT  + 131072ull;    // bf16 [512][512]  Wo^T
constexpr size_t OFF_WGT  = OFF_WOT  + 524288ull;    // bf16 [2048][512] Wg^T
constexpr size_t OFF_WUT  = OFF_WGT  + 2097152ull;   // bf16 [2048][512] Wu^T
constexpr size_t OFF_WDT  = OFF_WUT  + 2097152ull;   // bf16 [512][2048] Wd^T
constexpr size_t OFF_KV   = OFF_WDT  + 2097152ull;   // f32  [8][2][64][64]
constexpr size_t OFF_Z    = OFF_KV   + 262144ull;    // f32  [8][2][64]
constexpr size_t OFF_POOL = OFF_Z    + 4096ull;      // f32  [8][512]
constexpr size_t OFF_FLAG = OFF_POOL + 16384ull;     // int  dtype flag (1 = f32 inputs)
constexpr size_t PERSIST  = OFF_FLAG + 256ull;       // 7,885,056 B
constexpr int    ZERO_FLOATS = (262144 + 4096 + 16384) / 4;  // kv+z+pooled
// per-token chunk bytes: xf 2048 + h 1024 + pq 1024 + pkv 512 + attn 1024 + tbuf 4096 = 9728
constexpr size_t PERTOK = 9728ull;

// ---------------- dtype detection ----------------
__global__ __launch_bounds__(128) void detect_kernel(
    const unsigned int* __restrict__ w, int* __restrict__ flag)
{
    __shared__ int cnt;
    if (threadIdx.x == 0) cnt = 0;
    __syncthreads();
    unsigned int v = w[threadIdx.x];
    float a = fabsf(us2f((unsigned short)(v & 0xFFFFu)));
    if (a >= 0.0625f && a <= 8.0f) atomicAdd(&cnt, 1);
    __syncthreads();
    if (threadIdx.x == 0) *flag = (cnt < 64) ? 1 : 0;
}

// ---------------- tiny init ----------------
__global__ __launch_bounds__(256) void zero_kernel(float* __restrict__ p, int n)
{
    int i = blockIdx.x * 256 + threadIdx.x;
    if (i < n) p[i] = 0.0f;
}

// ---------------- weight prep ----------------
// outT[hm][d] = sum_dh W[d][h*64+dh] * Wphi[dh][m]   (hm = h*64+m), row-major [nh*64][512]
__global__ __launch_bounds__(256) void fuse_phi_kernel(
    const void* __restrict__ W, const void* __restrict__ Wphi,
    __hip_bfloat16* __restrict__ outT, int wld, const int* __restrict__ flag)
{
    const int f = *flag;
    int o = blockIdx.x * 256 + threadIdx.x;   // o = hm*512 + d
    int hm = o >> 9, d = o & 511;
    int h = hm >> 6, m = hm & 63;
    float acc = 0.f;
    if (f) {
        const float* Wf = (const float*)W;
        const float* Pf = (const float*)Wphi;
        #pragma unroll 8
        for (int dh = 0; dh < 64; ++dh)
            acc += Wf[(size_t)d * wld + h * 64 + dh] * Pf[dh * 64 + m];
    } else {
        const __hip_bfloat16* Wb = (const __hip_bfloat16*)W;
        const __hip_bfloat16* Pb = (const __hip_bfloat16*)Wphi;
        #pragma unroll 8
        for (int dh = 0; dh < 64; ++dh)
            acc += bf2f(Wb[(size_t)d * wld + h * 64 + dh]) * bf2f(Pb[dh * 64 + m]);
    }
    outT[o] = f2bf(acc);
}

// dst[C][R] = src[R][C]^T  (src f32 or bf16; dst bf16)
__global__ __launch_bounds__(256) void transpose_kernel(
    const void* __restrict__ src, __hip_bfloat16* __restrict__ dst, int R, int C,
    const int* __restrict__ flag)
{
    const int f = *flag;
    int o = blockIdx.x * 256 + threadIdx.x;
    if (o >= R * C) return;
    int c = o / R, r = o - c * R;
    dst[o] = f2bf(loadElem(src, (size_t)r * C + c, f));
}

// ---------------- embedding gather + rmsnorm (wave per row; chunk-local) ----------------
__global__ __launch_bounds__(256) void embed_rms_kernel(
    const int* __restrict__ ids, const void* __restrict__ emb,
    const void* __restrict__ g1, float* __restrict__ xf,
    __hip_bfloat16* __restrict__ h, const int* __restrict__ flag, int write_xf)
{
    const int f = *flag;
    const int n = blockIdx.x * 4 + (threadIdx.x >> 6);   // local row in chunk
    const int lane = threadIdx.x & 63;
    const int id = ids[n];
    float x[8];
    load8(emb, (size_t)id * 512 + lane * 8, f, x);
    float ss = 0.f;
    #pragma unroll
    for (int i = 0; i < 8; ++i) ss += x[i] * x[i];
    #pragma unroll
    for (int off = 32; off; off >>= 1) ss += __shfl_xor(ss, off, 64);
    const float scale = rsqrtf(ss * (1.0f / 512.0f) + 1e-6f);

    if (write_xf) {
        float4* xo = (float4*)(xf + (size_t)n * 512 + lane * 8);
        xo[0] = make_float4(x[0], x[1], x[2], x[3]);
        xo[1] = make_float4(x[4], x[5], x[6], x[7]);
    }

    float gv[8];
    load8(g1, (size_t)lane * 8, f, gv);
    ushort4 h0, h1;
    h0.x = f2us(x[0] * scale * gv[0]); h0.y = f2us(x[1] * scale * gv[1]);
    h0.z = f2us(x[2] * scale * gv[2]); h0.w = f2us(x[3] * scale * gv[3]);
    h1.x = f2us(x[4] * scale * gv[4]); h1.y = f2us(x[5] * scale * gv[5]);
    h1.z = f2us(x[6] * scale * gv[6]); h1.w = f2us(x[7] * scale * gv[7]);
    ushort4* ho = (ushort4*)(h + (size_t)n * 512 + lane * 8);
    ho[0] = h0; ho[1] = h1;
}

// ---------------- rmsnorm from f32 residual (chunk-local) ----------------
__global__ __launch_bounds__(256) void rms2_kernel(
    const float* __restrict__ xf, const void* __restrict__ g2,
    __hip_bfloat16* __restrict__ h, const int* __restrict__ flag)
{
    const int f = *flag;
    const int n = blockIdx.x * 4 + (threadIdx.x >> 6);
    const int lane = threadIdx.x & 63;
    const float4* xr = (const float4*)(xf + (size_t)n * 512);
    float4 a = xr[lane * 2], b = xr[lane * 2 + 1];
    float x[8] = { a.x, a.y, a.z, a.w, b.x, b.y, b.z, b.w };
    float ss = 0.f;
    #pragma unroll
    for (int i = 0; i < 8; ++i) ss += x[i] * x[i];
    #pragma unroll
    for (int off = 32; off; off >>= 1) ss += __shfl_xor(ss, off, 64);
    const float scale = rsqrtf(ss * (1.0f / 512.0f) + 1e-6f);

    float gv[8];
    load8(g2, (size_t)lane * 8, f, gv);
    ushort4 h0, h1;
    h0.x = f2us(x[0] * scale * gv[0]); h0.y = f2us(x[1] * scale * gv[1]);
    h0.z = f2us(x[2] * scale * gv[2]); h0.w = f2us(x[3] * scale * gv[3]);
    h1.x = f2us(x[4] * scale * gv[4]); h1.y = f2us(x[5] * scale * gv[5]);
    h1.z = f2us(x[6] * scale * gv[6]); h1.w = f2us(x[7] * scale * gv[7]);
    ushort4* ho = (ushort4*)(h + (size_t)n * 512 + lane * 8);
    ho[0] = h0; ho[1] = h1;
}

// ---------------- MFMA GEMM: C[M,N] = A[M,K] @ Bt[N,K]^T ----------------
// m97 structure: 128x128 tile, BK=32, global_load_lds width-16 staging into
// flat [128][32] LDS tiles with XOR bank swizzle; 4 waves (2x2), wave tile
// 64x64 = 4x4 mfma_f32_16x16x32_bf16.
// MODE 0: C=bf16(acc)  1: C=bf16(exp(-|acc|))  2: Cf32[idx] += acc
// MODE 4: C=bf16(col<128 ? exp(-|acc|) : acc)   (combined pk|v epilogue)
template<int MODE>
__global__ __launch_bounds__(256) void gemm128_kernel(
    const __hip_bfloat16* __restrict__ A, const __hip_bfloat16* __restrict__ Bt,
    void* __restrict__ Cout, int K, int Ncols)
{
    __shared__ __align__(16) char As[8192];   // bf16 [128 rows][32 k], swizzled chunks
    __shared__ __align__(16) char Bs[8192];

    const int tid = threadIdx.x;
    const int bm = blockIdx.x, bn = blockIdx.y;
    const int wave = tid >> 6, lane = tid & 63;
    const int quad = lane >> 4, lr = lane & 15;
    const int wm = (wave >> 1) << 6, wn = (wave & 1) << 6;

    // staging: wave w, instr t in {0,1}; LDS chunk idx = w*128 + t*64 + lane
    const int srow = (wave << 5) + (lane >> 2);          // row for t=0 (t=1: +16)
    const int scol = lane & 3;
    const int sfr  = (srow + (srow >> 2)) & 3;           // == f(srow+16)
    const int sofs = ((scol ^ sfr) << 3);                // swizzled global col (elements)

    const __hip_bfloat16* ga0 = A  + (size_t)(bm * 128 + srow) * K + sofs;
    const __hip_bfloat16* gb0 = Bt + (size_t)(bn * 128 + srow) * K + sofs;
    const __hip_bfloat16* ga1 = ga0 + (size_t)16 * K;
    const __hip_bfloat16* gb1 = gb0 + (size_t)16 * K;
    char* lA0 = As + (wave << 11);
    char* lA1 = lA0 + 1024;
    char* lB0 = Bs + (wave << 11);
    char* lB1 = lB0 + 1024;

    // fragment reads
    const int fl  = (lr + (lr >> 2)) & 3;
    const int ac  = (quad ^ fl) << 4;
    const char* arp = As + ((wm + lr) << 6) + ac;
    const char* brp = Bs + ((wn + lr) << 6) + ac;

    f32x4 acc[4][4];
    #pragma unroll
    for (int i = 0; i < 4; ++i)
        #pragma unroll
        for (int j = 0; j < 4; ++j)
            #pragma unroll
            for (int r = 0; r < 4; ++r) acc[i][j][r] = 0.0f;

    for (int k0 = 0; k0 < K; k0 += 32) {
        __syncthreads();
        gload_lds16(ga0 + k0, lA0);
        gload_lds16(ga1 + k0, lA1);
        gload_lds16(gb0 + k0, lB0);
        gload_lds16(gb1 + k0, lB1);
        __syncthreads();

        bf16x8 af[4], bfr[4];
        #pragma unroll
        for (int i = 0; i < 4; ++i)
            af[i] = *(const bf16x8*)(arp + i * 1024);
        #pragma unroll
        for (int j = 0; j < 4; ++j)
            bfr[j] = *(const bf16x8*)(brp + j * 1024);
        #pragma unroll
        for (int i = 0; i < 4; ++i)
            #pragma unroll
            for (int j = 0; j < 4; ++j)
                acc[i][j] = __builtin_amdgcn_mfma_f32_16x16x32_bf16(af[i], bfr[j], acc[i][j], 0, 0, 0);
    }

    // C/D layout: col = lane&15, row = quad*4 + reg  [m89/m91]
    const int col0 = bn * 128 + wn + lr;
    const int row0 = bm * 128 + wm + quad * 4;
    #pragma unroll
    for (int i = 0; i < 4; ++i)
        #pragma unroll
        for (int j = 0; j < 4; ++j) {
            const int col = col0 + j * 16;
            #pragma unroll
            for (int r = 0; r < 4; ++r) {
                const int row = row0 + i * 16 + r;
                const size_t idx = (size_t)row * Ncols + col;
                const float v = acc[i][j][r];
                if (MODE == 0) {
                    ((__hip_bfloat16*)Cout)[idx] = f2bf(v);
                } else if (MODE == 1) {
                    ((__hip_bfloat16*)Cout)[idx] = f2bf(expf(-fabsf(v)));
                } else if (MODE == 2) {
                    ((float*)Cout)[idx] += v;
                } else {   // MODE 4
                    ((__hip_bfloat16*)Cout)[idx] =
                        f2bf(col < 128 ? expf(-fabsf(v)) : v);
                }
            }
        }
}

// ---------------- fused SwiGLU up-GEMM: t = silu(A@Wg^T) * (A@Wu^T) ----------------
// Same m97 tile structure; A-tile staged once, both B-tiles staged; 32 MFMA/wave/iter.
__global__ __launch_bounds__(256, 2) void gemm_ffn_kernel(
    const __hip_bfloat16* __restrict__ A, const __hip_bfloat16* __restrict__ Bg,
    const __hip_bfloat16* __restrict__ Bu, __hip_bfloat16* __restrict__ Cout,
    int K, int Ncols)
{
    __shared__ __align__(16) char As[8192];
    __shared__ __align__(16) char Gs[8192];
    __shared__ __align__(16) char Us[8192];

    const int tid = threadIdx.x;
    const int bm = blockIdx.x, bn = blockIdx.y;
    const int wave = tid >> 6, lane = tid & 63;
    const int quad = lane >> 4, lr = lane & 15;
    const int wm = (wave >> 1) << 6, wn = (wave & 1) << 6;

    const int srow = (wave << 5) + (lane >> 2);
    const int scol = lane & 3;
    const int sfr  = (srow + (srow >> 2)) & 3;
    const int sofs = ((scol ^ sfr) << 3);

    const __hip_bfloat16* ga0 = A  + (size_t)(bm * 128 + srow) * K + sofs;
    const __hip_bfloat16* gg0 = Bg + (size_t)(bn * 128 + srow) * K + sofs;
    const __hip_bfloat16* gu0 = Bu + (size_t)(bn * 128 + srow) * K + sofs;
    const __hip_bfloat16* ga1 = ga0 + (size_t)16 * K;
    const __hip_bfloat16* gg1 = gg0 + (size_t)16 * K;
    const __hip_bfloat16* gu1 = gu0 + (size_t)16 * K;
    char* lA0 = As + (wave << 11);
    char* lG0 = Gs + (wave << 11);
    char* lU0 = Us + (wave << 11);

    const int fl  = (lr + (lr >> 2)) & 3;
    const int ac  = (quad ^ fl) << 4;
    const char* arp = As + ((wm + lr) << 6) + ac;
    const char* grp = Gs + ((wn + lr) << 6) + ac;
    const char* urp = Us + ((wn + lr) << 6) + ac;

    f32x4 accG[4][4], accU[4][4];
    #pragma unroll
    for (int i = 0; i < 4; ++i)
        #pragma unroll
        for (int j = 0; j < 4; ++j)
            #pragma unroll
            for (int r = 0; r < 4; ++r) { accG[i][j][r] = 0.0f; accU[i][j][r] = 0.0f; }

    for (int k0 = 0; k0 < K; k0 += 32) {
        __syncthreads();
        gload_lds16(ga0 + k0, lA0);
        gload_lds16(ga1 + k0, lA0 + 1024);
        gload_lds16(gg0 + k0, lG0);
        gload_lds16(gg1 + k0, lG0 + 1024);
        gload_lds16(gu0 + k0, lU0);
        gload_lds16(gu1 + k0, lU0 + 1024);
        __syncthreads();

        bf16x8 af[4], bgf[4], buf_[4];
        #pragma unroll
        for (int i = 0; i < 4; ++i)
            af[i] = *(const bf16x8*)(arp + i * 1024);
        #pragma unroll
        for (int j = 0; j < 4; ++j) {
            bgf[j]  = *(const bf16x8*)(grp + j * 1024);
            buf_[j] = *(const bf16x8*)(urp + j * 1024);
        }
        #pragma unroll
        for (int i = 0; i < 4; ++i)
            #pragma unroll
            for (int j = 0; j < 4; ++j) {
                accG[i][j] = __builtin_amdgcn_mfma_f32_16x16x32_bf16(af[i], bgf[j],  accG[i][j], 0, 0, 0);
                accU[i][j] = __builtin_amdgcn_mfma_f32_16x16x32_bf16(af[i], buf_[j], accU[i][j], 0, 0, 0);
            }
    }

    const int col0 = bn * 128 + wn + lr;
    const int row0 = bm * 128 + wm + quad * 4;
    #pragma unroll
    for (int i = 0; i < 4; ++i)
        #pragma unroll
        for (int j = 0; j < 4; ++j) {
            const int col = col0 + j * 16;
            #pragma unroll
            for (int r = 0; r < 4; ++r) {
                const int row = row0 + i * 16 + r;
                const float g = accG[i][j][r];
                const float s = g / (1.0f + expf(-g));   // silu(g), f32 acc直接
                Cout[(size_t)row * Ncols + col] = f2bf(s * accU[i][j][r]);
            }
        }
}

// ---------------- kv / z global-state reduction (pkv [C][256] input) ----------------
__global__ __launch_bounds__(256) void kv_z_kernel(
    const __hip_bfloat16* __restrict__ pkv,
    float* __restrict__ kv, float* __restrict__ z, int gbase, int nrows)
{
    __shared__ float pks[8][64], vs[8][64];
    const int slab = blockIdx.x, kh = blockIdx.y;
    const int b = (gbase + slab * nrows) >> 13;   // nrows | 8192 -> uniform per block
    const int tid = threadIdx.x;
    const int tm = (tid & 15) << 2, tdh = (tid >> 4) << 2;
    const int lss = tid >> 5, lmm = (tid & 31) << 1;

    float acc[4][4] = {};
    float zacc[4] = {};
    for (int sb = 0; sb < nrows; sb += 8) {
        __syncthreads();
        {
            const size_t n = (size_t)slab * nrows + sb + lss;   // local row
            const __hip_bfloat16* pr = pkv + n * 256 + kh * 64 + lmm;        // pk cols 0..127
            const __hip_bfloat16* vr = pkv + n * 256 + 128 + kh * 64 + lmm;  // v  cols 128..255
            pks[lss][lmm]     = bf2f(pr[0]);
            pks[lss][lmm + 1] = bf2f(pr[1]);
            vs[lss][lmm]      = bf2f(vr[0]);
            vs[lss][lmm + 1]  = bf2f(vr[1]);
        }
        __syncthreads();
        #pragma unroll
        for (int ss = 0; ss < 8; ++ss) {
            f32x4 p = *(const f32x4*)&pks[ss][tm];
            f32x4 w = *(const f32x4*)&vs[ss][tdh];
            #pragma unroll
            for (int i = 0; i < 4; ++i)
                #pragma unroll
                for (int j = 0; j < 4; ++j)
                    acc[i][j] += p[i] * w[j];
            if ((tid >> 4) == 0) {
                #pragma unroll
                for (int i = 0; i < 4; ++i) zacc[i] += p[i];
            }
        }
    }
    #pragma unroll
    for (int i = 0; i < 4; ++i)
        #pragma unroll
        for (int j = 0; j < 4; ++j)
            atomicAdd(&kv[(((size_t)b * 2 + kh) * 64 + tm + i) * 64 + tdh + j], acc[i][j]);
    if ((tid >> 4) == 0) {
        #pragma unroll
        for (int i = 0; i < 4; ++i)
            atomicAdd(&z[((size_t)b * 2 + kh) * 64 + tm + i], zacc[i]);
    }
}

// ---------------- attention mix (MFMA): attn = (pq @ kv) / (pq @ z + eps) ----------------
__global__ __launch_bounds__(256) void attn_mix_kernel(
    const __hip_bfloat16* __restrict__ pq, const float* __restrict__ kvf,
    const float* __restrict__ zf, __hip_bfloat16* __restrict__ attn, int gbase)
{
    __shared__ __align__(16) __hip_bfloat16 kvT[80][72];
    const int kh = blockIdx.y;
    const int row0b = blockIdx.x * 128;
    const int b = (gbase + row0b) >> 13;
    const int tid = threadIdx.x;

    const float* kvsrc = kvf + ((size_t)b * 2 + kh) * 4096;
    for (int i = tid; i < 4096; i += 256) {
        const int m = i >> 6, dh = i & 63;
        kvT[dh][m] = f2bf(kvsrc[i]);
    }
    if (tid < 64) kvT[64][tid] = f2bf(zf[((size_t)b * 2 + kh) * 64 + tid]);
    for (int i = tid; i < 15 * 64; i += 256) {
        const int rr = 65 + (i >> 6), m = i & 63;
        kvT[rr][m] = f2bf(0.0f);
    }
    __syncthreads();

    const int wave = tid >> 6, lane = tid & 63;
    const int quad = lane >> 4, lr = lane & 15;
    const int wm = (wave >> 1) << 6;
    const int whead = (wave & 1) << 1;

    #pragma unroll
    for (int g2 = 0; g2 < 2; ++g2) {
        const int hh = kh * 4 + whead + g2;
        f32x4 acc[4][5];
        #pragma unroll
        for (int i = 0; i < 4; ++i)
            #pragma unroll
            for (int j = 0; j < 5; ++j)
                #pragma unroll
                for (int r = 0; r < 4; ++r) acc[i][j][r] = 0.0f;

        #pragma unroll
        for (int kk = 0; kk < 2; ++kk) {
            const int kofs = kk * 32 + quad * 8;
            bf16x8 af[4], bfr[5];
            #pragma unroll
            for (int i = 0; i < 4; ++i)
                af[i] = *(const bf16x8*)(pq + (size_t)(row0b + wm + i * 16 + lr) * 512
                                            + hh * 64 + kofs);
            #pragma unroll
            for (int j = 0; j < 5; ++j)
                bfr[j] = *(const bf16x8*)&kvT[j * 16 + lr][kofs];
            #pragma unroll
            for (int i = 0; i < 4; ++i)
                #pragma unroll
                for (int j = 0; j < 5; ++j)
                    acc[i][j] = __builtin_amdgcn_mfma_f32_16x16x32_bf16(af[i], bfr[j], acc[i][j], 0, 0, 0);
        }

        const int colb = hh * 64;
        #pragma unroll
        for (int i = 0; i < 4; ++i) {
            const int rowb = row0b + wm + i * 16 + quad * 4;
            #pragma unroll
            for (int r = 0; r < 4; ++r) {
                const float den = __shfl(acc[i][4][r], lane & 48, 64);
                const float inv = 1.0f / (den + 1e-6f);
                const size_t base = (size_t)(rowb + r) * 512 + colb;
                #pragma unroll
                for (int j = 0; j < 4; ++j)
                    attn[base + j * 16 + lr] = f2bf(acc[i][j][r] * inv);
            }
        }
    }
}

// ---------------- mean pool accumulate ----------------
__global__ __launch_bounds__(256) void pool_kernel(
    const float* __restrict__ xf, float* __restrict__ pooled, int gbase)
{
    const int row0 = blockIdx.x * 256;
    const int b = (gbase + row0) >> 13;
    const int t = threadIdx.x;
    float a0 = 0.f, a1 = 0.f;
    const size_t base = (size_t)row0 * 512;
    for (int s = 0; s < 256; ++s) {
        a0 += xf[base + (size_t)s * 512 + t];
        a1 += xf[base + (size_t)s * 512 + t + 256];
    }
    atomicAdd(&pooled[b * 512 + t], a0);
    atomicAdd(&pooled[b * 512 + t + 256], a1);
}

// ---------------- classifier head ----------------
__global__ __launch_bounds__(256) void head_kernel(
    const float* __restrict__ pooled, const void* __restrict__ Wc,
    const void* __restrict__ bc, void* __restrict__ out, const int* __restrict__ flag)
{
    const int f = *flag;
    const int t = threadIdx.x;
    const int grp = t >> 4, ln = t & 15;
    const int b = grp >> 1, c = grp & 1;
    float p = 0.f;
    for (int d = ln; d < 512; d += 16)
        p += pooled[b * 512 + d] * loadElem(Wc, (size_t)d * 2 + c, f);
    #pragma unroll
    for (int off = 8; off; off >>= 1) p += __shfl_xor(p, off, 64);
    if (ln == 0) {
        const float val = p * (1.0f / 8192.0f) + loadElem(bc, c, f);
        if (f) ((float*)out)[b * 2 + c] = val;
        else   ((__hip_bfloat16*)out)[b * 2 + c] = f2bf(val);
    }
}

// ---------------- launch ----------------
extern "C" void kernel_launch(void* const* d_in, const int* in_sizes, int n_in,
                              void* d_out, int out_size, void* d_ws, size_t ws_size,
                              hipStream_t stream)
{
    const int* ids   = (const int*)d_in[0];
    const void* emb  = d_in[1];
    const void* Wq   = d_in[2];
    const void* Wk   = d_in[3];
    const void* Wv   = d_in[4];
    const void* Wph  = d_in[5];
    const void* Wo   = d_in[6];
    const void* g1   = d_in[7];
    const void* g2   = d_in[8];
    const void* Wg   = d_in[9];
    const void* Wu   = d_in[10];
    const void* Wd   = d_in[11];
    const void* Wc   = d_in[12];
    const void* bc   = d_in[13];

    char* ws = (char*)d_ws;
    __hip_bfloat16* WQPt  = (__hip_bfloat16*)(ws + OFF_WQPT);
    __hip_bfloat16* WKPt  = (__hip_bfloat16*)(ws + OFF_WKPT);  // [WKPt|WvT] = [256][512] contiguous
    __hip_bfloat16* WvT   = (__hip_bfloat16*)(ws + OFF_WVT);
    __hip_bfloat16* WoT   = (__hip_bfloat16*)(ws + OFF_WOT);
    __hip_bfloat16* WgT   = (__hip_bfloat16*)(ws + OFF_WGT);
    __hip_bfloat16* WuT   = (__hip_bfloat16*)(ws + OFF_WUT);
    __hip_bfloat16* WdT   = (__hip_bfloat16*)(ws + OFF_WDT);
    float*          kv    = (float*)(ws + OFF_KV);
    float*          z     = (float*)(ws + OFF_Z);
    float*          pooled= (float*)(ws + OFF_POOL);
    int*            flag  = (int*)(ws + OFF_FLAG);

    // ---- adaptive chunk: largest power-of-2 C in [256, 16384] that fits ws ----
    int C = 16384;
    while (C > 256 && PERSIST + PERTOK * (size_t)C > ws_size) C >>= 1;
    const int NC = NTOK / C;

    char* cb = ws + PERSIST;
    float*          xf   = (float*)cb;                                  // f32  [C][512]
    __hip_bfloat16* h    = (__hip_bfloat16*)(cb + (size_t)C * 2048);    // bf16 [C][512]
    __hip_bfloat16* pq   = (__hip_bfloat16*)(cb + (size_t)C * 3072);    // bf16 [C][512]
    __hip_bfloat16* pkv  = (__hip_bfloat16*)(cb + (size_t)C * 4096);    // bf16 [C][256]  pk|v
    __hip_bfloat16* attn = (__hip_bfloat16*)(cb + (size_t)C * 4608);    // bf16 [C][512]
    __hip_bfloat16* tbuf = (__hip_bfloat16*)(cb + (size_t)C * 5632);    // bf16 [C][2048]

    detect_kernel<<<1, 128, 0, stream>>>((const unsigned int*)Wph, flag);
    zero_kernel<<<(ZERO_FLOATS + 255) / 256, 256, 0, stream>>>(kv, ZERO_FLOATS);

    // weight prep
    fuse_phi_kernel<<<1024, 256, 0, stream>>>(Wq, Wph, WQPt, 512, flag);
    fuse_phi_kernel<<<256, 256, 0, stream>>>(Wk, Wph, WKPt, 128, flag);
    transpose_kernel<<<(512 * 128) / 256, 256, 0, stream>>>(Wv, WvT, 512, 128, flag);
    transpose_kernel<<<(512 * 512) / 256, 256, 0, stream>>>(Wo, WoT, 512, 512, flag);
    transpose_kernel<<<(512 * 2048) / 256, 256, 0, stream>>>(Wg, WgT, 512, 2048, flag);
    transpose_kernel<<<(512 * 2048) / 256, 256, 0, stream>>>(Wu, WuT, 512, 2048, flag);
    transpose_kernel<<<(2048 * 512) / 256, 256, 0, stream>>>(Wd, WdT, 2048, 512, flag);

    // ---- pass A: accumulate global kv / z over all token chunks ----
    for (int c = 0; c < NC; ++c) {
        const int g0 = c * C;
        embed_rms_kernel<<<C / 4, 256, 0, stream>>>(ids + g0, emb, g1, xf, h, flag, 0);
        // combined [pk | v] GEMM: B = [WKPt ; WvT] rows 0..255
        gemm128_kernel<4><<<dim3(C / 128, 2), 256, 0, stream>>>(h, WKPt, pkv, 512, 256);
        kv_z_kernel<<<dim3(C / 128, 2), 256, 0, stream>>>(pkv, kv, z, g0, 128);
    }

    // ---- pass B: per chunk -> pq, mix, +Wo, rms, fused SwiGLU, +Wd, pool ----
    for (int c = 0; c < NC; ++c) {
        const int g0 = c * C;
        embed_rms_kernel<<<C / 4, 256, 0, stream>>>(ids + g0, emb, g1, xf, h, flag, 1);
        dim3 gq(C / 128, 4);
        gemm128_kernel<1><<<gq, 256, 0, stream>>>(h, WQPt, pq, 512, 512);
        attn_mix_kernel<<<dim3(C / 128, 2), 256, 0, stream>>>(pq, kv, z, attn, g0);
        gemm128_kernel<2><<<gq, 256, 0, stream>>>(attn, WoT, xf, 512, 512);
        rms2_kernel<<<C / 4, 256, 0, stream>>>(xf, g2, h, flag);
        dim3 gg(C / 128, 16);
        gemm_ffn_kernel<<<gg, 256, 0, stream>>>(h, WgT, WuT, tbuf, 512, 2048);
        dim3 gd(C / 128, 4);
        gemm128_kernel<2><<<gd, 256, 0, stream>>>(tbuf, WdT, xf, 2048, 512);
        pool_kernel<<<C / 256, 256, 0, stream>>>(xf, pooled, g0);
    }

    head_kernel<<<1, 256, 0, stream>>>(pooled, Wc, bc, d_out, flag);
}

// Round 7
// 1382.836 us; speedup vs baseline: 2.2572x; 1.0259x over previous
//
#include <hip/hip_runtime.h>
#include <hip/hip_bf16.h>
#include <math.h>

// ---------------- types / helpers ----------------
typedef __attribute__((ext_vector_type(8))) short bf16x8;
typedef __attribute__((ext_vector_type(4))) float f32x4;

#define DEV static __device__ __forceinline__
#define AS1 __attribute__((address_space(1)))
#define AS3 __attribute__((address_space(3)))

DEV float bf2f(__hip_bfloat16 v) { return __bfloat162float(v); }
DEV __hip_bfloat16 f2bf(float f) { return __float2bfloat16(f); }
DEV float us2f(unsigned short u) { return __uint_as_float(((unsigned int)u) << 16); }
DEV unsigned short f2us(float f) {
    __hip_bfloat16 b = __float2bfloat16(f);
    return *(unsigned short*)&b;
}

// async global->LDS, 16 B per lane (LDS dst = wave-uniform base + lane*16)
DEV void gload_lds16(const void* g, void* l) {
    __builtin_amdgcn_global_load_lds((const AS1 unsigned int*)g,
                                     (AS3 unsigned int*)l, 16, 0, 0);
}

// load 8 consecutive floats from an input tensor that is either f32 or bf16
DEV void load8(const void* p, size_t off, int f32m, float* o) {
    if (f32m) {
        const float4* r = (const float4*)((const float*)p + off);
        float4 A = r[0], B = r[1];
        o[0] = A.x; o[1] = A.y; o[2] = A.z; o[3] = A.w;
        o[4] = B.x; o[5] = B.y; o[6] = B.z; o[7] = B.w;
    } else {
        const ushort4* r = (const ushort4*)((const __hip_bfloat16*)p + off);
        ushort4 A = r[0], B = r[1];
        o[0] = us2f(A.x); o[1] = us2f(A.y); o[2] = us2f(A.z); o[3] = us2f(A.w);
        o[4] = us2f(B.x); o[5] = us2f(B.y); o[6] = us2f(B.z); o[7] = us2f(B.w);
    }
}

DEV float loadElem(const void* p, size_t idx, int f32m) {
    return f32m ? ((const float*)p)[idx] : bf2f(((const __hip_bfloat16*)p)[idx]);
}

// ---------------- problem constants ----------------
// B=8 S=8192 D=512 H=8 HK=2 DH=64 M=64 DFF=2048 NCLS=2 G=4
constexpr int NTOK = 65536;   // 8*8192

// ---------------- persistent ws layout (bytes) ----------------
constexpr size_t OFF_WQPT = 0;                       // bf16 [512][512]  (Wq@Wphi)^T
constexpr size_t OFF_WKPT = OFF_WQPT + 524288ull;    // bf16 [128][512]  (Wk@Wphi)^T   } contiguous:
constexpr size_t OFF_WVT  = OFF_WKPT + 131072ull;    // bf16 [128][512]  Wv^T          } [768][512] B-matrix
constexpr size_t OFF_WOT  = OFF_WVT  + 131072ull;    // bf16 [512][512]  Wo^T
constexpr size_t OFF_WGT  = OFF_WOT  + 524288ull;    // bf16 [2048][512] Wg^T
constexpr size_t OFF_WUT  = OFF_WGT  + 2097152ull;   // bf16 [2048][512] Wu^T
constexpr size_t OFF_WDT  = OFF_WUT  + 2097152ull;   // bf16 [512][2048] Wd^T
constexpr size_t OFF_KV   = OFF_WDT  + 2097152ull;   // f32  [8][2][64][64]
constexpr size_t OFF_Z    = OFF_KV   + 262144ull;    // f32  [8][2][64]
constexpr size_t OFF_POOL = OFF_Z    + 4096ull;      // f32  [8][512]
constexpr size_t OFF_FLAG = OFF_POOL + 16384ull;     // int  dtype flag (1 = f32 inputs)
constexpr size_t PERSIST  = OFF_FLAG + 256ull;       // 7,885,056 B
constexpr size_t OFF_PQALL = PERSIST;                // bf16 [65536][512] pq (all tokens)
constexpr size_t PQALL_SZ  = 67108864ull;
constexpr size_t CHUNKBASE = OFF_PQALL + PQALL_SZ;   // 74,993,920 B
constexpr int    ZERO_FLOATS = (262144 + 4096 + 16384) / 4;  // kv+z+pooled
// per-token chunk bytes: xf 2048 + h 1024 + attn 1024 + pkv 512 + tbuf 4096 = 8704
constexpr size_t PERTOK = 8704ull;
// ws check: rounds 3-6 ran C=16384 at PERTOK=13824 => ws >= 234.4 MB;
// this layout at C=16384 needs 74.99 MB + 142.6 MB = 217.6 MB  -> fits.

// ---------------- dtype detection ----------------
__global__ __launch_bounds__(128) void detect_kernel(
    const unsigned int* __restrict__ w, int* __restrict__ flag)
{
    __shared__ int cnt;
    if (threadIdx.x == 0) cnt = 0;
    __syncthreads();
    unsigned int v = w[threadIdx.x];
    float a = fabsf(us2f((unsigned short)(v & 0xFFFFu)));
    if (a >= 0.0625f && a <= 8.0f) atomicAdd(&cnt, 1);
    __syncthreads();
    if (threadIdx.x == 0) *flag = (cnt < 64) ? 1 : 0;
}

// ---------------- tiny init ----------------
__global__ __launch_bounds__(256) void zero_kernel(float* __restrict__ p, int n)
{
    int i = blockIdx.x * 256 + threadIdx.x;
    if (i < n) p[i] = 0.0f;
}

// ---------------- weight prep ----------------
// outT[hm][d] = sum_dh W[d][h*64+dh] * Wphi[dh][m]   (hm = h*64+m), row-major [nh*64][512]
__global__ __launch_bounds__(256) void fuse_phi_kernel(
    const void* __restrict__ W, const void* __restrict__ Wphi,
    __hip_bfloat16* __restrict__ outT, int wld, const int* __restrict__ flag)
{
    const int f = *flag;
    int o = blockIdx.x * 256 + threadIdx.x;   // o = hm*512 + d
    int hm = o >> 9, d = o & 511;
    int h = hm >> 6, m = hm & 63;
    float acc = 0.f;
    if (f) {
        const float* Wf = (const float*)W;
        const float* Pf = (const float*)Wphi;
        #pragma unroll 8
        for (int dh = 0; dh < 64; ++dh)
            acc += Wf[(size_t)d * wld + h * 64 + dh] * Pf[dh * 64 + m];
    } else {
        const __hip_bfloat16* Wb = (const __hip_bfloat16*)W;
        const __hip_bfloat16* Pb = (const __hip_bfloat16*)Wphi;
        #pragma unroll 8
        for (int dh = 0; dh < 64; ++dh)
            acc += bf2f(Wb[(size_t)d * wld + h * 64 + dh]) * bf2f(Pb[dh * 64 + m]);
    }
    outT[o] = f2bf(acc);
}

// dst[Ccols][R] = src[R][Ccols]^T, LDS-tiled 32x32 (R, Ccols multiples of 32)
__global__ __launch_bounds__(256) void transpose_kernel(
    const void* __restrict__ src, __hip_bfloat16* __restrict__ dst, int R, int Ccols,
    const int* __restrict__ flag)
{
    __shared__ float tile[32][33];
    const int f = *flag;
    const int tx = threadIdx.x & 31, ty = threadIdx.x >> 5;   // 32 x 8
    const int c0 = blockIdx.x * 32, r0 = blockIdx.y * 32;
    #pragma unroll
    for (int k = 0; k < 4; ++k) {
        const int rl = ty + k * 8;
        tile[rl][tx] = loadElem(src, (size_t)(r0 + rl) * Ccols + c0 + tx, f);
    }
    __syncthreads();
    #pragma unroll
    for (int k = 0; k < 4; ++k) {
        const int cl = ty + k * 8;
        dst[(size_t)(c0 + cl) * R + r0 + tx] = f2bf(tile[tx][cl]);
    }
}

// ---------------- embedding gather + rmsnorm (wave per row; chunk-local) ----------------
__global__ __launch_bounds__(256) void embed_rms_kernel(
    const int* __restrict__ ids, const void* __restrict__ emb,
    const void* __restrict__ g1, float* __restrict__ xf,
    __hip_bfloat16* __restrict__ h, const int* __restrict__ flag,
    int write_xf, int write_h)
{
    const int f = *flag;
    const int n = blockIdx.x * 4 + (threadIdx.x >> 6);   // local row in chunk
    const int lane = threadIdx.x & 63;
    const int id = ids[n];
    float x[8];
    load8(emb, (size_t)id * 512 + lane * 8, f, x);
    float ss = 0.f;
    #pragma unroll
    for (int i = 0; i < 8; ++i) ss += x[i] * x[i];
    #pragma unroll
    for (int off = 32; off; off >>= 1) ss += __shfl_xor(ss, off, 64);
    const float scale = rsqrtf(ss * (1.0f / 512.0f) + 1e-6f);

    if (write_xf) {
        float4* xo = (float4*)(xf + (size_t)n * 512 + lane * 8);
        xo[0] = make_float4(x[0], x[1], x[2], x[3]);
        xo[1] = make_float4(x[4], x[5], x[6], x[7]);
    }
    if (write_h) {
        float gv[8];
        load8(g1, (size_t)lane * 8, f, gv);
        ushort4 h0, h1;
        h0.x = f2us(x[0] * scale * gv[0]); h0.y = f2us(x[1] * scale * gv[1]);
        h0.z = f2us(x[2] * scale * gv[2]); h0.w = f2us(x[3] * scale * gv[3]);
        h1.x = f2us(x[4] * scale * gv[4]); h1.y = f2us(x[5] * scale * gv[5]);
        h1.z = f2us(x[6] * scale * gv[6]); h1.w = f2us(x[7] * scale * gv[7]);
        ushort4* ho = (ushort4*)(h + (size_t)n * 512 + lane * 8);
        ho[0] = h0; ho[1] = h1;
    }
}

// ---------------- rmsnorm from f32 residual (chunk-local) ----------------
__global__ __launch_bounds__(256) void rms2_kernel(
    const float* __restrict__ xf, const void* __restrict__ g2,
    __hip_bfloat16* __restrict__ h, const int* __restrict__ flag)
{
    const int f = *flag;
    const int n = blockIdx.x * 4 + (threadIdx.x >> 6);
    const int lane = threadIdx.x & 63;
    const float4* xr = (const float4*)(xf + (size_t)n * 512);
    float4 a = xr[lane * 2], b = xr[lane * 2 + 1];
    float x[8] = { a.x, a.y, a.z, a.w, b.x, b.y, b.z, b.w };
    float ss = 0.f;
    #pragma unroll
    for (int i = 0; i < 8; ++i) ss += x[i] * x[i];
    #pragma unroll
    for (int off = 32; off; off >>= 1) ss += __shfl_xor(ss, off, 64);
    const float scale = rsqrtf(ss * (1.0f / 512.0f) + 1e-6f);

    float gv[8];
    load8(g2, (size_t)lane * 8, f, gv);
    ushort4 h0, h1;
    h0.x = f2us(x[0] * scale * gv[0]); h0.y = f2us(x[1] * scale * gv[1]);
    h0.z = f2us(x[2] * scale * gv[2]); h0.w = f2us(x[3] * scale * gv[3]);
    h1.x = f2us(x[4] * scale * gv[4]); h1.y = f2us(x[5] * scale * gv[5]);
    h1.z = f2us(x[6] * scale * gv[6]); h1.w = f2us(x[7] * scale * gv[7]);
    ushort4* ho = (ushort4*)(h + (size_t)n * 512 + lane * 8);
    ho[0] = h0; ho[1] = h1;
}

// ---------------- MFMA GEMM: C[M,N] = A[M,K] @ Bt[N,K]^T ----------------
// m97 structure: 128x128 tile, BK=32, global_load_lds width-16 staging into
// flat [128][32] LDS tiles with XOR bank swizzle; 4 waves (2x2), wave tile
// 64x64 = 4x4 mfma_f32_16x16x32_bf16.
// MODE 2: Cf32[idx] += acc
// MODE 5: combined pq|pk|v epilogue: bn 0-3 -> Cout=pq (exp(-|.|), Ncols=512);
//         bn 4 -> Cout2=pkv cols 0..127 (exp); bn 5 -> pkv cols 128..255 (plain)
template<int MODE>
__global__ __launch_bounds__(256) void gemm128_kernel(
    const __hip_bfloat16* __restrict__ A, const __hip_bfloat16* __restrict__ Bt,
    void* __restrict__ Cout, __hip_bfloat16* __restrict__ Cout2, int K, int Ncols)
{
    __shared__ __align__(16) char As[8192];   // bf16 [128 rows][32 k], swizzled chunks
    __shared__ __align__(16) char Bs[8192];

    const int tid = threadIdx.x;
    const int bm = blockIdx.x, bn = blockIdx.y;
    const int wave = tid >> 6, lane = tid & 63;
    const int quad = lane >> 4, lr = lane & 15;
    const int wm = (wave >> 1) << 6, wn = (wave & 1) << 6;

    // staging: wave w, instr t in {0,1}; LDS chunk idx = w*128 + t*64 + lane
    const int srow = (wave << 5) + (lane >> 2);          // row for t=0 (t=1: +16)
    const int scol = lane & 3;
    const int sfr  = (srow + (srow >> 2)) & 3;           // == f(srow+16)
    const int sofs = ((scol ^ sfr) << 3);                // swizzled global col (elements)

    const __hip_bfloat16* ga0 = A  + (size_t)(bm * 128 + srow) * K + sofs;
    const __hip_bfloat16* gb0 = Bt + (size_t)(bn * 128 + srow) * K + sofs;
    const __hip_bfloat16* ga1 = ga0 + (size_t)16 * K;
    const __hip_bfloat16* gb1 = gb0 + (size_t)16 * K;
    char* lA0 = As + (wave << 11);
    char* lA1 = lA0 + 1024;
    char* lB0 = Bs + (wave << 11);
    char* lB1 = lB0 + 1024;

    // fragment reads
    const int fl  = (lr + (lr >> 2)) & 3;
    const int ac  = (quad ^ fl) << 4;
    const char* arp = As + ((wm + lr) << 6) + ac;
    const char* brp = Bs + ((wn + lr) << 6) + ac;

    f32x4 acc[4][4];
    #pragma unroll
    for (int i = 0; i < 4; ++i)
        #pragma unroll
        for (int j = 0; j < 4; ++j)
            #pragma unroll
            for (int r = 0; r < 4; ++r) acc[i][j][r] = 0.0f;

    for (int k0 = 0; k0 < K; k0 += 32) {
        __syncthreads();
        gload_lds16(ga0 + k0, lA0);
        gload_lds16(ga1 + k0, lA1);
        gload_lds16(gb0 + k0, lB0);
        gload_lds16(gb1 + k0, lB1);
        __syncthreads();

        bf16x8 af[4], bfr[4];
        #pragma unroll
        for (int i = 0; i < 4; ++i)
            af[i] = *(const bf16x8*)(arp + i * 1024);
        #pragma unroll
        for (int j = 0; j < 4; ++j)
            bfr[j] = *(const bf16x8*)(brp + j * 1024);
        #pragma unroll
        for (int i = 0; i < 4; ++i)
            #pragma unroll
            for (int j = 0; j < 4; ++j)
                acc[i][j] = __builtin_amdgcn_mfma_f32_16x16x32_bf16(af[i], bfr[j], acc[i][j], 0, 0, 0);
    }

    // C/D layout: col = lane&15, row = quad*4 + reg  [m89/m91]
    const int col0 = bn * 128 + wn + lr;
    const int row0 = bm * 128 + wm + quad * 4;
    #pragma unroll
    for (int i = 0; i < 4; ++i)
        #pragma unroll
        for (int j = 0; j < 4; ++j) {
            const int col = col0 + j * 16;
            #pragma unroll
            for (int r = 0; r < 4; ++r) {
                const int row = row0 + i * 16 + r;
                const float v = acc[i][j][r];
                if (MODE == 2) {
                    ((float*)Cout)[(size_t)row * Ncols + col] += v;
                } else {   // MODE 5
                    if (bn < 4) {
                        ((__hip_bfloat16*)Cout)[(size_t)row * 512 + col] =
                            f2bf(expf(-fabsf(v)));
                    } else {
                        const int c2 = col - 512;   // 0..255
                        Cout2[(size_t)row * 256 + c2] =
                            f2bf(bn == 4 ? expf(-fabsf(v)) : v);
                    }
                }
            }
        }
}

// ---------------- fused SwiGLU up-GEMM: t = silu(A@Wg^T) * (A@Wu^T) ----------------
__global__ __launch_bounds__(256, 2) void gemm_ffn_kernel(
    const __hip_bfloat16* __restrict__ A, const __hip_bfloat16* __restrict__ Bg,
    const __hip_bfloat16* __restrict__ Bu, __hip_bfloat16* __restrict__ Cout,
    int K, int Ncols)
{
    __shared__ __align__(16) char As[8192];
    __shared__ __align__(16) char Gs[8192];
    __shared__ __align__(16) char Us[8192];

    const int tid = threadIdx.x;
    const int bm = blockIdx.x, bn = blockIdx.y;
    const int wave = tid >> 6, lane = tid & 63;
    const int quad = lane >> 4, lr = lane & 15;
    const int wm = (wave >> 1) << 6, wn = (wave & 1) << 6;

    const int srow = (wave << 5) + (lane >> 2);
    const int scol = lane & 3;
    const int sfr  = (srow + (srow >> 2)) & 3;
    const int sofs = ((scol ^ sfr) << 3);

    const __hip_bfloat16* ga0 = A  + (size_t)(bm * 128 + srow) * K + sofs;
    const __hip_bfloat16* gg0 = Bg + (size_t)(bn * 128 + srow) * K + sofs;
    const __hip_bfloat16* gu0 = Bu + (size_t)(bn * 128 + srow) * K + sofs;
    const __hip_bfloat16* ga1 = ga0 + (size_t)16 * K;
    const __hip_bfloat16* gg1 = gg0 + (size_t)16 * K;
    const __hip_bfloat16* gu1 = gu0 + (size_t)16 * K;
    char* lA0 = As + (wave << 11);
    char* lG0 = Gs + (wave << 11);
    char* lU0 = Us + (wave << 11);

    const int fl  = (lr + (lr >> 2)) & 3;
    const int ac  = (quad ^ fl) << 4;
    const char* arp = As + ((wm + lr) << 6) + ac;
    const char* grp = Gs + ((wn + lr) << 6) + ac;
    const char* urp = Us + ((wn + lr) << 6) + ac;

    f32x4 accG[4][4], accU[4][4];
    #pragma unroll
    for (int i = 0; i < 4; ++i)
        #pragma unroll
        for (int j = 0; j < 4; ++j)
            #pragma unroll
            for (int r = 0; r < 4; ++r) { accG[i][j][r] = 0.0f; accU[i][j][r] = 0.0f; }

    for (int k0 = 0; k0 < K; k0 += 32) {
        __syncthreads();
        gload_lds16(ga0 + k0, lA0);
        gload_lds16(ga1 + k0, lA0 + 1024);
        gload_lds16(gg0 + k0, lG0);
        gload_lds16(gg1 + k0, lG0 + 1024);
        gload_lds16(gu0 + k0, lU0);
        gload_lds16(gu1 + k0, lU0 + 1024);
        __syncthreads();

        bf16x8 af[4], bgf[4], buf_[4];
        #pragma unroll
        for (int i = 0; i < 4; ++i)
            af[i] = *(const bf16x8*)(arp + i * 1024);
        #pragma unroll
        for (int j = 0; j < 4; ++j) {
            bgf[j]  = *(const bf16x8*)(grp + j * 1024);
            buf_[j] = *(const bf16x8*)(urp + j * 1024);
        }
        #pragma unroll
        for (int i = 0; i < 4; ++i)
            #pragma unroll
            for (int j = 0; j < 4; ++j) {
                accG[i][j] = __builtin_amdgcn_mfma_f32_16x16x32_bf16(af[i], bgf[j],  accG[i][j], 0, 0, 0);
                accU[i][j] = __builtin_amdgcn_mfma_f32_16x16x32_bf16(af[i], buf_[j], accU[i][j], 0, 0, 0);
            }
    }

    const int col0 = bn * 128 + wn + lr;
    const int row0 = bm * 128 + wm + quad * 4;
    #pragma unroll
    for (int i = 0; i < 4; ++i)
        #pragma unroll
        for (int j = 0; j < 4; ++j) {
            const int col = col0 + j * 16;
            #pragma unroll
            for (int r = 0; r < 4; ++r) {
                const int row = row0 + i * 16 + r;
                const float g = accG[i][j][r];
                const float s = g / (1.0f + expf(-g));   // silu(g) from f32 acc
                Cout[(size_t)row * Ncols + col] = f2bf(s * accU[i][j][r]);
            }
        }
}

// ---------------- kv / z global-state reduction (pkv [C][256] input) ----------------
__global__ __launch_bounds__(256) void kv_z_kernel(
    const __hip_bfloat16* __restrict__ pkv,
    float* __restrict__ kv, float* __restrict__ z, int gbase, int nrows)
{
    __shared__ float pks[8][64], vs[8][64];
    const int slab = blockIdx.x, kh = blockIdx.y;
    const int b = (gbase + slab * nrows) >> 13;   // nrows | 8192 -> uniform per block
    const int tid = threadIdx.x;
    const int tm = (tid & 15) << 2, tdh = (tid >> 4) << 2;
    const int lss = tid >> 5, lmm = (tid & 31) << 1;

    float acc[4][4] = {};
    float zacc[4] = {};
    for (int sb = 0; sb < nrows; sb += 8) {
        __syncthreads();
        {
            const size_t n = (size_t)slab * nrows + sb + lss;   // local row
            const __hip_bfloat16* pr = pkv + n * 256 + kh * 64 + lmm;        // pk cols 0..127
            const __hip_bfloat16* vr = pkv + n * 256 + 128 + kh * 64 + lmm;  // v  cols 128..255
            pks[lss][lmm]     = bf2f(pr[0]);
            pks[lss][lmm + 1] = bf2f(pr[1]);
            vs[lss][lmm]      = bf2f(vr[0]);
            vs[lss][lmm + 1]  = bf2f(vr[1]);
        }
        __syncthreads();
        #pragma unroll
        for (int ss = 0; ss < 8; ++ss) {
            f32x4 p = *(const f32x4*)&pks[ss][tm];
            f32x4 w = *(const f32x4*)&vs[ss][tdh];
            #pragma unroll
            for (int i = 0; i < 4; ++i)
                #pragma unroll
                for (int j = 0; j < 4; ++j)
                    acc[i][j] += p[i] * w[j];
            if ((tid >> 4) == 0) {
                #pragma unroll
                for (int i = 0; i < 4; ++i) zacc[i] += p[i];
            }
        }
    }
    #pragma unroll
    for (int i = 0; i < 4; ++i)
        #pragma unroll
        for (int j = 0; j < 4; ++j)
            atomicAdd(&kv[(((size_t)b * 2 + kh) * 64 + tm + i) * 64 + tdh + j], acc[i][j]);
    if ((tid >> 4) == 0) {
        #pragma unroll
        for (int i = 0; i < 4; ++i)
            atomicAdd(&z[((size_t)b * 2 + kh) * 64 + tm + i], zacc[i]);
    }
}

// ---------------- attention mix (MFMA): attn = (pq @ kv) / (pq @ z + eps) ----------------
__global__ __launch_bounds__(256) void attn_mix_kernel(
    const __hip_bfloat16* __restrict__ pq, const float* __restrict__ kvf,
    const float* __restrict__ zf, __hip_bfloat16* __restrict__ attn, int gbase)
{
    __shared__ __align__(16) __hip_bfloat16 kvT[80][72];
    const int kh = blockIdx.y;
    const int row0b = blockIdx.x * 128;
    const int b = (gbase + row0b) >> 13;
    const int tid = threadIdx.x;

    const float* kvsrc = kvf + ((size_t)b * 2 + kh) * 4096;
    for (int i = tid; i < 4096; i += 256) {
        const int m = i >> 6, dh = i & 63;
        kvT[dh][m] = f2bf(kvsrc[i]);
    }
    if (tid < 64) kvT[64][tid] = f2bf(zf[((size_t)b * 2 + kh) * 64 + tid]);
    for (int i = tid; i < 15 * 64; i += 256) {
        const int rr = 65 + (i >> 6), m = i & 63;
        kvT[rr][m] = f2bf(0.0f);
    }
    __syncthreads();

    const int wave = tid >> 6, lane = tid & 63;
    const int quad = lane >> 4, lr = lane & 15;
    const int wm = (wave >> 1) << 6;
    const int whead = (wave & 1) << 1;

    #pragma unroll
    for (int g2 = 0; g2 < 2; ++g2) {
        const int hh = kh * 4 + whead + g2;
        f32x4 acc[4][5];
        #pragma unroll
        for (int i = 0; i < 4; ++i)
            #pragma unroll
            for (int j = 0; j < 5; ++j)
                #pragma unroll
                for (int r = 0; r < 4; ++r) acc[i][j][r] = 0.0f;

        #pragma unroll
        for (int kk = 0; kk < 2; ++kk) {
            const int kofs = kk * 32 + quad * 8;
            bf16x8 af[4], bfr[5];
            #pragma unroll
            for (int i = 0; i < 4; ++i)
                af[i] = *(const bf16x8*)(pq + (size_t)(row0b + wm + i * 16 + lr) * 512
                                            + hh * 64 + kofs);
            #pragma unroll
            for (int j = 0; j < 5; ++j)
                bfr[j] = *(const bf16x8*)&kvT[j * 16 + lr][kofs];
            #pragma unroll
            for (int i = 0; i < 4; ++i)
                #pragma unroll
                for (int j = 0; j < 5; ++j)
                    acc[i][j] = __builtin_amdgcn_mfma_f32_16x16x32_bf16(af[i], bfr[j], acc[i][j], 0, 0, 0);
        }

        const int colb = hh * 64;
        #pragma unroll
        for (int i = 0; i < 4; ++i) {
            const int rowb = row0b + wm + i * 16 + quad * 4;
            #pragma unroll
            for (int r = 0; r < 4; ++r) {
                const float den = __shfl(acc[i][4][r], lane & 48, 64);
                const float inv = 1.0f / (den + 1e-6f);
                const size_t base = (size_t)(rowb + r) * 512 + colb;
                #pragma unroll
                for (int j = 0; j < 4; ++j)
                    attn[base + j * 16 + lr] = f2bf(acc[i][j][r] * inv);
            }
        }
    }
}

// ---------------- mean pool accumulate ----------------
__global__ __launch_bounds__(256) void pool_kernel(
    const float* __restrict__ xf, float* __restrict__ pooled, int gbase)
{
    const int row0 = blockIdx.x * 256;
    const int b = (gbase + row0) >> 13;
    const int t = threadIdx.x;
    float a0 = 0.f, a1 = 0.f;
    const size_t base = (size_t)row0 * 512;
    for (int s = 0; s < 256; ++s) {
        a0 += xf[base + (size_t)s * 512 + t];
        a1 += xf[base + (size_t)s * 512 + t + 256];
    }
    atomicAdd(&pooled[b * 512 + t], a0);
    atomicAdd(&pooled[b * 512 + t + 256], a1);
}

// ---------------- classifier head ----------------
__global__ __launch_bounds__(256) void head_kernel(
    const float* __restrict__ pooled, const void* __restrict__ Wc,
    const void* __restrict__ bc, void* __restrict__ out, const int* __restrict__ flag)
{
    const int f = *flag;
    const int t = threadIdx.x;
    const int grp = t >> 4, ln = t & 15;
    const int b = grp >> 1, c = grp & 1;
    float p = 0.f;
    for (int d = ln; d < 512; d += 16)
        p += pooled[b * 512 + d] * loadElem(Wc, (size_t)d * 2 + c, f);
    #pragma unroll
    for (int off = 8; off; off >>= 1) p += __shfl_xor(p, off, 64);
    if (ln == 0) {
        const float val = p * (1.0f / 8192.0f) + loadElem(bc, c, f);
        if (f) ((float*)out)[b * 2 + c] = val;
        else   ((__hip_bfloat16*)out)[b * 2 + c] = f2bf(val);
    }
}

// ---------------- launch ----------------
extern "C" void kernel_launch(void* const* d_in, const int* in_sizes, int n_in,
                              void* d_out, int out_size, void* d_ws, size_t ws_size,
                              hipStream_t stream)
{
    const int* ids   = (const int*)d_in[0];
    const void* emb  = d_in[1];
    const void* Wq   = d_in[2];
    const void* Wk   = d_in[3];
    const void* Wv   = d_in[4];
    const void* Wph  = d_in[5];
    const void* Wo   = d_in[6];
    const void* g1   = d_in[7];
    const void* g2   = d_in[8];
    const void* Wg   = d_in[9];
    const void* Wu   = d_in[10];
    const void* Wd   = d_in[11];
    const void* Wc   = d_in[12];
    const void* bc   = d_in[13];

    char* ws = (char*)d_ws;
    __hip_bfloat16* WQPt  = (__hip_bfloat16*)(ws + OFF_WQPT);  // [WQPt|WKPt|WvT] = [768][512]
    __hip_bfloat16* WKPt  = (__hip_bfloat16*)(ws + OFF_WKPT);
    __hip_bfloat16* WvT   = (__hip_bfloat16*)(ws + OFF_WVT);
    __hip_bfloat16* WoT   = (__hip_bfloat16*)(ws + OFF_WOT);
    __hip_bfloat16* WgT   = (__hip_bfloat16*)(ws + OFF_WGT);
    __hip_bfloat16* WuT   = (__hip_bfloat16*)(ws + OFF_WUT);
    __hip_bfloat16* WdT   = (__hip_bfloat16*)(ws + OFF_WDT);
    float*          kv    = (float*)(ws + OFF_KV);
    float*          z     = (float*)(ws + OFF_Z);
    float*          pooled= (float*)(ws + OFF_POOL);
    int*            flag  = (int*)(ws + OFF_FLAG);
    __hip_bfloat16* pqall = (__hip_bfloat16*)(ws + OFF_PQALL); // bf16 [NTOK][512]

    // ---- adaptive chunk: largest power-of-2 C in [256, 16384] that fits ws ----
    int C = 16384;
    while (C > 256 && CHUNKBASE + PERTOK * (size_t)C > ws_size) C >>= 1;
    const int NC = NTOK / C;

    char* cb = ws + CHUNKBASE;
    float*          xf   = (float*)cb;                                  // f32  [C][512]
    __hip_bfloat16* h    = (__hip_bfloat16*)(cb + (size_t)C * 2048);    // bf16 [C][512]
    __hip_bfloat16* attn = (__hip_bfloat16*)(cb + (size_t)C * 3072);    // bf16 [C][512]
    __hip_bfloat16* pkv  = (__hip_bfloat16*)(cb + (size_t)C * 4096);    // bf16 [C][256]  pk|v
    __hip_bfloat16* tbuf = (__hip_bfloat16*)(cb + (size_t)C * 4608);    // bf16 [C][2048]

    detect_kernel<<<1, 128, 0, stream>>>((const unsigned int*)Wph, flag);
    zero_kernel<<<(ZERO_FLOATS + 255) / 256, 256, 0, stream>>>(kv, ZERO_FLOATS);

    // weight prep
    fuse_phi_kernel<<<1024, 256, 0, stream>>>(Wq, Wph, WQPt, 512, flag);
    fuse_phi_kernel<<<256, 256, 0, stream>>>(Wk, Wph, WKPt, 128, flag);
    transpose_kernel<<<dim3(128 / 32, 512 / 32), 256, 0, stream>>>(Wv, WvT, 512, 128, flag);
    transpose_kernel<<<dim3(512 / 32, 512 / 32), 256, 0, stream>>>(Wo, WoT, 512, 512, flag);
    transpose_kernel<<<dim3(2048 / 32, 512 / 32), 256, 0, stream>>>(Wg, WgT, 512, 2048, flag);
    transpose_kernel<<<dim3(2048 / 32, 512 / 32), 256, 0, stream>>>(Wu, WuT, 512, 2048, flag);
    transpose_kernel<<<dim3(512 / 32, 2048 / 32), 256, 0, stream>>>(Wd, WdT, 2048, 512, flag);

    // ---- pass A: pq (all tokens) + per-chunk pk|v -> accumulate global kv / z ----
    for (int c = 0; c < NC; ++c) {
        const int g0 = c * C;
        embed_rms_kernel<<<C / 4, 256, 0, stream>>>(ids + g0, emb, g1, xf, h, flag, 0, 1);
        // combined [pq | pk | v] GEMM: B = [WQPt;WKPt;WvT] rows 0..767
        gemm128_kernel<5><<<dim3(C / 128, 6), 256, 0, stream>>>(
            h, WQPt, pqall + (size_t)g0 * 512, pkv, 512, 512);
        kv_z_kernel<<<dim3(C / 128, 2), 256, 0, stream>>>(pkv, kv, z, g0, 128);
    }

    // ---- pass B: per chunk -> mix, +Wo, rms, fused SwiGLU, +Wd, pool ----
    for (int c = 0; c < NC; ++c) {
        const int g0 = c * C;
        embed_rms_kernel<<<C / 4, 256, 0, stream>>>(ids + g0, emb, g1, xf, h, flag, 1, 0);
        attn_mix_kernel<<<dim3(C / 128, 2), 256, 0, stream>>>(
            pqall + (size_t)g0 * 512, kv, z, attn, g0);
        gemm128_kernel<2><<<dim3(C / 128, 4), 256, 0, stream>>>(
            attn, WoT, xf, nullptr, 512, 512);
        rms2_kernel<<<C / 4, 256, 0, stream>>>(xf, g2, h, flag);
        dim3 gg(C / 128, 16);
        gemm_ffn_kernel<<<gg, 256, 0, stream>>>(h, WgT, WuT, tbuf, 512, 2048);
        gemm128_kernel<2><<<dim3(C / 128, 4), 256, 0, stream>>>(
            tbuf, WdT, xf, nullptr, 2048, 512);
        pool_kernel<<<C / 256, 256, 0, stream>>>(xf, pooled, g0);
    }

    head_kernel<<<1, 256, 0, stream>>>(pooled, Wc, bc, d_out, flag);
}

// Round 8
// 1307.283 us; speedup vs baseline: 2.3877x; 1.0578x over previous
//
#include <hip/hip_runtime.h>
#include <hip/hip_bf16.h>
#include <math.h>

// ---------------- types / helpers ----------------
typedef __attribute__((ext_vector_type(8))) short bf16x8;
typedef __attribute__((ext_vector_type(4))) float f32x4;

#define DEV static __device__ __forceinline__
#define AS1 __attribute__((address_space(1)))
#define AS3 __attribute__((address_space(3)))

DEV float bf2f(__hip_bfloat16 v) { return __bfloat162float(v); }
DEV __hip_bfloat16 f2bf(float f) { return __float2bfloat16(f); }
DEV float us2f(unsigned short u) { return __uint_as_float(((unsigned int)u) << 16); }
DEV unsigned short f2us(float f) {
    __hip_bfloat16 b = __float2bfloat16(f);
    return *(unsigned short*)&b;
}

// async global->LDS, 16 B per lane (LDS dst = wave-uniform base + lane*16)
DEV void gload_lds16(const void* g, void* l) {
    __builtin_amdgcn_global_load_lds((const AS1 unsigned int*)g,
                                     (AS3 unsigned int*)l, 16, 0, 0);
}

// load 8 consecutive floats from an input tensor that is either f32 or bf16
DEV void load8(const void* p, size_t off, int f32m, float* o) {
    if (f32m) {
        const float4* r = (const float4*)((const float*)p + off);
        float4 A = r[0], B = r[1];
        o[0] = A.x; o[1] = A.y; o[2] = A.z; o[3] = A.w;
        o[4] = B.x; o[5] = B.y; o[6] = B.z; o[7] = B.w;
    } else {
        const ushort4* r = (const ushort4*)((const __hip_bfloat16*)p + off);
        ushort4 A = r[0], B = r[1];
        o[0] = us2f(A.x); o[1] = us2f(A.y); o[2] = us2f(A.z); o[3] = us2f(A.w);
        o[4] = us2f(B.x); o[5] = us2f(B.y); o[6] = us2f(B.z); o[7] = us2f(B.w);
    }
}

DEV float loadElem(const void* p, size_t idx, int f32m) {
    return f32m ? ((const float*)p)[idx] : bf2f(((const __hip_bfloat16*)p)[idx]);
}

// ---------------- problem constants ----------------
// B=8 S=8192 D=512 H=8 HK=2 DH=64 M=64 DFF=2048 NCLS=2 G=4
constexpr int NTOK = 65536;   // 8*8192

// ---------------- persistent ws layout (bytes) ----------------
constexpr size_t OFF_WQPT = 0;                       // bf16 [512][512]  (Wq@Wphi)^T
constexpr size_t OFF_WKPT = OFF_WQPT + 524288ull;    // bf16 [128][512]  (Wk@Wphi)^T   } contiguous:
constexpr size_t OFF_WVT  = OFF_WKPT + 131072ull;    // bf16 [128][512]  Wv^T          } [768][512] B-matrix
constexpr size_t OFF_WOT  = OFF_WVT  + 131072ull;    // bf16 [512][512]  Wo^T
constexpr size_t OFF_WGT  = OFF_WOT  + 524288ull;    // bf16 [2048][512] Wg^T
constexpr size_t OFF_WUT  = OFF_WGT  + 2097152ull;   // bf16 [2048][512] Wu^T
constexpr size_t OFF_WDT  = OFF_WUT  + 2097152ull;   // bf16 [512][2048] Wd^T
constexpr size_t OFF_KV   = OFF_WDT  + 2097152ull;   // f32  [8][2][64][64]
constexpr size_t OFF_Z    = OFF_KV   + 262144ull;    // f32  [8][2][64]
constexpr size_t OFF_POOL = OFF_Z    + 4096ull;      // f32  [8][512]
constexpr size_t OFF_FLAG = OFF_POOL + 16384ull;     // int  dtype flag (1 = f32 inputs)
constexpr size_t PERSIST  = OFF_FLAG + 256ull;       // 7,885,056 B
constexpr size_t OFF_PQALL = PERSIST;                // bf16 [65536][512] pq (all tokens)
constexpr size_t PQALL_SZ  = 67108864ull;
constexpr size_t CHUNKBASE = OFF_PQALL + PQALL_SZ;   // 74,993,920 B
constexpr int    ZERO_FLOATS = (262144 + 4096 + 16384) / 4;  // kv+z+pooled
// per-token chunk bytes: xf 2048 + h 1024 + attn 1024 + pkv 512 + tbuf 4096 = 8704
constexpr size_t PERTOK = 8704ull;
// ws check: rounds 3-6 ran C=16384 at PERTOK=13824 => ws >= 234.4 MB;
// this layout at C=16384 needs 74.99 MB + 142.6 MB = 217.6 MB  -> fits.

// ---------------- dtype detection ----------------
__global__ __launch_bounds__(128) void detect_kernel(
    const unsigned int* __restrict__ w, int* __restrict__ flag)
{
    __shared__ int cnt;
    if (threadIdx.x == 0) cnt = 0;
    __syncthreads();
    unsigned int v = w[threadIdx.x];
    float a = fabsf(us2f((unsigned short)(v & 0xFFFFu)));
    if (a >= 0.0625f && a <= 8.0f) atomicAdd(&cnt, 1);
    __syncthreads();
    if (threadIdx.x == 0) *flag = (cnt < 64) ? 1 : 0;
}

// ---------------- tiny init ----------------
__global__ __launch_bounds__(256) void zero_kernel(float* __restrict__ p, int n)
{
    int i = blockIdx.x * 256 + threadIdx.x;
    if (i < n) p[i] = 0.0f;
}

// ---------------- weight prep ----------------
// outT[hm][d] = sum_dh W[d][h*64+dh] * Wphi[dh][m]   (hm = h*64+m), row-major [nh*64][512]
__global__ __launch_bounds__(256) void fuse_phi_kernel(
    const void* __restrict__ W, const void* __restrict__ Wphi,
    __hip_bfloat16* __restrict__ outT, int wld, const int* __restrict__ flag)
{
    const int f = *flag;
    int o = blockIdx.x * 256 + threadIdx.x;   // o = hm*512 + d
    int hm = o >> 9, d = o & 511;
    int h = hm >> 6, m = hm & 63;
    float acc = 0.f;
    if (f) {
        const float* Wf = (const float*)W;
        const float* Pf = (const float*)Wphi;
        #pragma unroll 8
        for (int dh = 0; dh < 64; ++dh)
            acc += Wf[(size_t)d * wld + h * 64 + dh] * Pf[dh * 64 + m];
    } else {
        const __hip_bfloat16* Wb = (const __hip_bfloat16*)W;
        const __hip_bfloat16* Pb = (const __hip_bfloat16*)Wphi;
        #pragma unroll 8
        for (int dh = 0; dh < 64; ++dh)
            acc += bf2f(Wb[(size_t)d * wld + h * 64 + dh]) * bf2f(Pb[dh * 64 + m]);
    }
    outT[o] = f2bf(acc);
}

// dst[Ccols][R] = src[R][Ccols]^T, LDS-tiled 32x32 (R, Ccols multiples of 32)
__global__ __launch_bounds__(256) void transpose_kernel(
    const void* __restrict__ src, __hip_bfloat16* __restrict__ dst, int R, int Ccols,
    const int* __restrict__ flag)
{
    __shared__ float tile[32][33];
    const int f = *flag;
    const int tx = threadIdx.x & 31, ty = threadIdx.x >> 5;   // 32 x 8
    const int c0 = blockIdx.x * 32, r0 = blockIdx.y * 32;
    #pragma unroll
    for (int k = 0; k < 4; ++k) {
        const int rl = ty + k * 8;
        tile[rl][tx] = loadElem(src, (size_t)(r0 + rl) * Ccols + c0 + tx, f);
    }
    __syncthreads();
    #pragma unroll
    for (int k = 0; k < 4; ++k) {
        const int cl = ty + k * 8;
        dst[(size_t)(c0 + cl) * R + r0 + tx] = f2bf(tile[tx][cl]);
    }
}

// ---------------- embedding gather + rmsnorm (wave per row; chunk-local) ----------------
__global__ __launch_bounds__(256) void embed_rms_kernel(
    const int* __restrict__ ids, const void* __restrict__ emb,
    const void* __restrict__ g1, float* __restrict__ xf,
    __hip_bfloat16* __restrict__ h, const int* __restrict__ flag,
    int write_xf, int write_h)
{
    const int f = *flag;
    const int n = blockIdx.x * 4 + (threadIdx.x >> 6);   // local row in chunk
    const int lane = threadIdx.x & 63;
    const int id = ids[n];
    float x[8];
    load8(emb, (size_t)id * 512 + lane * 8, f, x);
    float ss = 0.f;
    #pragma unroll
    for (int i = 0; i < 8; ++i) ss += x[i] * x[i];
    #pragma unroll
    for (int off = 32; off; off >>= 1) ss += __shfl_xor(ss, off, 64);
    const float scale = rsqrtf(ss * (1.0f / 512.0f) + 1e-6f);

    if (write_xf) {
        float4* xo = (float4*)(xf + (size_t)n * 512 + lane * 8);
        xo[0] = make_float4(x[0], x[1], x[2], x[3]);
        xo[1] = make_float4(x[4], x[5], x[6], x[7]);
    }
    if (write_h) {
        float gv[8];
        load8(g1, (size_t)lane * 8, f, gv);
        ushort4 h0, h1;
        h0.x = f2us(x[0] * scale * gv[0]); h0.y = f2us(x[1] * scale * gv[1]);
        h0.z = f2us(x[2] * scale * gv[2]); h0.w = f2us(x[3] * scale * gv[3]);
        h1.x = f2us(x[4] * scale * gv[4]); h1.y = f2us(x[5] * scale * gv[5]);
        h1.z = f2us(x[6] * scale * gv[6]); h1.w = f2us(x[7] * scale * gv[7]);
        ushort4* ho = (ushort4*)(h + (size_t)n * 512 + lane * 8);
        ho[0] = h0; ho[1] = h1;
    }
}

// ---------------- rmsnorm from f32 residual (chunk-local) ----------------
__global__ __launch_bounds__(256) void rms2_kernel(
    const float* __restrict__ xf, const void* __restrict__ g2,
    __hip_bfloat16* __restrict__ h, const int* __restrict__ flag)
{
    const int f = *flag;
    const int n = blockIdx.x * 4 + (threadIdx.x >> 6);
    const int lane = threadIdx.x & 63;
    const float4* xr = (const float4*)(xf + (size_t)n * 512);
    float4 a = xr[lane * 2], b = xr[lane * 2 + 1];
    float x[8] = { a.x, a.y, a.z, a.w, b.x, b.y, b.z, b.w };
    float ss = 0.f;
    #pragma unroll
    for (int i = 0; i < 8; ++i) ss += x[i] * x[i];
    #pragma unroll
    for (int off = 32; off; off >>= 1) ss += __shfl_xor(ss, off, 64);
    const float scale = rsqrtf(ss * (1.0f / 512.0f) + 1e-6f);

    float gv[8];
    load8(g2, (size_t)lane * 8, f, gv);
    ushort4 h0, h1;
    h0.x = f2us(x[0] * scale * gv[0]); h0.y = f2us(x[1] * scale * gv[1]);
    h0.z = f2us(x[2] * scale * gv[2]); h0.w = f2us(x[3] * scale * gv[3]);
    h1.x = f2us(x[4] * scale * gv[4]); h1.y = f2us(x[5] * scale * gv[5]);
    h1.z = f2us(x[6] * scale * gv[6]); h1.w = f2us(x[7] * scale * gv[7]);
    ushort4* ho = (ushort4*)(h + (size_t)n * 512 + lane * 8);
    ho[0] = h0; ho[1] = h1;
}

// ---------------- MFMA GEMM: C[M,N] = A[M,K] @ Bt[N,K]^T ----------------
// m97 structure: 128x128 tile, BK=32, global_load_lds width-16 staging into
// flat [128][32] LDS tiles with XOR bank swizzle; 4 waves (2x2), wave tile
// 64x64 = 4x4 mfma_f32_16x16x32_bf16.
// MODE 2: Cf32[idx] += acc
// MODE 5: combined pq|pk|v epilogue: bn 0-3 -> Cout=pq (exp(-|.|), Ncols=512);
//         bn 4 -> Cout2=pkv cols 0..127 (exp); bn 5 -> pkv cols 128..255 (plain)
// MODE 6: no C write; column sums over the 128-row tile -> atomicAdd pooled[b][col]
template<int MODE>
__global__ __launch_bounds__(256) void gemm128_kernel(
    const __hip_bfloat16* __restrict__ A, const __hip_bfloat16* __restrict__ Bt,
    void* __restrict__ Cout, __hip_bfloat16* __restrict__ Cout2,
    float* __restrict__ pooled, int gbase, int K, int Ncols)
{
    __shared__ __align__(16) char As[8192];   // bf16 [128 rows][32 k], swizzled chunks
    __shared__ __align__(16) char Bs[8192];

    const int tid = threadIdx.x;
    const int bm = blockIdx.x, bn = blockIdx.y;
    const int wave = tid >> 6, lane = tid & 63;
    const int quad = lane >> 4, lr = lane & 15;
    const int wm = (wave >> 1) << 6, wn = (wave & 1) << 6;

    // staging: wave w, instr t in {0,1}; LDS chunk idx = w*128 + t*64 + lane
    const int srow = (wave << 5) + (lane >> 2);          // row for t=0 (t=1: +16)
    const int scol = lane & 3;
    const int sfr  = (srow + (srow >> 2)) & 3;           // == f(srow+16)
    const int sofs = ((scol ^ sfr) << 3);                // swizzled global col (elements)

    const __hip_bfloat16* ga0 = A  + (size_t)(bm * 128 + srow) * K + sofs;
    const __hip_bfloat16* gb0 = Bt + (size_t)(bn * 128 + srow) * K + sofs;
    const __hip_bfloat16* ga1 = ga0 + (size_t)16 * K;
    const __hip_bfloat16* gb1 = gb0 + (size_t)16 * K;
    char* lA0 = As + (wave << 11);
    char* lA1 = lA0 + 1024;
    char* lB0 = Bs + (wave << 11);
    char* lB1 = lB0 + 1024;

    // fragment reads
    const int fl  = (lr + (lr >> 2)) & 3;
    const int ac  = (quad ^ fl) << 4;
    const char* arp = As + ((wm + lr) << 6) + ac;
    const char* brp = Bs + ((wn + lr) << 6) + ac;

    f32x4 acc[4][4];
    #pragma unroll
    for (int i = 0; i < 4; ++i)
        #pragma unroll
        for (int j = 0; j < 4; ++j)
            #pragma unroll
            for (int r = 0; r < 4; ++r) acc[i][j][r] = 0.0f;

    for (int k0 = 0; k0 < K; k0 += 32) {
        __syncthreads();
        gload_lds16(ga0 + k0, lA0);
        gload_lds16(ga1 + k0, lA1);
        gload_lds16(gb0 + k0, lB0);
        gload_lds16(gb1 + k0, lB1);
        __syncthreads();

        bf16x8 af[4], bfr[4];
        #pragma unroll
        for (int i = 0; i < 4; ++i)
            af[i] = *(const bf16x8*)(arp + i * 1024);
        #pragma unroll
        for (int j = 0; j < 4; ++j)
            bfr[j] = *(const bf16x8*)(brp + j * 1024);
        #pragma unroll
        for (int i = 0; i < 4; ++i)
            #pragma unroll
            for (int j = 0; j < 4; ++j)
                acc[i][j] = __builtin_amdgcn_mfma_f32_16x16x32_bf16(af[i], bfr[j], acc[i][j], 0, 0, 0);
    }

    // C/D layout: col = lane&15, row = quad*4 + reg  [m89/m91]
    if (MODE == 6) {
        // column sums over this block's 128 rows; col = bn*128+wn+lr+j*16 (quad-pure)
        const int b = (gbase + bm * 128) >> 13;   // 128 | 8192 -> uniform per block
        #pragma unroll
        for (int j = 0; j < 4; ++j) {
            float s = 0.f;
            #pragma unroll
            for (int i = 0; i < 4; ++i)
                #pragma unroll
                for (int r = 0; r < 4; ++r) s += acc[i][j][r];
            s += __shfl_xor(s, 16, 64);
            s += __shfl_xor(s, 32, 64);
            if (quad == 0)
                atomicAdd(&pooled[b * 512 + bn * 128 + wn + lr + j * 16], s);
        }
        return;
    }

    const int col0 = bn * 128 + wn + lr;
    const int row0 = bm * 128 + wm + quad * 4;
    #pragma unroll
    for (int i = 0; i < 4; ++i)
        #pragma unroll
        for (int j = 0; j < 4; ++j) {
            const int col = col0 + j * 16;
            #pragma unroll
            for (int r = 0; r < 4; ++r) {
                const int row = row0 + i * 16 + r;
                const float v = acc[i][j][r];
                if (MODE == 2) {
                    ((float*)Cout)[(size_t)row * Ncols + col] += v;
                } else {   // MODE 5
                    if (bn < 4) {
                        ((__hip_bfloat16*)Cout)[(size_t)row * 512 + col] =
                            f2bf(expf(-fabsf(v)));
                    } else {
                        const int c2 = col - 512;   // 0..255
                        Cout2[(size_t)row * 256 + c2] =
                            f2bf(bn == 4 ? expf(-fabsf(v)) : v);
                    }
                }
            }
        }
}

// ---------------- fused SwiGLU up-GEMM: t = silu(A@Wg^T) * (A@Wu^T) ----------------
__global__ __launch_bounds__(256, 2) void gemm_ffn_kernel(
    const __hip_bfloat16* __restrict__ A, const __hip_bfloat16* __restrict__ Bg,
    const __hip_bfloat16* __restrict__ Bu, __hip_bfloat16* __restrict__ Cout,
    int K, int Ncols)
{
    __shared__ __align__(16) char As[8192];
    __shared__ __align__(16) char Gs[8192];
    __shared__ __align__(16) char Us[8192];

    const int tid = threadIdx.x;
    const int bm = blockIdx.x, bn = blockIdx.y;
    const int wave = tid >> 6, lane = tid & 63;
    const int quad = lane >> 4, lr = lane & 15;
    const int wm = (wave >> 1) << 6, wn = (wave & 1) << 6;

    const int srow = (wave << 5) + (lane >> 2);
    const int scol = lane & 3;
    const int sfr  = (srow + (srow >> 2)) & 3;
    const int sofs = ((scol ^ sfr) << 3);

    const __hip_bfloat16* ga0 = A  + (size_t)(bm * 128 + srow) * K + sofs;
    const __hip_bfloat16* gg0 = Bg + (size_t)(bn * 128 + srow) * K + sofs;
    const __hip_bfloat16* gu0 = Bu + (size_t)(bn * 128 + srow) * K + sofs;
    const __hip_bfloat16* ga1 = ga0 + (size_t)16 * K;
    const __hip_bfloat16* gg1 = gg0 + (size_t)16 * K;
    const __hip_bfloat16* gu1 = gu0 + (size_t)16 * K;
    char* lA0 = As + (wave << 11);
    char* lG0 = Gs + (wave << 11);
    char* lU0 = Us + (wave << 11);

    const int fl  = (lr + (lr >> 2)) & 3;
    const int ac  = (quad ^ fl) << 4;
    const char* arp = As + ((wm + lr) << 6) + ac;
    const char* grp = Gs + ((wn + lr) << 6) + ac;
    const char* urp = Us + ((wn + lr) << 6) + ac;

    f32x4 accG[4][4], accU[4][4];
    #pragma unroll
    for (int i = 0; i < 4; ++i)
        #pragma unroll
        for (int j = 0; j < 4; ++j)
            #pragma unroll
            for (int r = 0; r < 4; ++r) { accG[i][j][r] = 0.0f; accU[i][j][r] = 0.0f; }

    for (int k0 = 0; k0 < K; k0 += 32) {
        __syncthreads();
        gload_lds16(ga0 + k0, lA0);
        gload_lds16(ga1 + k0, lA0 + 1024);
        gload_lds16(gg0 + k0, lG0);
        gload_lds16(gg1 + k0, lG0 + 1024);
        gload_lds16(gu0 + k0, lU0);
        gload_lds16(gu1 + k0, lU0 + 1024);
        __syncthreads();

        bf16x8 af[4], bgf[4], buf_[4];
        #pragma unroll
        for (int i = 0; i < 4; ++i)
            af[i] = *(const bf16x8*)(arp + i * 1024);
        #pragma unroll
        for (int j = 0; j < 4; ++j) {
            bgf[j]  = *(const bf16x8*)(grp + j * 1024);
            buf_[j] = *(const bf16x8*)(urp + j * 1024);
        }
        #pragma unroll
        for (int i = 0; i < 4; ++i)
            #pragma unroll
            for (int j = 0; j < 4; ++j) {
                accG[i][j] = __builtin_amdgcn_mfma_f32_16x16x32_bf16(af[i], bgf[j],  accG[i][j], 0, 0, 0);
                accU[i][j] = __builtin_amdgcn_mfma_f32_16x16x32_bf16(af[i], buf_[j], accU[i][j], 0, 0, 0);
            }
    }

    const int col0 = bn * 128 + wn + lr;
    const int row0 = bm * 128 + wm + quad * 4;
    #pragma unroll
    for (int i = 0; i < 4; ++i)
        #pragma unroll
        for (int j = 0; j < 4; ++j) {
            const int col = col0 + j * 16;
            #pragma unroll
            for (int r = 0; r < 4; ++r) {
                const int row = row0 + i * 16 + r;
                const float g = accG[i][j][r];
                const float s = g / (1.0f + expf(-g));   // silu(g) from f32 acc
                Cout[(size_t)row * Ncols + col] = f2bf(s * accU[i][j][r]);
            }
        }
}

// ---------------- kv / z global-state reduction (pkv [C][256] input) ----------------
__global__ __launch_bounds__(256) void kv_z_kernel(
    const __hip_bfloat16* __restrict__ pkv,
    float* __restrict__ kv, float* __restrict__ z, int gbase, int nrows)
{
    __shared__ float pks[8][64], vs[8][64];
    const int slab = blockIdx.x, kh = blockIdx.y;
    const int b = (gbase + slab * nrows) >> 13;   // nrows | 8192 -> uniform per block
    const int tid = threadIdx.x;
    const int tm = (tid & 15) << 2, tdh = (tid >> 4) << 2;
    const int lss = tid >> 5, lmm = (tid & 31) << 1;

    float acc[4][4] = {};
    float zacc[4] = {};
    for (int sb = 0; sb < nrows; sb += 8) {
        __syncthreads();
        {
            const size_t n = (size_t)slab * nrows + sb + lss;   // local row
            const __hip_bfloat16* pr = pkv + n * 256 + kh * 64 + lmm;        // pk cols 0..127
            const __hip_bfloat16* vr = pkv + n * 256 + 128 + kh * 64 + lmm;  // v  cols 128..255
            pks[lss][lmm]     = bf2f(pr[0]);
            pks[lss][lmm + 1] = bf2f(pr[1]);
            vs[lss][lmm]      = bf2f(vr[0]);
            vs[lss][lmm + 1]  = bf2f(vr[1]);
        }
        __syncthreads();
        #pragma unroll
        for (int ss = 0; ss < 8; ++ss) {
            f32x4 p = *(const f32x4*)&pks[ss][tm];
            f32x4 w = *(const f32x4*)&vs[ss][tdh];
            #pragma unroll
            for (int i = 0; i < 4; ++i)
                #pragma unroll
                for (int j = 0; j < 4; ++j)
                    acc[i][j] += p[i] * w[j];
            if ((tid >> 4) == 0) {
                #pragma unroll
                for (int i = 0; i < 4; ++i) zacc[i] += p[i];
            }
        }
    }
    #pragma unroll
    for (int i = 0; i < 4; ++i)
        #pragma unroll
        for (int j = 0; j < 4; ++j)
            atomicAdd(&kv[(((size_t)b * 2 + kh) * 64 + tm + i) * 64 + tdh + j], acc[i][j]);
    if ((tid >> 4) == 0) {
        #pragma unroll
        for (int i = 0; i < 4; ++i)
            atomicAdd(&z[((size_t)b * 2 + kh) * 64 + tm + i], zacc[i]);
    }
}

// ---------------- attention mix (MFMA): attn = (pq @ kv) / (pq @ z + eps) ----------------
__global__ __launch_bounds__(256) void attn_mix_kernel(
    const __hip_bfloat16* __restrict__ pq, const float* __restrict__ kvf,
    const float* __restrict__ zf, __hip_bfloat16* __restrict__ attn, int gbase)
{
    __shared__ __align__(16) __hip_bfloat16 kvT[80][72];
    const int kh = blockIdx.y;
    const int row0b = blockIdx.x * 128;
    const int b = (gbase + row0b) >> 13;
    const int tid = threadIdx.x;

    const float* kvsrc = kvf + ((size_t)b * 2 + kh) * 4096;
    for (int i = tid; i < 4096; i += 256) {
        const int m = i >> 6, dh = i & 63;
        kvT[dh][m] = f2bf(kvsrc[i]);
    }
    if (tid < 64) kvT[64][tid] = f2bf(zf[((size_t)b * 2 + kh) * 64 + tid]);
    for (int i = tid; i < 15 * 64; i += 256) {
        const int rr = 65 + (i >> 6), m = i & 63;
        kvT[rr][m] = f2bf(0.0f);
    }
    __syncthreads();

    const int wave = tid >> 6, lane = tid & 63;
    const int quad = lane >> 4, lr = lane & 15;
    const int wm = (wave >> 1) << 6;
    const int whead = (wave & 1) << 1;

    #pragma unroll
    for (int g2 = 0; g2 < 2; ++g2) {
        const int hh = kh * 4 + whead + g2;
        f32x4 acc[4][5];
        #pragma unroll
        for (int i = 0; i < 4; ++i)
            #pragma unroll
            for (int j = 0; j < 5; ++j)
                #pragma unroll
                for (int r = 0; r < 4; ++r) acc[i][j][r] = 0.0f;

        #pragma unroll
        for (int kk = 0; kk < 2; ++kk) {
            const int kofs = kk * 32 + quad * 8;
            bf16x8 af[4], bfr[5];
            #pragma unroll
            for (int i = 0; i < 4; ++i)
                af[i] = *(const bf16x8*)(pq + (size_t)(row0b + wm + i * 16 + lr) * 512
                                            + hh * 64 + kofs);
            #pragma unroll
            for (int j = 0; j < 5; ++j)
                bfr[j] = *(const bf16x8*)&kvT[j * 16 + lr][kofs];
            #pragma unroll
            for (int i = 0; i < 4; ++i)
                #pragma unroll
                for (int j = 0; j < 5; ++j)
                    acc[i][j] = __builtin_amdgcn_mfma_f32_16x16x32_bf16(af[i], bfr[j], acc[i][j], 0, 0, 0);
        }

        const int colb = hh * 64;
        #pragma unroll
        for (int i = 0; i < 4; ++i) {
            const int rowb = row0b + wm + i * 16 + quad * 4;
            #pragma unroll
            for (int r = 0; r < 4; ++r) {
                const float den = __shfl(acc[i][4][r], lane & 48, 64);
                const float inv = 1.0f / (den + 1e-6f);
                const size_t base = (size_t)(rowb + r) * 512 + colb;
                #pragma unroll
                for (int j = 0; j < 4; ++j)
                    attn[base + j * 16 + lr] = f2bf(acc[i][j][r] * inv);
            }
        }
    }
}

// ---------------- mean pool accumulate (x1 contribution) ----------------
__global__ __launch_bounds__(256) void pool_kernel(
    const float* __restrict__ xf, float* __restrict__ pooled, int gbase)
{
    const int row0 = blockIdx.x * 256;
    const int b = (gbase + row0) >> 13;
    const int t = threadIdx.x;
    float a0 = 0.f, a1 = 0.f;
    const size_t base = (size_t)row0 * 512;
    for (int s = 0; s < 256; ++s) {
        a0 += xf[base + (size_t)s * 512 + t];
        a1 += xf[base + (size_t)s * 512 + t + 256];
    }
    atomicAdd(&pooled[b * 512 + t], a0);
    atomicAdd(&pooled[b * 512 + t + 256], a1);
}

// ---------------- classifier head ----------------
__global__ __launch_bounds__(256) void head_kernel(
    const float* __restrict__ pooled, const void* __restrict__ Wc,
    const void* __restrict__ bc, void* __restrict__ out, const int* __restrict__ flag)
{
    const int f = *flag;
    const int t = threadIdx.x;
    const int grp = t >> 4, ln = t & 15;
    const int b = grp >> 1, c = grp & 1;
    float p = 0.f;
    for (int d = ln; d < 512; d += 16)
        p += pooled[b * 512 + d] * loadElem(Wc, (size_t)d * 2 + c, f);
    #pragma unroll
    for (int off = 8; off; off >>= 1) p += __shfl_xor(p, off, 64);
    if (ln == 0) {
        const float val = p * (1.0f / 8192.0f) + loadElem(bc, c, f);
        if (f) ((float*)out)[b * 2 + c] = val;
        else   ((__hip_bfloat16*)out)[b * 2 + c] = f2bf(val);
    }
}

// ---------------- launch ----------------
extern "C" void kernel_launch(void* const* d_in, const int* in_sizes, int n_in,
                              void* d_out, int out_size, void* d_ws, size_t ws_size,
                              hipStream_t stream)
{
    const int* ids   = (const int*)d_in[0];
    const void* emb  = d_in[1];
    const void* Wq   = d_in[2];
    const void* Wk   = d_in[3];
    const void* Wv   = d_in[4];
    const void* Wph  = d_in[5];
    const void* Wo   = d_in[6];
    const void* g1   = d_in[7];
    const void* g2   = d_in[8];
    const void* Wg   = d_in[9];
    const void* Wu   = d_in[10];
    const void* Wd   = d_in[11];
    const void* Wc   = d_in[12];
    const void* bc   = d_in[13];

    char* ws = (char*)d_ws;
    __hip_bfloat16* WQPt  = (__hip_bfloat16*)(ws + OFF_WQPT);  // [WQPt|WKPt|WvT] = [768][512]
    __hip_bfloat16* WKPt  = (__hip_bfloat16*)(ws + OFF_WKPT);
    __hip_bfloat16* WvT   = (__hip_bfloat16*)(ws + OFF_WVT);
    __hip_bfloat16* WoT   = (__hip_bfloat16*)(ws + OFF_WOT);
    __hip_bfloat16* WgT   = (__hip_bfloat16*)(ws + OFF_WGT);
    __hip_bfloat16* WuT   = (__hip_bfloat16*)(ws + OFF_WUT);
    __hip_bfloat16* WdT   = (__hip_bfloat16*)(ws + OFF_WDT);
    float*          kv    = (float*)(ws + OFF_KV);
    float*          z     = (float*)(ws + OFF_Z);
    float*          pooled= (float*)(ws + OFF_POOL);
    int*            flag  = (int*)(ws + OFF_FLAG);
    __hip_bfloat16* pqall = (__hip_bfloat16*)(ws + OFF_PQALL); // bf16 [NTOK][512]

    // ---- adaptive chunk: largest power-of-2 C in [256, 16384] that fits ws ----
    int C = 16384;
    while (C > 256 && CHUNKBASE + PERTOK * (size_t)C > ws_size) C >>= 1;
    const int NC = NTOK / C;

    char* cb = ws + CHUNKBASE;
    float*          xf   = (float*)cb;                                  // f32  [C][512]
    __hip_bfloat16* h    = (__hip_bfloat16*)(cb + (size_t)C * 2048);    // bf16 [C][512]
    __hip_bfloat16* attn = (__hip_bfloat16*)(cb + (size_t)C * 3072);    // bf16 [C][512]
    __hip_bfloat16* pkv  = (__hip_bfloat16*)(cb + (size_t)C * 4096);    // bf16 [C][256]  pk|v
    __hip_bfloat16* tbuf = (__hip_bfloat16*)(cb + (size_t)C * 4608);    // bf16 [C][2048]

    detect_kernel<<<1, 128, 0, stream>>>((const unsigned int*)Wph, flag);
    zero_kernel<<<(ZERO_FLOATS + 255) / 256, 256, 0, stream>>>(kv, ZERO_FLOATS);

    // weight prep
    fuse_phi_kernel<<<1024, 256, 0, stream>>>(Wq, Wph, WQPt, 512, flag);
    fuse_phi_kernel<<<256, 256, 0, stream>>>(Wk, Wph, WKPt, 128, flag);
    transpose_kernel<<<dim3(128 / 32, 512 / 32), 256, 0, stream>>>(Wv, WvT, 512, 128, flag);
    transpose_kernel<<<dim3(512 / 32, 512 / 32), 256, 0, stream>>>(Wo, WoT, 512, 512, flag);
    transpose_kernel<<<dim3(2048 / 32, 512 / 32), 256, 0, stream>>>(Wg, WgT, 512, 2048, flag);
    transpose_kernel<<<dim3(2048 / 32, 512 / 32), 256, 0, stream>>>(Wu, WuT, 512, 2048, flag);
    transpose_kernel<<<dim3(512 / 32, 2048 / 32), 256, 0, stream>>>(Wd, WdT, 2048, 512, flag);

    // ---- pass A: pq (all tokens) + per-chunk pk|v -> accumulate global kv / z ----
    for (int c = 0; c < NC; ++c) {
        const int g0 = c * C;
        embed_rms_kernel<<<C / 4, 256, 0, stream>>>(ids + g0, emb, g1, xf, h, flag, 0, 1);
        // combined [pq | pk | v] GEMM: B = [WQPt;WKPt;WvT] rows 0..767
        gemm128_kernel<5><<<dim3(C / 128, 6), 256, 0, stream>>>(
            h, WQPt, pqall + (size_t)g0 * 512, pkv, nullptr, g0, 512, 512);
        kv_z_kernel<<<dim3(C / 128, 2), 256, 0, stream>>>(pkv, kv, z, g0, 128);
    }

    // ---- pass B: per chunk -> mix, +Wo, pool(x1)+rms, fused SwiGLU, Wd->pool ----
    for (int c = 0; c < NC; ++c) {
        const int g0 = c * C;
        embed_rms_kernel<<<C / 4, 256, 0, stream>>>(ids + g0, emb, g1, xf, h, flag, 1, 0);
        attn_mix_kernel<<<dim3(C / 128, 2), 256, 0, stream>>>(
            pqall + (size_t)g0 * 512, kv, z, attn, g0);
        gemm128_kernel<2><<<dim3(C / 128, 4), 256, 0, stream>>>(
            attn, WoT, xf, nullptr, nullptr, g0, 512, 512);
        pool_kernel<<<C / 256, 256, 0, stream>>>(xf, pooled, g0);       // x1 contribution
        rms2_kernel<<<C / 4, 256, 0, stream>>>(xf, g2, h, flag);
        dim3 gg(C / 128, 16);
        gemm_ffn_kernel<<<gg, 256, 0, stream>>>(h, WgT, WuT, tbuf, 512, 2048);
        // Wd GEMM fused with pool: column-sums of (tbuf @ Wd) -> pooled
        gemm128_kernel<6><<<dim3(C / 128, 4), 256, 0, stream>>>(
            tbuf, WdT, nullptr, nullptr, pooled, g0, 2048, 512);
    }

    head_kernel<<<1, 256, 0, stream>>>(pooled, Wc, bc, d_out, flag);
}

// Round 9
// 1305.325 us; speedup vs baseline: 2.3913x; 1.0015x over previous
//
#include <hip/hip_runtime.h>
#include <hip/hip_bf16.h>
#include <math.h>

// ---------------- types / helpers ----------------
typedef __attribute__((ext_vector_type(8))) short bf16x8;
typedef __attribute__((ext_vector_type(4))) float f32x4;

#define DEV static __device__ __forceinline__
#define AS1 __attribute__((address_space(1)))
#define AS3 __attribute__((address_space(3)))

DEV float bf2f(__hip_bfloat16 v) { return __bfloat162float(v); }
DEV __hip_bfloat16 f2bf(float f) { return __float2bfloat16(f); }
DEV float us2f(unsigned short u) { return __uint_as_float(((unsigned int)u) << 16); }
DEV unsigned short f2us(float f) {
    __hip_bfloat16 b = __float2bfloat16(f);
    return *(unsigned short*)&b;
}

// async global->LDS, 16 B per lane (LDS dst = wave-uniform base + lane*16)
DEV void gload_lds16(const void* g, void* l) {
    __builtin_amdgcn_global_load_lds((const AS1 unsigned int*)g,
                                     (AS3 unsigned int*)l, 16, 0, 0);
}

// load 8 consecutive floats from an input tensor that is either f32 or bf16
DEV void load8(const void* p, size_t off, int f32m, float* o) {
    if (f32m) {
        const float4* r = (const float4*)((const float*)p + off);
        float4 A = r[0], B = r[1];
        o[0] = A.x; o[1] = A.y; o[2] = A.z; o[3] = A.w;
        o[4] = B.x; o[5] = B.y; o[6] = B.z; o[7] = B.w;
    } else {
        const ushort4* r = (const ushort4*)((const __hip_bfloat16*)p + off);
        ushort4 A = r[0], B = r[1];
        o[0] = us2f(A.x); o[1] = us2f(A.y); o[2] = us2f(A.z); o[3] = us2f(A.w);
        o[4] = us2f(B.x); o[5] = us2f(B.y); o[6] = us2f(B.z); o[7] = us2f(B.w);
    }
}

DEV float loadElem(const void* p, size_t idx, int f32m) {
    return f32m ? ((const float*)p)[idx] : bf2f(((const __hip_bfloat16*)p)[idx]);
}

// ---------------- problem constants ----------------
// B=8 S=8192 D=512 H=8 HK=2 DH=64 M=64 DFF=2048 NCLS=2 G=4
constexpr int NTOK = 65536;   // 8*8192

// ---------------- persistent ws layout (bytes) ----------------
constexpr size_t OFF_WQPT = 0;                       // bf16 [512][512]  (Wq@Wphi)^T
constexpr size_t OFF_WKPT = OFF_WQPT + 524288ull;    // bf16 [128][512]  (Wk@Wphi)^T   } contiguous:
constexpr size_t OFF_WVT  = OFF_WKPT + 131072ull;    // bf16 [128][512]  Wv^T          } [768][512] B-matrix
constexpr size_t OFF_WOT  = OFF_WVT  + 131072ull;    // bf16 [512][512]  Wo^T
constexpr size_t OFF_WGT  = OFF_WOT  + 524288ull;    // bf16 [2048][512] Wg^T
constexpr size_t OFF_WUT  = OFF_WGT  + 2097152ull;   // bf16 [2048][512] Wu^T
constexpr size_t OFF_KV   = OFF_WUT  + 2097152ull;   // f32  [8][2][64][64]
constexpr size_t OFF_Z    = OFF_KV   + 262144ull;    // f32  [8][2][64]
constexpr size_t OFF_POOL = OFF_Z    + 4096ull;      // f32  [8][512]
constexpr size_t OFF_TSUM = OFF_POOL + 16384ull;     // f32  [8][2048]  col-sums of FFN t
constexpr size_t OFF_FLAG = OFF_TSUM + 65536ull;     // int  dtype flag (1 = f32 inputs)
constexpr size_t PERSIST  = OFF_FLAG + 256ull;
constexpr size_t OFF_PQALL = PERSIST;                // bf16 [65536][512] pq (all tokens)
constexpr size_t PQALL_SZ  = 67108864ull;
constexpr size_t CHUNKBASE = OFF_PQALL + PQALL_SZ;
constexpr int    ZERO_FLOATS = (262144 + 4096 + 16384 + 65536) / 4;  // kv+z+pooled+tsum
// per-token chunk bytes: xf 2048 + h 1024 + attn 1024 + pkv 512 = 4608
constexpr size_t PERTOK = 4608ull;
// ws check: rounds 3-6 ran C=16384 at PERTOK=13824 => ws >= 234.4 MB;
// C=32768 here needs 75.1 MB + 151.0 MB = 226.1 MB -> fits (runtime-checked anyway).

// ---------------- dtype detection ----------------
__global__ __launch_bounds__(128) void detect_kernel(
    const unsigned int* __restrict__ w, int* __restrict__ flag)
{
    __shared__ int cnt;
    if (threadIdx.x == 0) cnt = 0;
    __syncthreads();
    unsigned int v = w[threadIdx.x];
    float a = fabsf(us2f((unsigned short)(v & 0xFFFFu)));
    if (a >= 0.0625f && a <= 8.0f) atomicAdd(&cnt, 1);
    __syncthreads();
    if (threadIdx.x == 0) *flag = (cnt < 64) ? 1 : 0;
}

// ---------------- tiny init ----------------
__global__ __launch_bounds__(256) void zero_kernel(float* __restrict__ p, int n)
{
    int i = blockIdx.x * 256 + threadIdx.x;
    if (i < n) p[i] = 0.0f;
}

// ---------------- weight prep ----------------
// outT[hm][d] = sum_dh W[d][h*64+dh] * Wphi[dh][m]   (hm = h*64+m), row-major [nh*64][512]
__global__ __launch_bounds__(256) void fuse_phi_kernel(
    const void* __restrict__ W, const void* __restrict__ Wphi,
    __hip_bfloat16* __restrict__ outT, int wld, const int* __restrict__ flag)
{
    const int f = *flag;
    int o = blockIdx.x * 256 + threadIdx.x;   // o = hm*512 + d
    int hm = o >> 9, d = o & 511;
    int h = hm >> 6, m = hm & 63;
    float acc = 0.f;
    if (f) {
        const float* Wf = (const float*)W;
        const float* Pf = (const float*)Wphi;
        #pragma unroll 8
        for (int dh = 0; dh < 64; ++dh)
            acc += Wf[(size_t)d * wld + h * 64 + dh] * Pf[dh * 64 + m];
    } else {
        const __hip_bfloat16* Wb = (const __hip_bfloat16*)W;
        const __hip_bfloat16* Pb = (const __hip_bfloat16*)Wphi;
        #pragma unroll 8
        for (int dh = 0; dh < 64; ++dh)
            acc += bf2f(Wb[(size_t)d * wld + h * 64 + dh]) * bf2f(Pb[dh * 64 + m]);
    }
    outT[o] = f2bf(acc);
}

// dst[Ccols][R] = src[R][Ccols]^T, LDS-tiled 32x32 (R, Ccols multiples of 32)
__global__ __launch_bounds__(256) void transpose_kernel(
    const void* __restrict__ src, __hip_bfloat16* __restrict__ dst, int R, int Ccols,
    const int* __restrict__ flag)
{
    __shared__ float tile[32][33];
    const int f = *flag;
    const int tx = threadIdx.x & 31, ty = threadIdx.x >> 5;   // 32 x 8
    const int c0 = blockIdx.x * 32, r0 = blockIdx.y * 32;
    #pragma unroll
    for (int k = 0; k < 4; ++k) {
        const int rl = ty + k * 8;
        tile[rl][tx] = loadElem(src, (size_t)(r0 + rl) * Ccols + c0 + tx, f);
    }
    __syncthreads();
    #pragma unroll
    for (int k = 0; k < 4; ++k) {
        const int cl = ty + k * 8;
        dst[(size_t)(c0 + cl) * R + r0 + tx] = f2bf(tile[tx][cl]);
    }
}

// ---------------- embedding gather + rmsnorm (wave per row; chunk-local) ----------------
__global__ __launch_bounds__(256) void embed_rms_kernel(
    const int* __restrict__ ids, const void* __restrict__ emb,
    const void* __restrict__ g1, float* __restrict__ xf,
    __hip_bfloat16* __restrict__ h, const int* __restrict__ flag,
    int write_xf, int write_h)
{
    const int f = *flag;
    const int n = blockIdx.x * 4 + (threadIdx.x >> 6);   // local row in chunk
    const int lane = threadIdx.x & 63;
    const int id = ids[n];
    float x[8];
    load8(emb, (size_t)id * 512 + lane * 8, f, x);
    float ss = 0.f;
    #pragma unroll
    for (int i = 0; i < 8; ++i) ss += x[i] * x[i];
    #pragma unroll
    for (int off = 32; off; off >>= 1) ss += __shfl_xor(ss, off, 64);
    const float scale = rsqrtf(ss * (1.0f / 512.0f) + 1e-6f);

    if (write_xf) {
        float4* xo = (float4*)(xf + (size_t)n * 512 + lane * 8);
        xo[0] = make_float4(x[0], x[1], x[2], x[3]);
        xo[1] = make_float4(x[4], x[5], x[6], x[7]);
    }
    if (write_h) {
        float gv[8];
        load8(g1, (size_t)lane * 8, f, gv);
        ushort4 h0, h1;
        h0.x = f2us(x[0] * scale * gv[0]); h0.y = f2us(x[1] * scale * gv[1]);
        h0.z = f2us(x[2] * scale * gv[2]); h0.w = f2us(x[3] * scale * gv[3]);
        h1.x = f2us(x[4] * scale * gv[4]); h1.y = f2us(x[5] * scale * gv[5]);
        h1.z = f2us(x[6] * scale * gv[6]); h1.w = f2us(x[7] * scale * gv[7]);
        ushort4* ho = (ushort4*)(h + (size_t)n * 512 + lane * 8);
        ho[0] = h0; ho[1] = h1;
    }
}

// ---------------- rmsnorm from f32 residual (chunk-local) ----------------
__global__ __launch_bounds__(256) void rms2_kernel(
    const float* __restrict__ xf, const void* __restrict__ g2,
    __hip_bfloat16* __restrict__ h, const int* __restrict__ flag)
{
    const int f = *flag;
    const int n = blockIdx.x * 4 + (threadIdx.x >> 6);
    const int lane = threadIdx.x & 63;
    const float4* xr = (const float4*)(xf + (size_t)n * 512);
    float4 a = xr[lane * 2], b = xr[lane * 2 + 1];
    float x[8] = { a.x, a.y, a.z, a.w, b.x, b.y, b.z, b.w };
    float ss = 0.f;
    #pragma unroll
    for (int i = 0; i < 8; ++i) ss += x[i] * x[i];
    #pragma unroll
    for (int off = 32; off; off >>= 1) ss += __shfl_xor(ss, off, 64);
    const float scale = rsqrtf(ss * (1.0f / 512.0f) + 1e-6f);

    float gv[8];
    load8(g2, (size_t)lane * 8, f, gv);
    ushort4 h0, h1;
    h0.x = f2us(x[0] * scale * gv[0]); h0.y = f2us(x[1] * scale * gv[1]);
    h0.z = f2us(x[2] * scale * gv[2]); h0.w = f2us(x[3] * scale * gv[3]);
    h1.x = f2us(x[4] * scale * gv[4]); h1.y = f2us(x[5] * scale * gv[5]);
    h1.z = f2us(x[6] * scale * gv[6]); h1.w = f2us(x[7] * scale * gv[7]);
    ushort4* ho = (ushort4*)(h + (size_t)n * 512 + lane * 8);
    ho[0] = h0; ho[1] = h1;
}

// ---------------- MFMA GEMM: C[M,N] = A[M,K] @ Bt[N,K]^T ----------------
// m97 structure: 128x128 tile, BK=32, global_load_lds width-16 staging into
// flat [128][32] LDS tiles with XOR bank swizzle; 4 waves (2x2), wave tile
// 64x64 = 4x4 mfma_f32_16x16x32_bf16.
// MODE 2: Cf32[idx] += acc
// MODE 5: combined pq|pk|v epilogue: bn 0-3 -> Cout=pq (exp(-|.|), Ncols=512);
//         bn 4 -> Cout2=pkv cols 0..127 (exp); bn 5 -> pkv cols 128..255 (plain)
template<int MODE>
__global__ __launch_bounds__(256) void gemm128_kernel(
    const __hip_bfloat16* __restrict__ A, const __hip_bfloat16* __restrict__ Bt,
    void* __restrict__ Cout, __hip_bfloat16* __restrict__ Cout2, int K, int Ncols)
{
    __shared__ __align__(16) char As[8192];   // bf16 [128 rows][32 k], swizzled chunks
    __shared__ __align__(16) char Bs[8192];

    const int tid = threadIdx.x;
    const int bm = blockIdx.x, bn = blockIdx.y;
    const int wave = tid >> 6, lane = tid & 63;
    const int quad = lane >> 4, lr = lane & 15;
    const int wm = (wave >> 1) << 6, wn = (wave & 1) << 6;

    // staging: wave w, instr t in {0,1}; LDS chunk idx = w*128 + t*64 + lane
    const int srow = (wave << 5) + (lane >> 2);          // row for t=0 (t=1: +16)
    const int scol = lane & 3;
    const int sfr  = (srow + (srow >> 2)) & 3;           // == f(srow+16)
    const int sofs = ((scol ^ sfr) << 3);                // swizzled global col (elements)

    const __hip_bfloat16* ga0 = A  + (size_t)(bm * 128 + srow) * K + sofs;
    const __hip_bfloat16* gb0 = Bt + (size_t)(bn * 128 + srow) * K + sofs;
    const __hip_bfloat16* ga1 = ga0 + (size_t)16 * K;
    const __hip_bfloat16* gb1 = gb0 + (size_t)16 * K;
    char* lA0 = As + (wave << 11);
    char* lA1 = lA0 + 1024;
    char* lB0 = Bs + (wave << 11);
    char* lB1 = lB0 + 1024;

    // fragment reads
    const int fl  = (lr + (lr >> 2)) & 3;
    const int ac  = (quad ^ fl) << 4;
    const char* arp = As + ((wm + lr) << 6) + ac;
    const char* brp = Bs + ((wn + lr) << 6) + ac;

    f32x4 acc[4][4];
    #pragma unroll
    for (int i = 0; i < 4; ++i)
        #pragma unroll
        for (int j = 0; j < 4; ++j)
            #pragma unroll
            for (int r = 0; r < 4; ++r) acc[i][j][r] = 0.0f;

    for (int k0 = 0; k0 < K; k0 += 32) {
        __syncthreads();
        gload_lds16(ga0 + k0, lA0);
        gload_lds16(ga1 + k0, lA1);
        gload_lds16(gb0 + k0, lB0);
        gload_lds16(gb1 + k0, lB1);
        __syncthreads();

        bf16x8 af[4], bfr[4];
        #pragma unroll
        for (int i = 0; i < 4; ++i)
            af[i] = *(const bf16x8*)(arp + i * 1024);
        #pragma unroll
        for (int j = 0; j < 4; ++j)
            bfr[j] = *(const bf16x8*)(brp + j * 1024);
        #pragma unroll
        for (int i = 0; i < 4; ++i)
            #pragma unroll
            for (int j = 0; j < 4; ++j)
                acc[i][j] = __builtin_amdgcn_mfma_f32_16x16x32_bf16(af[i], bfr[j], acc[i][j], 0, 0, 0);
    }

    // C/D layout: col = lane&15, row = quad*4 + reg  [m89/m91]
    const int col0 = bn * 128 + wn + lr;
    const int row0 = bm * 128 + wm + quad * 4;
    #pragma unroll
    for (int i = 0; i < 4; ++i)
        #pragma unroll
        for (int j = 0; j < 4; ++j) {
            const int col = col0 + j * 16;
            #pragma unroll
            for (int r = 0; r < 4; ++r) {
                const int row = row0 + i * 16 + r;
                const float v = acc[i][j][r];
                if (MODE == 2) {
                    ((float*)Cout)[(size_t)row * Ncols + col] += v;
                } else {   // MODE 5
                    if (bn < 4) {
                        ((__hip_bfloat16*)Cout)[(size_t)row * 512 + col] =
                            f2bf(expf(-fabsf(v)));
                    } else {
                        const int c2 = col - 512;   // 0..255
                        Cout2[(size_t)row * 256 + c2] =
                            f2bf(bn == 4 ? expf(-fabsf(v)) : v);
                    }
                }
            }
        }
}

// ---------------- fused SwiGLU up-GEMM + column-sum ----------------
// t = silu(A@Wg^T) * (A@Wu^T); no t materialization — accumulate column sums
// of t (per batch) into tsum[b][2048]:  sum_rows(t@Wd) == (sum_rows t)@Wd.
__global__ __launch_bounds__(256, 2) void gemm_ffn_kernel(
    const __hip_bfloat16* __restrict__ A, const __hip_bfloat16* __restrict__ Bg,
    const __hip_bfloat16* __restrict__ Bu, float* __restrict__ tsum,
    int gbase, int K)
{
    __shared__ __align__(16) char As[8192];
    __shared__ __align__(16) char Gs[8192];
    __shared__ __align__(16) char Us[8192];

    const int tid = threadIdx.x;
    const int bm = blockIdx.x, bn = blockIdx.y;
    const int wave = tid >> 6, lane = tid & 63;
    const int quad = lane >> 4, lr = lane & 15;
    const int wm = (wave >> 1) << 6, wn = (wave & 1) << 6;

    const int srow = (wave << 5) + (lane >> 2);
    const int scol = lane & 3;
    const int sfr  = (srow + (srow >> 2)) & 3;
    const int sofs = ((scol ^ sfr) << 3);

    const __hip_bfloat16* ga0 = A  + (size_t)(bm * 128 + srow) * K + sofs;
    const __hip_bfloat16* gg0 = Bg + (size_t)(bn * 128 + srow) * K + sofs;
    const __hip_bfloat16* gu0 = Bu + (size_t)(bn * 128 + srow) * K + sofs;
    const __hip_bfloat16* ga1 = ga0 + (size_t)16 * K;
    const __hip_bfloat16* gg1 = gg0 + (size_t)16 * K;
    const __hip_bfloat16* gu1 = gu0 + (size_t)16 * K;
    char* lA0 = As + (wave << 11);
    char* lG0 = Gs + (wave << 11);
    char* lU0 = Us + (wave << 11);

    const int fl  = (lr + (lr >> 2)) & 3;
    const int ac  = (quad ^ fl) << 4;
    const char* arp = As + ((wm + lr) << 6) + ac;
    const char* grp = Gs + ((wn + lr) << 6) + ac;
    const char* urp = Us + ((wn + lr) << 6) + ac;

    f32x4 accG[4][4], accU[4][4];
    #pragma unroll
    for (int i = 0; i < 4; ++i)
        #pragma unroll
        for (int j = 0; j < 4; ++j)
            #pragma unroll
            for (int r = 0; r < 4; ++r) { accG[i][j][r] = 0.0f; accU[i][j][r] = 0.0f; }

    for (int k0 = 0; k0 < K; k0 += 32) {
        __syncthreads();
        gload_lds16(ga0 + k0, lA0);
        gload_lds16(ga1 + k0, lA0 + 1024);
        gload_lds16(gg0 + k0, lG0);
        gload_lds16(gg1 + k0, lG0 + 1024);
        gload_lds16(gu0 + k0, lU0);
        gload_lds16(gu1 + k0, lU0 + 1024);
        __syncthreads();

        bf16x8 af[4], bgf[4], buf_[4];
        #pragma unroll
        for (int i = 0; i < 4; ++i)
            af[i] = *(const bf16x8*)(arp + i * 1024);
        #pragma unroll
        for (int j = 0; j < 4; ++j) {
            bgf[j]  = *(const bf16x8*)(grp + j * 1024);
            buf_[j] = *(const bf16x8*)(urp + j * 1024);
        }
        #pragma unroll
        for (int i = 0; i < 4; ++i)
            #pragma unroll
            for (int j = 0; j < 4; ++j) {
                accG[i][j] = __builtin_amdgcn_mfma_f32_16x16x32_bf16(af[i], bgf[j],  accG[i][j], 0, 0, 0);
                accU[i][j] = __builtin_amdgcn_mfma_f32_16x16x32_bf16(af[i], buf_[j], accU[i][j], 0, 0, 0);
            }
    }

    // epilogue: column sums of silu(G)*U over this block's 128 rows
    // col = bn*128 + wn + lr + j*16 (quad-pure); batch uniform per block.
    const int b = (gbase + bm * 128) >> 13;   // 128 | 8192
    #pragma unroll
    for (int j = 0; j < 4; ++j) {
        float s = 0.f;
        #pragma unroll
        for (int i = 0; i < 4; ++i)
            #pragma unroll
            for (int r = 0; r < 4; ++r) {
                const float g = accG[i][j][r];
                s += (g / (1.0f + expf(-g))) * accU[i][j][r];
            }
        s += __shfl_xor(s, 16, 64);
        s += __shfl_xor(s, 32, 64);
        if (quad == 0)
            atomicAdd(&tsum[b * 2048 + bn * 128 + wn + lr + j * 16], s);
    }
}

// ---------------- tiny: pooled[b][:] += tsum[b][:] @ Wd ----------------
__global__ __launch_bounds__(256) void ffn_pool_kernel(
    const float* __restrict__ tsum, const void* __restrict__ Wd,
    float* __restrict__ pooled, const int* __restrict__ flag)
{
    const int f = *flag;
    const int o = blockIdx.x * 256 + threadIdx.x;   // 16 blocks x 256 = 4096 outputs
    const int b = o >> 9, d = o & 511;
    float acc = 0.f;
    for (int k = 0; k < 2048; ++k)
        acc += tsum[b * 2048 + k] * loadElem(Wd, (size_t)k * 512 + d, f);
    pooled[b * 512 + d] += acc;   // stream-ordered single writer
}

// ---------------- kv / z global-state reduction (pkv [C][256] input) ----------------
__global__ __launch_bounds__(256) void kv_z_kernel(
    const __hip_bfloat16* __restrict__ pkv,
    float* __restrict__ kv, float* __restrict__ z, int gbase, int nrows)
{
    __shared__ float pks[8][64], vs[8][64];
    const int slab = blockIdx.x, kh = blockIdx.y;
    const int b = (gbase + slab * nrows) >> 13;   // nrows | 8192 -> uniform per block
    const int tid = threadIdx.x;
    const int tm = (tid & 15) << 2, tdh = (tid >> 4) << 2;
    const int lss = tid >> 5, lmm = (tid & 31) << 1;

    float acc[4][4] = {};
    float zacc[4] = {};
    for (int sb = 0; sb < nrows; sb += 8) {
        __syncthreads();
        {
            const size_t n = (size_t)slab * nrows + sb + lss;   // local row
            const __hip_bfloat16* pr = pkv + n * 256 + kh * 64 + lmm;        // pk cols 0..127
            const __hip_bfloat16* vr = pkv + n * 256 + 128 + kh * 64 + lmm;  // v  cols 128..255
            pks[lss][lmm]     = bf2f(pr[0]);
            pks[lss][lmm + 1] = bf2f(pr[1]);
            vs[lss][lmm]      = bf2f(vr[0]);
            vs[lss][lmm + 1]  = bf2f(vr[1]);
        }
        __syncthreads();
        #pragma unroll
        for (int ss = 0; ss < 8; ++ss) {
            f32x4 p = *(const f32x4*)&pks[ss][tm];
            f32x4 w = *(const f32x4*)&vs[ss][tdh];
            #pragma unroll
            for (int i = 0; i < 4; ++i)
                #pragma unroll
                for (int j = 0; j < 4; ++j)
                    acc[i][j] += p[i] * w[j];
            if ((tid >> 4) == 0) {
                #pragma unroll
                for (int i = 0; i < 4; ++i) zacc[i] += p[i];
            }
        }
    }
    #pragma unroll
    for (int i = 0; i < 4; ++i)
        #pragma unroll
        for (int j = 0; j < 4; ++j)
            atomicAdd(&kv[(((size_t)b * 2 + kh) * 64 + tm + i) * 64 + tdh + j], acc[i][j]);
    if ((tid >> 4) == 0) {
        #pragma unroll
        for (int i = 0; i < 4; ++i)
            atomicAdd(&z[((size_t)b * 2 + kh) * 64 + tm + i], zacc[i]);
    }
}

// ---------------- attention mix (MFMA): attn = (pq @ kv) / (pq @ z + eps) ----------------
__global__ __launch_bounds__(256) void attn_mix_kernel(
    const __hip_bfloat16* __restrict__ pq, const float* __restrict__ kvf,
    const float* __restrict__ zf, __hip_bfloat16* __restrict__ attn, int gbase)
{
    __shared__ __align__(16) __hip_bfloat16 kvT[80][72];
    const int kh = blockIdx.y;
    const int row0b = blockIdx.x * 128;
    const int b = (gbase + row0b) >> 13;
    const int tid = threadIdx.x;

    const float* kvsrc = kvf + ((size_t)b * 2 + kh) * 4096;
    for (int i = tid; i < 4096; i += 256) {
        const int m = i >> 6, dh = i & 63;
        kvT[dh][m] = f2bf(kvsrc[i]);
    }
    if (tid < 64) kvT[64][tid] = f2bf(zf[((size_t)b * 2 + kh) * 64 + tid]);
    for (int i = tid; i < 15 * 64; i += 256) {
        const int rr = 65 + (i >> 6), m = i & 63;
        kvT[rr][m] = f2bf(0.0f);
    }
    __syncthreads();

    const int wave = tid >> 6, lane = tid & 63;
    const int quad = lane >> 4, lr = lane & 15;
    const int wm = (wave >> 1) << 6;
    const int whead = (wave & 1) << 1;

    #pragma unroll
    for (int g2 = 0; g2 < 2; ++g2) {
        const int hh = kh * 4 + whead + g2;
        f32x4 acc[4][5];
        #pragma unroll
        for (int i = 0; i < 4; ++i)
            #pragma unroll
            for (int j = 0; j < 5; ++j)
                #pragma unroll
                for (int r = 0; r < 4; ++r) acc[i][j][r] = 0.0f;

        #pragma unroll
        for (int kk = 0; kk < 2; ++kk) {
            const int kofs = kk * 32 + quad * 8;
            bf16x8 af[4], bfr[5];
            #pragma unroll
            for (int i = 0; i < 4; ++i)
                af[i] = *(const bf16x8*)(pq + (size_t)(row0b + wm + i * 16 + lr) * 512
                                            + hh * 64 + kofs);
            #pragma unroll
            for (int j = 0; j < 5; ++j)
                bfr[j] = *(const bf16x8*)&kvT[j * 16 + lr][kofs];
            #pragma unroll
            for (int i = 0; i < 4; ++i)
                #pragma unroll
                for (int j = 0; j < 5; ++j)
                    acc[i][j] = __builtin_amdgcn_mfma_f32_16x16x32_bf16(af[i], bfr[j], acc[i][j], 0, 0, 0);
        }

        const int colb = hh * 64;
        #pragma unroll
        for (int i = 0; i < 4; ++i) {
            const int rowb = row0b + wm + i * 16 + quad * 4;
            #pragma unroll
            for (int r = 0; r < 4; ++r) {
                const float den = __shfl(acc[i][4][r], lane & 48, 64);
                const float inv = 1.0f / (den + 1e-6f);
                const size_t base = (size_t)(rowb + r) * 512 + colb;
                #pragma unroll
                for (int j = 0; j < 4; ++j)
                    attn[base + j * 16 + lr] = f2bf(acc[i][j][r] * inv);
            }
        }
    }
}

// ---------------- mean pool accumulate (x1 contribution) ----------------
__global__ __launch_bounds__(256) void pool_kernel(
    const float* __restrict__ xf, float* __restrict__ pooled, int gbase)
{
    const int row0 = blockIdx.x * 256;
    const int b = (gbase + row0) >> 13;
    const int t = threadIdx.x;
    float a0 = 0.f, a1 = 0.f;
    const size_t base = (size_t)row0 * 512;
    for (int s = 0; s < 256; ++s) {
        a0 += xf[base + (size_t)s * 512 + t];
        a1 += xf[base + (size_t)s * 512 + t + 256];
    }
    atomicAdd(&pooled[b * 512 + t], a0);
    atomicAdd(&pooled[b * 512 + t + 256], a1);
}

// ---------------- classifier head ----------------
__global__ __launch_bounds__(256) void head_kernel(
    const float* __restrict__ pooled, const void* __restrict__ Wc,
    const void* __restrict__ bc, void* __restrict__ out, const int* __restrict__ flag)
{
    const int f = *flag;
    const int t = threadIdx.x;
    const int grp = t >> 4, ln = t & 15;
    const int b = grp >> 1, c = grp & 1;
    float p = 0.f;
    for (int d = ln; d < 512; d += 16)
        p += pooled[b * 512 + d] * loadElem(Wc, (size_t)d * 2 + c, f);
    #pragma unroll
    for (int off = 8; off; off >>= 1) p += __shfl_xor(p, off, 64);
    if (ln == 0) {
        const float val = p * (1.0f / 8192.0f) + loadElem(bc, c, f);
        if (f) ((float*)out)[b * 2 + c] = val;
        else   ((__hip_bfloat16*)out)[b * 2 + c] = f2bf(val);
    }
}

// ---------------- launch ----------------
extern "C" void kernel_launch(void* const* d_in, const int* in_sizes, int n_in,
                              void* d_out, int out_size, void* d_ws, size_t ws_size,
                              hipStream_t stream)
{
    const int* ids   = (const int*)d_in[0];
    const void* emb  = d_in[1];
    const void* Wq   = d_in[2];
    const void* Wk   = d_in[3];
    const void* Wv   = d_in[4];
    const void* Wph  = d_in[5];
    const void* Wo   = d_in[6];
    const void* g1   = d_in[7];
    const void* g2   = d_in[8];
    const void* Wg   = d_in[9];
    const void* Wu   = d_in[10];
    const void* Wd   = d_in[11];
    const void* Wc   = d_in[12];
    const void* bc   = d_in[13];

    char* ws = (char*)d_ws;
    __hip_bfloat16* WQPt  = (__hip_bfloat16*)(ws + OFF_WQPT);  // [WQPt|WKPt|WvT] = [768][512]
    __hip_bfloat16* WKPt  = (__hip_bfloat16*)(ws + OFF_WKPT);
    __hip_bfloat16* WvT   = (__hip_bfloat16*)(ws + OFF_WVT);
    __hip_bfloat16* WoT   = (__hip_bfloat16*)(ws + OFF_WOT);
    __hip_bfloat16* WgT   = (__hip_bfloat16*)(ws + OFF_WGT);
    __hip_bfloat16* WuT   = (__hip_bfloat16*)(ws + OFF_WUT);
    float*          kv    = (float*)(ws + OFF_KV);
    float*          z     = (float*)(ws + OFF_Z);
    float*          pooled= (float*)(ws + OFF_POOL);
    float*          tsum  = (float*)(ws + OFF_TSUM);
    int*            flag  = (int*)(ws + OFF_FLAG);
    __hip_bfloat16* pqall = (__hip_bfloat16*)(ws + OFF_PQALL); // bf16 [NTOK][512]

    // ---- adaptive chunk: largest power-of-2 C in [256, 32768] that fits ws ----
    int C = 32768;
    while (C > 256 && CHUNKBASE + PERTOK * (size_t)C > ws_size) C >>= 1;
    const int NC = NTOK / C;

    char* cb = ws + CHUNKBASE;
    float*          xf   = (float*)cb;                                  // f32  [C][512]
    __hip_bfloat16* h    = (__hip_bfloat16*)(cb + (size_t)C * 2048);    // bf16 [C][512]
    __hip_bfloat16* attn = (__hip_bfloat16*)(cb + (size_t)C * 3072);    // bf16 [C][512]
    __hip_bfloat16* pkv  = (__hip_bfloat16*)(cb + (size_t)C * 4096);    // bf16 [C][256]  pk|v

    detect_kernel<<<1, 128, 0, stream>>>((const unsigned int*)Wph, flag);
    zero_kernel<<<(ZERO_FLOATS + 255) / 256, 256, 0, stream>>>(kv, ZERO_FLOATS);

    // weight prep (WdT no longer needed — Wd used directly in ffn_pool)
    fuse_phi_kernel<<<1024, 256, 0, stream>>>(Wq, Wph, WQPt, 512, flag);
    fuse_phi_kernel<<<256, 256, 0, stream>>>(Wk, Wph, WKPt, 128, flag);
    transpose_kernel<<<dim3(128 / 32, 512 / 32), 256, 0, stream>>>(Wv, WvT, 512, 128, flag);
    transpose_kernel<<<dim3(512 / 32, 512 / 32), 256, 0, stream>>>(Wo, WoT, 512, 512, flag);
    transpose_kernel<<<dim3(2048 / 32, 512 / 32), 256, 0, stream>>>(Wg, WgT, 512, 2048, flag);
    transpose_kernel<<<dim3(2048 / 32, 512 / 32), 256, 0, stream>>>(Wu, WuT, 512, 2048, flag);

    // ---- pass A: pq (all tokens) + per-chunk pk|v -> accumulate global kv / z ----
    for (int c = 0; c < NC; ++c) {
        const int g0 = c * C;
        embed_rms_kernel<<<C / 4, 256, 0, stream>>>(ids + g0, emb, g1, xf, h, flag, 0, 1);
        // combined [pq | pk | v] GEMM: B = [WQPt;WKPt;WvT] rows 0..767
        gemm128_kernel<5><<<dim3(C / 128, 6), 256, 0, stream>>>(
            h, WQPt, pqall + (size_t)g0 * 512, pkv, 512, 512);
        kv_z_kernel<<<dim3(C / 128, 2), 256, 0, stream>>>(pkv, kv, z, g0, 128);
    }

    // ---- pass B: per chunk -> mix, +Wo, pool(x1)+rms, fused SwiGLU -> tsum ----
    for (int c = 0; c < NC; ++c) {
        const int g0 = c * C;
        embed_rms_kernel<<<C / 4, 256, 0, stream>>>(ids + g0, emb, g1, xf, h, flag, 1, 0);
        attn_mix_kernel<<<dim3(C / 128, 2), 256, 0, stream>>>(
            pqall + (size_t)g0 * 512, kv, z, attn, g0);
        gemm128_kernel<2><<<dim3(C / 128, 4), 256, 0, stream>>>(
            attn, WoT, xf, nullptr, 512, 512);
        pool_kernel<<<C / 256, 256, 0, stream>>>(xf, pooled, g0);       // x1 contribution
        rms2_kernel<<<C / 4, 256, 0, stream>>>(xf, g2, h, flag);
        dim3 gg(C / 128, 16);
        gemm_ffn_kernel<<<gg, 256, 0, stream>>>(h, WgT, WuT, tsum, g0, 512);
    }

    // pooled += tsum @ Wd  (exact: pooling is linear)
    ffn_pool_kernel<<<16, 256, 0, stream>>>(tsum, Wd, pooled, flag);

    head_kernel<<<1, 256, 0, stream>>>(pooled, Wc, bc, d_out, flag);
}

// Round 10
// 1089.394 us; speedup vs baseline: 2.8653x; 1.1982x over previous
//
#include <hip/hip_runtime.h>
#include <hip/hip_bf16.h>
#include <math.h>

// ---------------- types / helpers ----------------
typedef __attribute__((ext_vector_type(8))) short bf16x8;
typedef __attribute__((ext_vector_type(4))) float f32x4;

#define DEV static __device__ __forceinline__
#define AS1 __attribute__((address_space(1)))
#define AS3 __attribute__((address_space(3)))

DEV float bf2f(__hip_bfloat16 v) { return __bfloat162float(v); }
DEV __hip_bfloat16 f2bf(float f) { return __float2bfloat16(f); }
DEV float us2f(unsigned short u) { return __uint_as_float(((unsigned int)u) << 16); }
DEV unsigned short f2us(float f) {
    __hip_bfloat16 b = __float2bfloat16(f);
    return *(unsigned short*)&b;
}

// async global->LDS, 16 B per lane (LDS dst = wave-uniform base + lane*16)
DEV void gload_lds16(const void* g, void* l) {
    __builtin_amdgcn_global_load_lds((const AS1 unsigned int*)g,
                                     (AS3 unsigned int*)l, 16, 0, 0);
}

// load 8 consecutive floats from an input tensor that is either f32 or bf16
DEV void load8(const void* p, size_t off, int f32m, float* o) {
    if (f32m) {
        const float4* r = (const float4*)((const float*)p + off);
        float4 A = r[0], B = r[1];
        o[0] = A.x; o[1] = A.y; o[2] = A.z; o[3] = A.w;
        o[4] = B.x; o[5] = B.y; o[6] = B.z; o[7] = B.w;
    } else {
        const ushort4* r = (const ushort4*)((const __hip_bfloat16*)p + off);
        ushort4 A = r[0], B = r[1];
        o[0] = us2f(A.x); o[1] = us2f(A.y); o[2] = us2f(A.z); o[3] = us2f(A.w);
        o[4] = us2f(B.x); o[5] = us2f(B.y); o[6] = us2f(B.z); o[7] = us2f(B.w);
    }
}

DEV float loadElem(const void* p, size_t idx, int f32m) {
    return f32m ? ((const float*)p)[idx] : bf2f(((const __hip_bfloat16*)p)[idx]);
}

// ---------------- problem constants ----------------
// B=8 S=8192 D=512 H=8 HK=2 DH=64 M=64 DFF=2048 NCLS=2 G=4
constexpr int NTOK = 65536;   // 8*8192

// ---------------- persistent ws layout (bytes) ----------------
constexpr size_t OFF_WQPT = 0;                       // bf16 [512][512]  (Wq@Wphi)^T
constexpr size_t OFF_WKPT = OFF_WQPT + 524288ull;    // bf16 [128][512]  (Wk@Wphi)^T   } contiguous:
constexpr size_t OFF_WVT  = OFF_WKPT + 131072ull;    // bf16 [128][512]  Wv^T          } [768][512] B-matrix
constexpr size_t OFF_WOT  = OFF_WVT  + 131072ull;    // bf16 [512][512]  Wo^T
constexpr size_t OFF_WGT  = OFF_WOT  + 524288ull;    // bf16 [2048][512] Wg^T
constexpr size_t OFF_WUT  = OFF_WGT  + 2097152ull;   // bf16 [2048][512] Wu^T
constexpr size_t OFF_KV   = OFF_WUT  + 2097152ull;   // f32  [8][2][64][64]
constexpr size_t OFF_Z    = OFF_KV   + 262144ull;    // f32  [8][2][64]
constexpr size_t OFF_POOL = OFF_Z    + 4096ull;      // f32  [8][512]
constexpr size_t OFF_TSUM = OFF_POOL + 16384ull;     // f32  [8][2048]  col-sums of FFN t
constexpr size_t OFF_FLAG = OFF_TSUM + 65536ull;     // int  dtype flag (1 = f32 inputs)
constexpr size_t PERSIST  = OFF_FLAG + 256ull;
constexpr size_t OFF_PQALL = PERSIST;                // bf16 [65536][512] pq (all tokens)
constexpr size_t PQALL_SZ  = 67108864ull;
constexpr size_t CHUNKBASE = OFF_PQALL + PQALL_SZ;
constexpr int    ZERO_FLOATS = (262144 + 4096 + 16384 + 65536) / 4;  // kv+z+pooled+tsum
// per-token chunk bytes: xf 2048 + h 1024 + attn 1024 + pkv 512 = 4608
constexpr size_t PERTOK = 4608ull;
// ws check: rounds 3-6 ran C=16384 at PERTOK=13824 => ws >= 234.4 MB;
// C=32768 here needs 75.1 MB + 151.0 MB = 226.1 MB -> fits (runtime-checked anyway).

// ---------------- dtype detection ----------------
__global__ __launch_bounds__(128) void detect_kernel(
    const unsigned int* __restrict__ w, int* __restrict__ flag)
{
    __shared__ int cnt;
    if (threadIdx.x == 0) cnt = 0;
    __syncthreads();
    unsigned int v = w[threadIdx.x];
    float a = fabsf(us2f((unsigned short)(v & 0xFFFFu)));
    if (a >= 0.0625f && a <= 8.0f) atomicAdd(&cnt, 1);
    __syncthreads();
    if (threadIdx.x == 0) *flag = (cnt < 64) ? 1 : 0;
}

// ---------------- tiny init ----------------
__global__ __launch_bounds__(256) void zero_kernel(float* __restrict__ p, int n)
{
    int i = blockIdx.x * 256 + threadIdx.x;
    if (i < n) p[i] = 0.0f;
}

// ---------------- weight prep ----------------
// outT[hm][d] = sum_dh W[d][h*64+dh] * Wphi[dh][m]   (hm = h*64+m), row-major [nh*64][512]
__global__ __launch_bounds__(256) void fuse_phi_kernel(
    const void* __restrict__ W, const void* __restrict__ Wphi,
    __hip_bfloat16* __restrict__ outT, int wld, const int* __restrict__ flag)
{
    const int f = *flag;
    int o = blockIdx.x * 256 + threadIdx.x;   // o = hm*512 + d
    int hm = o >> 9, d = o & 511;
    int h = hm >> 6, m = hm & 63;
    float acc = 0.f;
    if (f) {
        const float* Wf = (const float*)W;
        const float* Pf = (const float*)Wphi;
        #pragma unroll 8
        for (int dh = 0; dh < 64; ++dh)
            acc += Wf[(size_t)d * wld + h * 64 + dh] * Pf[dh * 64 + m];
    } else {
        const __hip_bfloat16* Wb = (const __hip_bfloat16*)W;
        const __hip_bfloat16* Pb = (const __hip_bfloat16*)Wphi;
        #pragma unroll 8
        for (int dh = 0; dh < 64; ++dh)
            acc += bf2f(Wb[(size_t)d * wld + h * 64 + dh]) * bf2f(Pb[dh * 64 + m]);
    }
    outT[o] = f2bf(acc);
}

// dst[Ccols][R] = src[R][Ccols]^T, LDS-tiled 32x32 (R, Ccols multiples of 32)
__global__ __launch_bounds__(256) void transpose_kernel(
    const void* __restrict__ src, __hip_bfloat16* __restrict__ dst, int R, int Ccols,
    const int* __restrict__ flag)
{
    __shared__ float tile[32][33];
    const int f = *flag;
    const int tx = threadIdx.x & 31, ty = threadIdx.x >> 5;   // 32 x 8
    const int c0 = blockIdx.x * 32, r0 = blockIdx.y * 32;
    #pragma unroll
    for (int k = 0; k < 4; ++k) {
        const int rl = ty + k * 8;
        tile[rl][tx] = loadElem(src, (size_t)(r0 + rl) * Ccols + c0 + tx, f);
    }
    __syncthreads();
    #pragma unroll
    for (int k = 0; k < 4; ++k) {
        const int cl = ty + k * 8;
        dst[(size_t)(c0 + cl) * R + r0 + tx] = f2bf(tile[tx][cl]);
    }
}

// ---------------- embedding gather + rmsnorm (wave per row; chunk-local) ----------------
__global__ __launch_bounds__(256) void embed_rms_kernel(
    const int* __restrict__ ids, const void* __restrict__ emb,
    const void* __restrict__ g1, float* __restrict__ xf,
    __hip_bfloat16* __restrict__ h, const int* __restrict__ flag,
    int write_xf, int write_h)
{
    const int f = *flag;
    const int n = blockIdx.x * 4 + (threadIdx.x >> 6);   // local row in chunk
    const int lane = threadIdx.x & 63;
    const int id = ids[n];
    float x[8];
    load8(emb, (size_t)id * 512 + lane * 8, f, x);
    float ss = 0.f;
    #pragma unroll
    for (int i = 0; i < 8; ++i) ss += x[i] * x[i];
    #pragma unroll
    for (int off = 32; off; off >>= 1) ss += __shfl_xor(ss, off, 64);
    const float scale = rsqrtf(ss * (1.0f / 512.0f) + 1e-6f);

    if (write_xf) {
        float4* xo = (float4*)(xf + (size_t)n * 512 + lane * 8);
        xo[0] = make_float4(x[0], x[1], x[2], x[3]);
        xo[1] = make_float4(x[4], x[5], x[6], x[7]);
    }
    if (write_h) {
        float gv[8];
        load8(g1, (size_t)lane * 8, f, gv);
        ushort4 h0, h1;
        h0.x = f2us(x[0] * scale * gv[0]); h0.y = f2us(x[1] * scale * gv[1]);
        h0.z = f2us(x[2] * scale * gv[2]); h0.w = f2us(x[3] * scale * gv[3]);
        h1.x = f2us(x[4] * scale * gv[4]); h1.y = f2us(x[5] * scale * gv[5]);
        h1.z = f2us(x[6] * scale * gv[6]); h1.w = f2us(x[7] * scale * gv[7]);
        ushort4* ho = (ushort4*)(h + (size_t)n * 512 + lane * 8);
        ho[0] = h0; ho[1] = h1;
    }
}

// ---------------- rmsnorm from f32 residual (chunk-local) ----------------
__global__ __launch_bounds__(256) void rms2_kernel(
    const float* __restrict__ xf, const void* __restrict__ g2,
    __hip_bfloat16* __restrict__ h, const int* __restrict__ flag)
{
    const int f = *flag;
    const int n = blockIdx.x * 4 + (threadIdx.x >> 6);
    const int lane = threadIdx.x & 63;
    const float4* xr = (const float4*)(xf + (size_t)n * 512);
    float4 a = xr[lane * 2], b = xr[lane * 2 + 1];
    float x[8] = { a.x, a.y, a.z, a.w, b.x, b.y, b.z, b.w };
    float ss = 0.f;
    #pragma unroll
    for (int i = 0; i < 8; ++i) ss += x[i] * x[i];
    #pragma unroll
    for (int off = 32; off; off >>= 1) ss += __shfl_xor(ss, off, 64);
    const float scale = rsqrtf(ss * (1.0f / 512.0f) + 1e-6f);

    float gv[8];
    load8(g2, (size_t)lane * 8, f, gv);
    ushort4 h0, h1;
    h0.x = f2us(x[0] * scale * gv[0]); h0.y = f2us(x[1] * scale * gv[1]);
    h0.z = f2us(x[2] * scale * gv[2]); h0.w = f2us(x[3] * scale * gv[3]);
    h1.x = f2us(x[4] * scale * gv[4]); h1.y = f2us(x[5] * scale * gv[5]);
    h1.z = f2us(x[6] * scale * gv[6]); h1.w = f2us(x[7] * scale * gv[7]);
    ushort4* ho = (ushort4*)(h + (size_t)n * 512 + lane * 8);
    ho[0] = h0; ho[1] = h1;
}

// ---------------- MFMA GEMM: C[M,N] = A[M,K] @ Bt[N,K]^T ----------------
// m97 structure: 128x128 tile, BK=32, global_load_lds width-16 staging into
// flat [128][32] LDS tiles with XOR bank swizzle; 4 waves (2x2), wave tile
// 64x64 = 4x4 mfma_f32_16x16x32_bf16.
// MODE 2: Cf32[idx] += acc
// MODE 5: combined pq|pk|v epilogue: bn 0-3 -> Cout=pq (exp(-|.|), Ncols=512);
//         bn 4 -> Cout2=pkv cols 0..127 (exp); bn 5 -> pkv cols 128..255 (plain)
template<int MODE>
__global__ __launch_bounds__(256) void gemm128_kernel(
    const __hip_bfloat16* __restrict__ A, const __hip_bfloat16* __restrict__ Bt,
    void* __restrict__ Cout, __hip_bfloat16* __restrict__ Cout2, int K, int Ncols)
{
    __shared__ __align__(16) char As[8192];   // bf16 [128 rows][32 k], swizzled chunks
    __shared__ __align__(16) char Bs[8192];

    const int tid = threadIdx.x;
    const int bm = blockIdx.x, bn = blockIdx.y;
    const int wave = tid >> 6, lane = tid & 63;
    const int quad = lane >> 4, lr = lane & 15;
    const int wm = (wave >> 1) << 6, wn = (wave & 1) << 6;

    // staging: wave w, instr t in {0,1}; LDS chunk idx = w*128 + t*64 + lane
    const int srow = (wave << 5) + (lane >> 2);          // row for t=0 (t=1: +16)
    const int scol = lane & 3;
    const int sfr  = (srow + (srow >> 2)) & 3;           // == f(srow+16)
    const int sofs = ((scol ^ sfr) << 3);                // swizzled global col (elements)

    const __hip_bfloat16* ga0 = A  + (size_t)(bm * 128 + srow) * K + sofs;
    const __hip_bfloat16* gb0 = Bt + (size_t)(bn * 128 + srow) * K + sofs;
    const __hip_bfloat16* ga1 = ga0 + (size_t)16 * K;
    const __hip_bfloat16* gb1 = gb0 + (size_t)16 * K;
    char* lA0 = As + (wave << 11);
    char* lA1 = lA0 + 1024;
    char* lB0 = Bs + (wave << 11);
    char* lB1 = lB0 + 1024;

    // fragment reads
    const int fl  = (lr + (lr >> 2)) & 3;
    const int ac  = (quad ^ fl) << 4;
    const char* arp = As + ((wm + lr) << 6) + ac;
    const char* brp = Bs + ((wn + lr) << 6) + ac;

    f32x4 acc[4][4];
    #pragma unroll
    for (int i = 0; i < 4; ++i)
        #pragma unroll
        for (int j = 0; j < 4; ++j)
            #pragma unroll
            for (int r = 0; r < 4; ++r) acc[i][j][r] = 0.0f;

    for (int k0 = 0; k0 < K; k0 += 32) {
        __syncthreads();
        gload_lds16(ga0 + k0, lA0);
        gload_lds16(ga1 + k0, lA1);
        gload_lds16(gb0 + k0, lB0);
        gload_lds16(gb1 + k0, lB1);
        __syncthreads();

        bf16x8 af[4], bfr[4];
        #pragma unroll
        for (int i = 0; i < 4; ++i)
            af[i] = *(const bf16x8*)(arp + i * 1024);
        #pragma unroll
        for (int j = 0; j < 4; ++j)
            bfr[j] = *(const bf16x8*)(brp + j * 1024);
        #pragma unroll
        for (int i = 0; i < 4; ++i)
            #pragma unroll
            for (int j = 0; j < 4; ++j)
                acc[i][j] = __builtin_amdgcn_mfma_f32_16x16x32_bf16(af[i], bfr[j], acc[i][j], 0, 0, 0);
    }

    // C/D layout: col = lane&15, row = quad*4 + reg  [m89/m91]
    const int col0 = bn * 128 + wn + lr;
    const int row0 = bm * 128 + wm + quad * 4;
    #pragma unroll
    for (int i = 0; i < 4; ++i)
        #pragma unroll
        for (int j = 0; j < 4; ++j) {
            const int col = col0 + j * 16;
            #pragma unroll
            for (int r = 0; r < 4; ++r) {
                const int row = row0 + i * 16 + r;
                const float v = acc[i][j][r];
                if (MODE == 2) {
                    ((float*)Cout)[(size_t)row * Ncols + col] += v;
                } else {   // MODE 5
                    if (bn < 4) {
                        ((__hip_bfloat16*)Cout)[(size_t)row * 512 + col] =
                            f2bf(expf(-fabsf(v)));
                    } else {
                        const int c2 = col - 512;   // 0..255
                        Cout2[(size_t)row * 256 + c2] =
                            f2bf(bn == 4 ? expf(-fabsf(v)) : v);
                    }
                }
            }
        }
}

// ---------------- fused SwiGLU up-GEMM + column-sum ----------------
// t = silu(A@Wg^T) * (A@Wu^T); no t materialization — accumulate column sums
// of t (per batch) into tsum[b][2048]:  sum_rows(t@Wd) == (sum_rows t)@Wd.
__global__ __launch_bounds__(256, 2) void gemm_ffn_kernel(
    const __hip_bfloat16* __restrict__ A, const __hip_bfloat16* __restrict__ Bg,
    const __hip_bfloat16* __restrict__ Bu, float* __restrict__ tsum,
    int gbase, int K)
{
    __shared__ __align__(16) char As[8192];
    __shared__ __align__(16) char Gs[8192];
    __shared__ __align__(16) char Us[8192];

    const int tid = threadIdx.x;
    const int bm = blockIdx.x, bn = blockIdx.y;
    const int wave = tid >> 6, lane = tid & 63;
    const int quad = lane >> 4, lr = lane & 15;
    const int wm = (wave >> 1) << 6, wn = (wave & 1) << 6;

    const int srow = (wave << 5) + (lane >> 2);
    const int scol = lane & 3;
    const int sfr  = (srow + (srow >> 2)) & 3;
    const int sofs = ((scol ^ sfr) << 3);

    const __hip_bfloat16* ga0 = A  + (size_t)(bm * 128 + srow) * K + sofs;
    const __hip_bfloat16* gg0 = Bg + (size_t)(bn * 128 + srow) * K + sofs;
    const __hip_bfloat16* gu0 = Bu + (size_t)(bn * 128 + srow) * K + sofs;
    const __hip_bfloat16* ga1 = ga0 + (size_t)16 * K;
    const __hip_bfloat16* gg1 = gg0 + (size_t)16 * K;
    const __hip_bfloat16* gu1 = gu0 + (size_t)16 * K;
    char* lA0 = As + (wave << 11);
    char* lG0 = Gs + (wave << 11);
    char* lU0 = Us + (wave << 11);

    const int fl  = (lr + (lr >> 2)) & 3;
    const int ac  = (quad ^ fl) << 4;
    const char* arp = As + ((wm + lr) << 6) + ac;
    const char* grp = Gs + ((wn + lr) << 6) + ac;
    const char* urp = Us + ((wn + lr) << 6) + ac;

    f32x4 accG[4][4], accU[4][4];
    #pragma unroll
    for (int i = 0; i < 4; ++i)
        #pragma unroll
        for (int j = 0; j < 4; ++j)
            #pragma unroll
            for (int r = 0; r < 4; ++r) { accG[i][j][r] = 0.0f; accU[i][j][r] = 0.0f; }

    for (int k0 = 0; k0 < K; k0 += 32) {
        __syncthreads();
        gload_lds16(ga0 + k0, lA0);
        gload_lds16(ga1 + k0, lA0 + 1024);
        gload_lds16(gg0 + k0, lG0);
        gload_lds16(gg1 + k0, lG0 + 1024);
        gload_lds16(gu0 + k0, lU0);
        gload_lds16(gu1 + k0, lU0 + 1024);
        __syncthreads();

        bf16x8 af[4], bgf[4], buf_[4];
        #pragma unroll
        for (int i = 0; i < 4; ++i)
            af[i] = *(const bf16x8*)(arp + i * 1024);
        #pragma unroll
        for (int j = 0; j < 4; ++j) {
            bgf[j]  = *(const bf16x8*)(grp + j * 1024);
            buf_[j] = *(const bf16x8*)(urp + j * 1024);
        }
        #pragma unroll
        for (int i = 0; i < 4; ++i)
            #pragma unroll
            for (int j = 0; j < 4; ++j) {
                accG[i][j] = __builtin_amdgcn_mfma_f32_16x16x32_bf16(af[i], bgf[j],  accG[i][j], 0, 0, 0);
                accU[i][j] = __builtin_amdgcn_mfma_f32_16x16x32_bf16(af[i], buf_[j], accU[i][j], 0, 0, 0);
            }
    }

    // epilogue: column sums of silu(G)*U over this block's 128 rows
    // col = bn*128 + wn + lr + j*16 (quad-pure); batch uniform per block.
    const int b = (gbase + bm * 128) >> 13;   // 128 | 8192
    #pragma unroll
    for (int j = 0; j < 4; ++j) {
        float s = 0.f;
        #pragma unroll
        for (int i = 0; i < 4; ++i)
            #pragma unroll
            for (int r = 0; r < 4; ++r) {
                const float g = accG[i][j][r];
                s += (g / (1.0f + expf(-g))) * accU[i][j][r];
            }
        s += __shfl_xor(s, 16, 64);
        s += __shfl_xor(s, 32, 64);
        if (quad == 0)
            atomicAdd(&tsum[b * 2048 + bn * 128 + wn + lr + j * 16], s);
    }
}

// ---------------- pooled[b][:] += tsum[b][:] @ Wd  (k-split parallel) ----------------
// grid 32 blocks; block owns 64 k-values. Wd read once total (coalesced rows);
// tsum slice staged in LDS; acc[8][2] in registers; 16 atomics/thread at end.
__global__ __launch_bounds__(256) void ffn_pool_kernel(
    const float* __restrict__ tsum, const void* __restrict__ Wd,
    float* __restrict__ pooled, const int* __restrict__ flag)
{
    __shared__ float ts[8][64];
    const int f = *flag;
    const int k0 = blockIdx.x * 64;
    const int t = threadIdx.x;
    for (int i = t; i < 512; i += 256)
        ts[i >> 6][i & 63] = tsum[(i >> 6) * 2048 + k0 + (i & 63)];
    __syncthreads();

    float acc0[8] = {}, acc1[8] = {};
    for (int kk = 0; kk < 64; ++kk) {
        const size_t krow = (size_t)(k0 + kk) * 512;
        const float w0 = loadElem(Wd, krow + t, f);
        const float w1 = loadElem(Wd, krow + t + 256, f);
        #pragma unroll
        for (int b = 0; b < 8; ++b) {
            acc0[b] += ts[b][kk] * w0;
            acc1[b] += ts[b][kk] * w1;
        }
    }
    #pragma unroll
    for (int b = 0; b < 8; ++b) {
        atomicAdd(&pooled[b * 512 + t], acc0[b]);
        atomicAdd(&pooled[b * 512 + t + 256], acc1[b]);
    }
}

// ---------------- kv / z global-state reduction (pkv [C][256] input) ----------------
__global__ __launch_bounds__(256) void kv_z_kernel(
    const __hip_bfloat16* __restrict__ pkv,
    float* __restrict__ kv, float* __restrict__ z, int gbase, int nrows)
{
    __shared__ float pks[8][64], vs[8][64];
    const int slab = blockIdx.x, kh = blockIdx.y;
    const int b = (gbase + slab * nrows) >> 13;   // nrows | 8192 -> uniform per block
    const int tid = threadIdx.x;
    const int tm = (tid & 15) << 2, tdh = (tid >> 4) << 2;
    const int lss = tid >> 5, lmm = (tid & 31) << 1;

    float acc[4][4] = {};
    float zacc[4] = {};
    for (int sb = 0; sb < nrows; sb += 8) {
        __syncthreads();
        {
            const size_t n = (size_t)slab * nrows + sb + lss;   // local row
            const __hip_bfloat16* pr = pkv + n * 256 + kh * 64 + lmm;        // pk cols 0..127
            const __hip_bfloat16* vr = pkv + n * 256 + 128 + kh * 64 + lmm;  // v  cols 128..255
            pks[lss][lmm]     = bf2f(pr[0]);
            pks[lss][lmm + 1] = bf2f(pr[1]);
            vs[lss][lmm]      = bf2f(vr[0]);
            vs[lss][lmm + 1]  = bf2f(vr[1]);
        }
        __syncthreads();
        #pragma unroll
        for (int ss = 0; ss < 8; ++ss) {
            f32x4 p = *(const f32x4*)&pks[ss][tm];
            f32x4 w = *(const f32x4*)&vs[ss][tdh];
            #pragma unroll
            for (int i = 0; i < 4; ++i)
                #pragma unroll
                for (int j = 0; j < 4; ++j)
                    acc[i][j] += p[i] * w[j];
            if ((tid >> 4) == 0) {
                #pragma unroll
                for (int i = 0; i < 4; ++i) zacc[i] += p[i];
            }
        }
    }
    #pragma unroll
    for (int i = 0; i < 4; ++i)
        #pragma unroll
        for (int j = 0; j < 4; ++j)
            atomicAdd(&kv[(((size_t)b * 2 + kh) * 64 + tm + i) * 64 + tdh + j], acc[i][j]);
    if ((tid >> 4) == 0) {
        #pragma unroll
        for (int i = 0; i < 4; ++i)
            atomicAdd(&z[((size_t)b * 2 + kh) * 64 + tm + i], zacc[i]);
    }
}

// ---------------- attention mix (MFMA): attn = (pq @ kv) / (pq @ z + eps) ----------------
__global__ __launch_bounds__(256) void attn_mix_kernel(
    const __hip_bfloat16* __restrict__ pq, const float* __restrict__ kvf,
    const float* __restrict__ zf, __hip_bfloat16* __restrict__ attn, int gbase)
{
    __shared__ __align__(16) __hip_bfloat16 kvT[80][72];
    const int kh = blockIdx.y;
    const int row0b = blockIdx.x * 128;
    const int b = (gbase + row0b) >> 13;
    const int tid = threadIdx.x;

    const float* kvsrc = kvf + ((size_t)b * 2 + kh) * 4096;
    for (int i = tid; i < 4096; i += 256) {
        const int m = i >> 6, dh = i & 63;
        kvT[dh][m] = f2bf(kvsrc[i]);
    }
    if (tid < 64) kvT[64][tid] = f2bf(zf[((size_t)b * 2 + kh) * 64 + tid]);
    for (int i = tid; i < 15 * 64; i += 256) {
        const int rr = 65 + (i >> 6), m = i & 63;
        kvT[rr][m] = f2bf(0.0f);
    }
    __syncthreads();

    const int wave = tid >> 6, lane = tid & 63;
    const int quad = lane >> 4, lr = lane & 15;
    const int wm = (wave >> 1) << 6;
    const int whead = (wave & 1) << 1;

    #pragma unroll
    for (int g2 = 0; g2 < 2; ++g2) {
        const int hh = kh * 4 + whead + g2;
        f32x4 acc[4][5];
        #pragma unroll
        for (int i = 0; i < 4; ++i)
            #pragma unroll
            for (int j = 0; j < 5; ++j)
                #pragma unroll
                for (int r = 0; r < 4; ++r) acc[i][j][r] = 0.0f;

        #pragma unroll
        for (int kk = 0; kk < 2; ++kk) {
            const int kofs = kk * 32 + quad * 8;
            bf16x8 af[4], bfr[5];
            #pragma unroll
            for (int i = 0; i < 4; ++i)
                af[i] = *(const bf16x8*)(pq + (size_t)(row0b + wm + i * 16 + lr) * 512
                                            + hh * 64 + kofs);
            #pragma unroll
            for (int j = 0; j < 5; ++j)
                bfr[j] = *(const bf16x8*)&kvT[j * 16 + lr][kofs];
            #pragma unroll
            for (int i = 0; i < 4; ++i)
                #pragma unroll
                for (int j = 0; j < 5; ++j)
                    acc[i][j] = __builtin_amdgcn_mfma_f32_16x16x32_bf16(af[i], bfr[j], acc[i][j], 0, 0, 0);
        }

        const int colb = hh * 64;
        #pragma unroll
        for (int i = 0; i < 4; ++i) {
            const int rowb = row0b + wm + i * 16 + quad * 4;
            #pragma unroll
            for (int r = 0; r < 4; ++r) {
                const float den = __shfl(acc[i][4][r], lane & 48, 64);
                const float inv = 1.0f / (den + 1e-6f);
                const size_t base = (size_t)(rowb + r) * 512 + colb;
                #pragma unroll
                for (int j = 0; j < 4; ++j)
                    attn[base + j * 16 + lr] = f2bf(acc[i][j][r] * inv);
            }
        }
    }
}

// ---------------- mean pool accumulate (x1 contribution) ----------------
__global__ __launch_bounds__(256) void pool_kernel(
    const float* __restrict__ xf, float* __restrict__ pooled, int gbase)
{
    const int row0 = blockIdx.x * 256;
    const int b = (gbase + row0) >> 13;
    const int t = threadIdx.x;
    float a0 = 0.f, a1 = 0.f;
    const size_t base = (size_t)row0 * 512;
    for (int s = 0; s < 256; ++s) {
        a0 += xf[base + (size_t)s * 512 + t];
        a1 += xf[base + (size_t)s * 512 + t + 256];
    }
    atomicAdd(&pooled[b * 512 + t], a0);
    atomicAdd(&pooled[b * 512 + t + 256], a1);
}

// ---------------- classifier head ----------------
__global__ __launch_bounds__(256) void head_kernel(
    const float* __restrict__ pooled, const void* __restrict__ Wc,
    const void* __restrict__ bc, void* __restrict__ out, const int* __restrict__ flag)
{
    const int f = *flag;
    const int t = threadIdx.x;
    const int grp = t >> 4, ln = t & 15;
    const int b = grp >> 1, c = grp & 1;
    float p = 0.f;
    for (int d = ln; d < 512; d += 16)
        p += pooled[b * 512 + d] * loadElem(Wc, (size_t)d * 2 + c, f);
    #pragma unroll
    for (int off = 8; off; off >>= 1) p += __shfl_xor(p, off, 64);
    if (ln == 0) {
        const float val = p * (1.0f / 8192.0f) + loadElem(bc, c, f);
        if (f) ((float*)out)[b * 2 + c] = val;
        else   ((__hip_bfloat16*)out)[b * 2 + c] = f2bf(val);
    }
}

// ---------------- launch ----------------
extern "C" void kernel_launch(void* const* d_in, const int* in_sizes, int n_in,
                              void* d_out, int out_size, void* d_ws, size_t ws_size,
                              hipStream_t stream)
{
    const int* ids   = (const int*)d_in[0];
    const void* emb  = d_in[1];
    const void* Wq   = d_in[2];
    const void* Wk   = d_in[3];
    const void* Wv   = d_in[4];
    const void* Wph  = d_in[5];
    const void* Wo   = d_in[6];
    const void* g1   = d_in[7];
    const void* g2   = d_in[8];
    const void* Wg   = d_in[9];
    const void* Wu   = d_in[10];
    const void* Wd   = d_in[11];
    const void* Wc   = d_in[12];
    const void* bc   = d_in[13];

    char* ws = (char*)d_ws;
    __hip_bfloat16* WQPt  = (__hip_bfloat16*)(ws + OFF_WQPT);  // [WQPt|WKPt|WvT] = [768][512]
    __hip_bfloat16* WKPt  = (__hip_bfloat16*)(ws + OFF_WKPT);
    __hip_bfloat16* WvT   = (__hip_bfloat16*)(ws + OFF_WVT);
    __hip_bfloat16* WoT   = (__hip_bfloat16*)(ws + OFF_WOT);
    __hip_bfloat16* WgT   = (__hip_bfloat16*)(ws + OFF_WGT);
    __hip_bfloat16* WuT   = (__hip_bfloat16*)(ws + OFF_WUT);
    float*          kv    = (float*)(ws + OFF_KV);
    float*          z     = (float*)(ws + OFF_Z);
    float*          pooled= (float*)(ws + OFF_POOL);
    float*          tsum  = (float*)(ws + OFF_TSUM);
    int*            flag  = (int*)(ws + OFF_FLAG);
    __hip_bfloat16* pqall = (__hip_bfloat16*)(ws + OFF_PQALL); // bf16 [NTOK][512]

    // ---- adaptive chunk: largest power-of-2 C in [256, 32768] that fits ws ----
    int C = 32768;
    while (C > 256 && CHUNKBASE + PERTOK * (size_t)C > ws_size) C >>= 1;
    const int NC = NTOK / C;

    char* cb = ws + CHUNKBASE;
    float*          xf   = (float*)cb;                                  // f32  [C][512]
    __hip_bfloat16* h    = (__hip_bfloat16*)(cb + (size_t)C * 2048);    // bf16 [C][512]
    __hip_bfloat16* attn = (__hip_bfloat16*)(cb + (size_t)C * 3072);    // bf16 [C][512]
    __hip_bfloat16* pkv  = (__hip_bfloat16*)(cb + (size_t)C * 4096);    // bf16 [C][256]  pk|v

    detect_kernel<<<1, 128, 0, stream>>>((const unsigned int*)Wph, flag);
    zero_kernel<<<(ZERO_FLOATS + 255) / 256, 256, 0, stream>>>(kv, ZERO_FLOATS);

    // weight prep (WdT no longer needed — Wd used directly in ffn_pool)
    fuse_phi_kernel<<<1024, 256, 0, stream>>>(Wq, Wph, WQPt, 512, flag);
    fuse_phi_kernel<<<256, 256, 0, stream>>>(Wk, Wph, WKPt, 128, flag);
    transpose_kernel<<<dim3(128 / 32, 512 / 32), 256, 0, stream>>>(Wv, WvT, 512, 128, flag);
    transpose_kernel<<<dim3(512 / 32, 512 / 32), 256, 0, stream>>>(Wo, WoT, 512, 512, flag);
    transpose_kernel<<<dim3(2048 / 32, 512 / 32), 256, 0, stream>>>(Wg, WgT, 512, 2048, flag);
    transpose_kernel<<<dim3(2048 / 32, 512 / 32), 256, 0, stream>>>(Wu, WuT, 512, 2048, flag);

    // ---- pass A: pq (all tokens) + per-chunk pk|v -> accumulate global kv / z ----
    for (int c = 0; c < NC; ++c) {
        const int g0 = c * C;
        embed_rms_kernel<<<C / 4, 256, 0, stream>>>(ids + g0, emb, g1, xf, h, flag, 0, 1);
        // combined [pq | pk | v] GEMM: B = [WQPt;WKPt;WvT] rows 0..767
        gemm128_kernel<5><<<dim3(C / 128, 6), 256, 0, stream>>>(
            h, WQPt, pqall + (size_t)g0 * 512, pkv, 512, 512);
        kv_z_kernel<<<dim3(C / 128, 2), 256, 0, stream>>>(pkv, kv, z, g0, 128);
    }

    // ---- pass B: per chunk -> mix, +Wo, pool(x1)+rms, fused SwiGLU -> tsum ----
    for (int c = 0; c < NC; ++c) {
        const int g0 = c * C;
        embed_rms_kernel<<<C / 4, 256, 0, stream>>>(ids + g0, emb, g1, xf, h, flag, 1, 0);
        attn_mix_kernel<<<dim3(C / 128, 2), 256, 0, stream>>>(
            pqall + (size_t)g0 * 512, kv, z, attn, g0);
        gemm128_kernel<2><<<dim3(C / 128, 4), 256, 0, stream>>>(
            attn, WoT, xf, nullptr, 512, 512);
        pool_kernel<<<C / 256, 256, 0, stream>>>(xf, pooled, g0);       // x1 contribution
        rms2_kernel<<<C / 4, 256, 0, stream>>>(xf, g2, h, flag);
        dim3 gg(C / 128, 16);
        gemm_ffn_kernel<<<gg, 256, 0, stream>>>(h, WgT, WuT, tsum, g0, 512);
    }

    // pooled += tsum @ Wd  (exact: pooling is linear; k-split parallel)
    ffn_pool_kernel<<<32, 256, 0, stream>>>(tsum, Wd, pooled, flag);

    head_kernel<<<1, 256, 0, stream>>>(pooled, Wc, bc, d_out, flag);
}

// Round 11
// 1030.266 us; speedup vs baseline: 3.0297x; 1.0574x over previous
//
#include <hip/hip_runtime.h>
#include <hip/hip_bf16.h>
#include <math.h>

// ---------------- types / helpers ----------------
typedef __attribute__((ext_vector_type(8))) short bf16x8;
typedef __attribute__((ext_vector_type(4))) float f32x4;

#define DEV static __device__ __forceinline__
#define AS1 __attribute__((address_space(1)))
#define AS3 __attribute__((address_space(3)))

DEV float bf2f(__hip_bfloat16 v) { return __bfloat162float(v); }
DEV __hip_bfloat16 f2bf(float f) { return __float2bfloat16(f); }
DEV float us2f(unsigned short u) { return __uint_as_float(((unsigned int)u) << 16); }
DEV unsigned short f2us(float f) {
    __hip_bfloat16 b = __float2bfloat16(f);
    return *(unsigned short*)&b;
}

// async global->LDS, 16 B per lane (LDS dst = wave-uniform base + lane*16)
DEV void gload_lds16(const void* g, void* l) {
    __builtin_amdgcn_global_load_lds((const AS1 unsigned int*)g,
                                     (AS3 unsigned int*)l, 16, 0, 0);
}

// load 8 consecutive floats from an input tensor that is either f32 or bf16
DEV void load8(const void* p, size_t off, int f32m, float* o) {
    if (f32m) {
        const float4* r = (const float4*)((const float*)p + off);
        float4 A = r[0], B = r[1];
        o[0] = A.x; o[1] = A.y; o[2] = A.z; o[3] = A.w;
        o[4] = B.x; o[5] = B.y; o[6] = B.z; o[7] = B.w;
    } else {
        const ushort4* r = (const ushort4*)((const __hip_bfloat16*)p + off);
        ushort4 A = r[0], B = r[1];
        o[0] = us2f(A.x); o[1] = us2f(A.y); o[2] = us2f(A.z); o[3] = us2f(A.w);
        o[4] = us2f(B.x); o[5] = us2f(B.y); o[6] = us2f(B.z); o[7] = us2f(B.w);
    }
}

DEV float loadElem(const void* p, size_t idx, int f32m) {
    return f32m ? ((const float*)p)[idx] : bf2f(((const __hip_bfloat16*)p)[idx]);
}

// ---------------- problem constants ----------------
// B=8 S=8192 D=512 H=8 HK=2 DH=64 M=64 DFF=2048 NCLS=2 G=4
constexpr int NTOK = 65536;   // 8*8192

// ---------------- persistent ws layout (bytes) ----------------
constexpr size_t OFF_WQPT = 0;                       // bf16 [512][512]  (Wq@Wphi)^T
constexpr size_t OFF_WKPT = OFF_WQPT + 524288ull;    // bf16 [128][512]  (Wk@Wphi)^T   } contiguous:
constexpr size_t OFF_WVT  = OFF_WKPT + 131072ull;    // bf16 [128][512]  Wv^T          } [768][512] B-matrix
constexpr size_t OFF_WOT  = OFF_WVT  + 131072ull;    // bf16 [512][512]  Wo^T
constexpr size_t OFF_WGT  = OFF_WOT  + 524288ull;    // bf16 [2048][512] Wg^T
constexpr size_t OFF_WUT  = OFF_WGT  + 2097152ull;   // bf16 [2048][512] Wu^T
constexpr size_t OFF_KV   = OFF_WUT  + 2097152ull;   // f32  [8][2][64][64]
constexpr size_t OFF_Z    = OFF_KV   + 262144ull;    // f32  [8][2][64]
constexpr size_t OFF_POOL = OFF_Z    + 4096ull;      // f32  [8][512]
constexpr size_t OFF_TSUM = OFF_POOL + 16384ull;     // f32  [8][2048]  col-sums of FFN t
constexpr size_t OFF_FLAG = OFF_TSUM + 65536ull;     // int  dtype flag (1 = f32 inputs)
constexpr size_t PERSIST  = OFF_FLAG + 256ull;
constexpr size_t OFF_PQALL = PERSIST;                // bf16 [65536][512] pq (all tokens)
constexpr size_t PQALL_SZ  = 67108864ull;
constexpr size_t CHUNKBASE = OFF_PQALL + PQALL_SZ;
constexpr int    ZERO_FLOATS = (262144 + 4096 + 16384 + 65536) / 4;  // kv+z+pooled+tsum
// per-token chunk bytes: xf 2048 + h 1024 + attn 1024 + pkv 512 = 4608
constexpr size_t PERTOK = 4608ull;
// ws check: rounds 3-6 ran C=16384 at PERTOK=13824 => ws >= 234.4 MB;
// C=32768 here needs 75.1 MB + 151.0 MB = 226.1 MB -> fits (runtime-checked anyway).

// ---------------- dtype detection ----------------
__global__ __launch_bounds__(128) void detect_kernel(
    const unsigned int* __restrict__ w, int* __restrict__ flag)
{
    __shared__ int cnt;
    if (threadIdx.x == 0) cnt = 0;
    __syncthreads();
    unsigned int v = w[threadIdx.x];
    float a = fabsf(us2f((unsigned short)(v & 0xFFFFu)));
    if (a >= 0.0625f && a <= 8.0f) atomicAdd(&cnt, 1);
    __syncthreads();
    if (threadIdx.x == 0) *flag = (cnt < 64) ? 1 : 0;
}

// ---------------- tiny init ----------------
__global__ __launch_bounds__(256) void zero_kernel(float* __restrict__ p, int n)
{
    int i = blockIdx.x * 256 + threadIdx.x;
    if (i < n) p[i] = 0.0f;
}

// ---------------- weight prep ----------------
// outT[hm][d] = sum_dh W[d][h*64+dh] * Wphi[dh][m]   (hm = h*64+m), row-major [nh*64][512]
__global__ __launch_bounds__(256) void fuse_phi_kernel(
    const void* __restrict__ W, const void* __restrict__ Wphi,
    __hip_bfloat16* __restrict__ outT, int wld, const int* __restrict__ flag)
{
    const int f = *flag;
    int o = blockIdx.x * 256 + threadIdx.x;   // o = hm*512 + d
    int hm = o >> 9, d = o & 511;
    int h = hm >> 6, m = hm & 63;
    float acc = 0.f;
    if (f) {
        const float* Wf = (const float*)W;
        const float* Pf = (const float*)Wphi;
        #pragma unroll 8
        for (int dh = 0; dh < 64; ++dh)
            acc += Wf[(size_t)d * wld + h * 64 + dh] * Pf[dh * 64 + m];
    } else {
        const __hip_bfloat16* Wb = (const __hip_bfloat16*)W;
        const __hip_bfloat16* Pb = (const __hip_bfloat16*)Wphi;
        #pragma unroll 8
        for (int dh = 0; dh < 64; ++dh)
            acc += bf2f(Wb[(size_t)d * wld + h * 64 + dh]) * bf2f(Pb[dh * 64 + m]);
    }
    outT[o] = f2bf(acc);
}

// dst[Ccols][R] = src[R][Ccols]^T, LDS-tiled 32x32 (R, Ccols multiples of 32)
__global__ __launch_bounds__(256) void transpose_kernel(
    const void* __restrict__ src, __hip_bfloat16* __restrict__ dst, int R, int Ccols,
    const int* __restrict__ flag)
{
    __shared__ float tile[32][33];
    const int f = *flag;
    const int tx = threadIdx.x & 31, ty = threadIdx.x >> 5;   // 32 x 8
    const int c0 = blockIdx.x * 32, r0 = blockIdx.y * 32;
    #pragma unroll
    for (int k = 0; k < 4; ++k) {
        const int rl = ty + k * 8;
        tile[rl][tx] = loadElem(src, (size_t)(r0 + rl) * Ccols + c0 + tx, f);
    }
    __syncthreads();
    #pragma unroll
    for (int k = 0; k < 4; ++k) {
        const int cl = ty + k * 8;
        dst[(size_t)(c0 + cl) * R + r0 + tx] = f2bf(tile[tx][cl]);
    }
}

// ---------------- embedding gather + rmsnorm (wave per row; chunk-local) ----------------
__global__ __launch_bounds__(256) void embed_rms_kernel(
    const int* __restrict__ ids, const void* __restrict__ emb,
    const void* __restrict__ g1, float* __restrict__ xf,
    __hip_bfloat16* __restrict__ h, const int* __restrict__ flag,
    int write_xf, int write_h)
{
    const int f = *flag;
    const int n = blockIdx.x * 4 + (threadIdx.x >> 6);   // local row in chunk
    const int lane = threadIdx.x & 63;
    const int id = ids[n];
    float x[8];
    load8(emb, (size_t)id * 512 + lane * 8, f, x);

    if (write_xf) {
        float4* xo = (float4*)(xf + (size_t)n * 512 + lane * 8);
        xo[0] = make_float4(x[0], x[1], x[2], x[3]);
        xo[1] = make_float4(x[4], x[5], x[6], x[7]);
    }
    if (write_h) {
        float ss = 0.f;
        #pragma unroll
        for (int i = 0; i < 8; ++i) ss += x[i] * x[i];
        #pragma unroll
        for (int off = 32; off; off >>= 1) ss += __shfl_xor(ss, off, 64);
        const float scale = rsqrtf(ss * (1.0f / 512.0f) + 1e-6f);
        float gv[8];
        load8(g1, (size_t)lane * 8, f, gv);
        ushort4 h0, h1;
        h0.x = f2us(x[0] * scale * gv[0]); h0.y = f2us(x[1] * scale * gv[1]);
        h0.z = f2us(x[2] * scale * gv[2]); h0.w = f2us(x[3] * scale * gv[3]);
        h1.x = f2us(x[4] * scale * gv[4]); h1.y = f2us(x[5] * scale * gv[5]);
        h1.z = f2us(x[6] * scale * gv[6]); h1.w = f2us(x[7] * scale * gv[7]);
        ushort4* ho = (ushort4*)(h + (size_t)n * 512 + lane * 8);
        ho[0] = h0; ho[1] = h1;
    }
}

// ---------------- rmsnorm from f32 residual (chunk-local) ----------------
__global__ __launch_bounds__(256) void rms2_kernel(
    const float* __restrict__ xf, const void* __restrict__ g2,
    __hip_bfloat16* __restrict__ h, const int* __restrict__ flag)
{
    const int f = *flag;
    const int n = blockIdx.x * 4 + (threadIdx.x >> 6);
    const int lane = threadIdx.x & 63;
    const float4* xr = (const float4*)(xf + (size_t)n * 512);
    float4 a = xr[lane * 2], b = xr[lane * 2 + 1];
    float x[8] = { a.x, a.y, a.z, a.w, b.x, b.y, b.z, b.w };
    float ss = 0.f;
    #pragma unroll
    for (int i = 0; i < 8; ++i) ss += x[i] * x[i];
    #pragma unroll
    for (int off = 32; off; off >>= 1) ss += __shfl_xor(ss, off, 64);
    const float scale = rsqrtf(ss * (1.0f / 512.0f) + 1e-6f);

    float gv[8];
    load8(g2, (size_t)lane * 8, f, gv);
    ushort4 h0, h1;
    h0.x = f2us(x[0] * scale * gv[0]); h0.y = f2us(x[1] * scale * gv[1]);
    h0.z = f2us(x[2] * scale * gv[2]); h0.w = f2us(x[3] * scale * gv[3]);
    h1.x = f2us(x[4] * scale * gv[4]); h1.y = f2us(x[5] * scale * gv[5]);
    h1.z = f2us(x[6] * scale * gv[6]); h1.w = f2us(x[7] * scale * gv[7]);
    ushort4* ho = (ushort4*)(h + (size_t)n * 512 + lane * 8);
    ho[0] = h0; ho[1] = h1;
}

// ---------------- MFMA GEMM: C[M,N] = A[M,K] @ Bt[N,K]^T ----------------
// m97 structure: 128x128 tile, BK=32, global_load_lds width-16 staging into
// flat [128][32] LDS tiles with XOR bank swizzle; 4 waves (2x2), wave tile
// 64x64 = 4x4 mfma_f32_16x16x32_bf16.
// MODE 5: combined pq|pk|v epilogue: bn 0-3 -> Cout=pq (exp(-|.|), Ncols=512);
//         bn 4 -> Cout2=pkv cols 0..127 (exp); bn 5 -> pkv cols 128..255 (plain)
// MODE 7: Cf32[idx] += acc, AND column sums of the updated values -> pooled[b][col]
template<int MODE>
__global__ __launch_bounds__(256) void gemm128_kernel(
    const __hip_bfloat16* __restrict__ A, const __hip_bfloat16* __restrict__ Bt,
    void* __restrict__ Cout, __hip_bfloat16* __restrict__ Cout2,
    float* __restrict__ pooled, int gbase, int K, int Ncols)
{
    __shared__ __align__(16) char As[8192];   // bf16 [128 rows][32 k], swizzled chunks
    __shared__ __align__(16) char Bs[8192];

    const int tid = threadIdx.x;
    const int bm = blockIdx.x, bn = blockIdx.y;
    const int wave = tid >> 6, lane = tid & 63;
    const int quad = lane >> 4, lr = lane & 15;
    const int wm = (wave >> 1) << 6, wn = (wave & 1) << 6;

    // staging: wave w, instr t in {0,1}; LDS chunk idx = w*128 + t*64 + lane
    const int srow = (wave << 5) + (lane >> 2);          // row for t=0 (t=1: +16)
    const int scol = lane & 3;
    const int sfr  = (srow + (srow >> 2)) & 3;           // == f(srow+16)
    const int sofs = ((scol ^ sfr) << 3);                // swizzled global col (elements)

    const __hip_bfloat16* ga0 = A  + (size_t)(bm * 128 + srow) * K + sofs;
    const __hip_bfloat16* gb0 = Bt + (size_t)(bn * 128 + srow) * K + sofs;
    const __hip_bfloat16* ga1 = ga0 + (size_t)16 * K;
    const __hip_bfloat16* gb1 = gb0 + (size_t)16 * K;
    char* lA0 = As + (wave << 11);
    char* lA1 = lA0 + 1024;
    char* lB0 = Bs + (wave << 11);
    char* lB1 = lB0 + 1024;

    // fragment reads
    const int fl  = (lr + (lr >> 2)) & 3;
    const int ac  = (quad ^ fl) << 4;
    const char* arp = As + ((wm + lr) << 6) + ac;
    const char* brp = Bs + ((wn + lr) << 6) + ac;

    f32x4 acc[4][4];
    #pragma unroll
    for (int i = 0; i < 4; ++i)
        #pragma unroll
        for (int j = 0; j < 4; ++j)
            #pragma unroll
            for (int r = 0; r < 4; ++r) acc[i][j][r] = 0.0f;

    for (int k0 = 0; k0 < K; k0 += 32) {
        __syncthreads();
        gload_lds16(ga0 + k0, lA0);
        gload_lds16(ga1 + k0, lA1);
        gload_lds16(gb0 + k0, lB0);
        gload_lds16(gb1 + k0, lB1);
        __syncthreads();

        bf16x8 af[4], bfr[4];
        #pragma unroll
        for (int i = 0; i < 4; ++i)
            af[i] = *(const bf16x8*)(arp + i * 1024);
        #pragma unroll
        for (int j = 0; j < 4; ++j)
            bfr[j] = *(const bf16x8*)(brp + j * 1024);
        #pragma unroll
        for (int i = 0; i < 4; ++i)
            #pragma unroll
            for (int j = 0; j < 4; ++j)
                acc[i][j] = __builtin_amdgcn_mfma_f32_16x16x32_bf16(af[i], bfr[j], acc[i][j], 0, 0, 0);
    }

    // C/D layout: col = lane&15, row = quad*4 + reg  [m89/m91]
    const int col0 = bn * 128 + wn + lr;
    const int row0 = bm * 128 + wm + quad * 4;

    if (MODE == 7) {
        // RMW xf += acc, plus column sums of the UPDATED xf -> pooled
        const int b = (gbase + bm * 128) >> 13;   // 128 | 8192 -> uniform per block
        #pragma unroll
        for (int j = 0; j < 4; ++j) {
            const int col = col0 + j * 16;
            float s = 0.f;
            #pragma unroll
            for (int i = 0; i < 4; ++i)
                #pragma unroll
                for (int r = 0; r < 4; ++r) {
                    const int row = row0 + i * 16 + r;
                    const size_t idx = (size_t)row * Ncols + col;
                    const float w = ((float*)Cout)[idx] + acc[i][j][r];
                    ((float*)Cout)[idx] = w;
                    s += w;
                }
            s += __shfl_xor(s, 16, 64);
            s += __shfl_xor(s, 32, 64);
            if (quad == 0) atomicAdd(&pooled[b * 512 + col], s);
        }
        return;
    }

    #pragma unroll
    for (int i = 0; i < 4; ++i)
        #pragma unroll
        for (int j = 0; j < 4; ++j) {
            const int col = col0 + j * 16;
            #pragma unroll
            for (int r = 0; r < 4; ++r) {
                const int row = row0 + i * 16 + r;
                const float v = acc[i][j][r];
                // MODE 5
                if (bn < 4) {
                    ((__hip_bfloat16*)Cout)[(size_t)row * 512 + col] =
                        f2bf(expf(-fabsf(v)));
                } else {
                    const int c2 = col - 512;   // 0..255
                    Cout2[(size_t)row * 256 + c2] =
                        f2bf(bn == 4 ? expf(-fabsf(v)) : v);
                }
            }
        }
}

// ---------------- fused SwiGLU up-GEMM + column-sum (BK=64) ----------------
// t = silu(A@Wg^T) * (A@Wu^T); no t materialization — accumulate column sums
// of t (per batch) into tsum[b][2048]:  sum_rows(t@Wd) == (sum_rows t)@Wd.
// BK=64: two 8 KB k-sub-tiles per matrix (48 KB LDS); halves barrier count.
// Occupancy is register-bound at 2 blocks/CU (128 acc regs), so 48 KB is free.
__global__ __launch_bounds__(256, 2) void gemm_ffn_kernel(
    const __hip_bfloat16* __restrict__ A, const __hip_bfloat16* __restrict__ Bg,
    const __hip_bfloat16* __restrict__ Bu, float* __restrict__ tsum,
    int gbase, int K)
{
    __shared__ __align__(16) char As[16384];
    __shared__ __align__(16) char Gs[16384];
    __shared__ __align__(16) char Us[16384];

    const int tid = threadIdx.x;
    const int bm = blockIdx.x, bn = blockIdx.y;
    const int wave = tid >> 6, lane = tid & 63;
    const int quad = lane >> 4, lr = lane & 15;
    const int wm = (wave >> 1) << 6, wn = (wave & 1) << 6;

    const int srow = (wave << 5) + (lane >> 2);
    const int scol = lane & 3;
    const int sfr  = (srow + (srow >> 2)) & 3;
    const int sofs = ((scol ^ sfr) << 3);

    const __hip_bfloat16* ga0 = A  + (size_t)(bm * 128 + srow) * K + sofs;
    const __hip_bfloat16* gg0 = Bg + (size_t)(bn * 128 + srow) * K + sofs;
    const __hip_bfloat16* gu0 = Bu + (size_t)(bn * 128 + srow) * K + sofs;
    const __hip_bfloat16* ga1 = ga0 + (size_t)16 * K;
    const __hip_bfloat16* gg1 = gg0 + (size_t)16 * K;
    const __hip_bfloat16* gu1 = gu0 + (size_t)16 * K;
    char* lA0 = As + (wave << 11);
    char* lG0 = Gs + (wave << 11);
    char* lU0 = Us + (wave << 11);

    const int fl  = (lr + (lr >> 2)) & 3;
    const int ac  = (quad ^ fl) << 4;
    const char* arp = As + ((wm + lr) << 6) + ac;
    const char* grp = Gs + ((wn + lr) << 6) + ac;
    const char* urp = Us + ((wn + lr) << 6) + ac;

    f32x4 accG[4][4], accU[4][4];
    #pragma unroll
    for (int i = 0; i < 4; ++i)
        #pragma unroll
        for (int j = 0; j < 4; ++j)
            #pragma unroll
            for (int r = 0; r < 4; ++r) { accG[i][j][r] = 0.0f; accU[i][j][r] = 0.0f; }

    for (int k0 = 0; k0 < K; k0 += 64) {
        __syncthreads();
        // sub-tile 0: k in [k0, k0+32); sub-tile 1 (+8192 B): k in [k0+32, k0+64)
        gload_lds16(ga0 + k0,      lA0);
        gload_lds16(ga1 + k0,      lA0 + 1024);
        gload_lds16(ga0 + k0 + 32, lA0 + 8192);
        gload_lds16(ga1 + k0 + 32, lA0 + 8192 + 1024);
        gload_lds16(gg0 + k0,      lG0);
        gload_lds16(gg1 + k0,      lG0 + 1024);
        gload_lds16(gg0 + k0 + 32, lG0 + 8192);
        gload_lds16(gg1 + k0 + 32, lG0 + 8192 + 1024);
        gload_lds16(gu0 + k0,      lU0);
        gload_lds16(gu1 + k0,      lU0 + 1024);
        gload_lds16(gu0 + k0 + 32, lU0 + 8192);
        gload_lds16(gu1 + k0 + 32, lU0 + 8192 + 1024);
        __syncthreads();

        #pragma unroll
        for (int kk = 0; kk < 2; ++kk) {
            const int so = kk * 8192;
            bf16x8 af[4], bgf[4], buf_[4];
            #pragma unroll
            for (int i = 0; i < 4; ++i)
                af[i] = *(const bf16x8*)(arp + so + i * 1024);
            #pragma unroll
            for (int j = 0; j < 4; ++j) {
                bgf[j]  = *(const bf16x8*)(grp + so + j * 1024);
                buf_[j] = *(const bf16x8*)(urp + so + j * 1024);
            }
            #pragma unroll
            for (int i = 0; i < 4; ++i)
                #pragma unroll
                for (int j = 0; j < 4; ++j) {
                    accG[i][j] = __builtin_amdgcn_mfma_f32_16x16x32_bf16(af[i], bgf[j],  accG[i][j], 0, 0, 0);
                    accU[i][j] = __builtin_amdgcn_mfma_f32_16x16x32_bf16(af[i], buf_[j], accU[i][j], 0, 0, 0);
                }
        }
    }

    // epilogue: column sums of silu(G)*U over this block's 128 rows
    // col = bn*128 + wn + lr + j*16 (quad-pure); batch uniform per block.
    const int b = (gbase + bm * 128) >> 13;   // 128 | 8192
    #pragma unroll
    for (int j = 0; j < 4; ++j) {
        float s = 0.f;
        #pragma unroll
        for (int i = 0; i < 4; ++i)
            #pragma unroll
            for (int r = 0; r < 4; ++r) {
                const float g = accG[i][j][r];
                s += (g / (1.0f + expf(-g))) * accU[i][j][r];
            }
        s += __shfl_xor(s, 16, 64);
        s += __shfl_xor(s, 32, 64);
        if (quad == 0)
            atomicAdd(&tsum[b * 2048 + bn * 128 + wn + lr + j * 16], s);
    }
}

// ---------------- pooled[b][:] += tsum[b][:] @ Wd  (k-split parallel) ----------------
__global__ __launch_bounds__(256) void ffn_pool_kernel(
    const float* __restrict__ tsum, const void* __restrict__ Wd,
    float* __restrict__ pooled, const int* __restrict__ flag)
{
    __shared__ float ts[8][64];
    const int f = *flag;
    const int k0 = blockIdx.x * 64;
    const int t = threadIdx.x;
    for (int i = t; i < 512; i += 256)
        ts[i >> 6][i & 63] = tsum[(i >> 6) * 2048 + k0 + (i & 63)];
    __syncthreads();

    float acc0[8] = {}, acc1[8] = {};
    for (int kk = 0; kk < 64; ++kk) {
        const size_t krow = (size_t)(k0 + kk) * 512;
        const float w0 = loadElem(Wd, krow + t, f);
        const float w1 = loadElem(Wd, krow + t + 256, f);
        #pragma unroll
        for (int b = 0; b < 8; ++b) {
            acc0[b] += ts[b][kk] * w0;
            acc1[b] += ts[b][kk] * w1;
        }
    }
    #pragma unroll
    for (int b = 0; b < 8; ++b) {
        atomicAdd(&pooled[b * 512 + t], acc0[b]);
        atomicAdd(&pooled[b * 512 + t + 256], acc1[b]);
    }
}

// ---------------- kv / z global-state reduction (pkv [C][256] input) ----------------
__global__ __launch_bounds__(256) void kv_z_kernel(
    const __hip_bfloat16* __restrict__ pkv,
    float* __restrict__ kv, float* __restrict__ z, int gbase, int nrows)
{
    __shared__ float pks[8][64], vs[8][64];
    const int slab = blockIdx.x, kh = blockIdx.y;
    const int b = (gbase + slab * nrows) >> 13;   // nrows | 8192 -> uniform per block
    const int tid = threadIdx.x;
    const int tm = (tid & 15) << 2, tdh = (tid >> 4) << 2;
    const int lss = tid >> 5, lmm = (tid & 31) << 1;

    float acc[4][4] = {};
    float zacc[4] = {};
    for (int sb = 0; sb < nrows; sb += 8) {
        __syncthreads();
        {
            const size_t n = (size_t)slab * nrows + sb + lss;   // local row
            const __hip_bfloat16* pr = pkv + n * 256 + kh * 64 + lmm;        // pk cols 0..127
            const __hip_bfloat16* vr = pkv + n * 256 + 128 + kh * 64 + lmm;  // v  cols 128..255
            pks[lss][lmm]     = bf2f(pr[0]);
            pks[lss][lmm + 1] = bf2f(pr[1]);
            vs[lss][lmm]      = bf2f(vr[0]);
            vs[lss][lmm + 1]  = bf2f(vr[1]);
        }
        __syncthreads();
        #pragma unroll
        for (int ss = 0; ss < 8; ++ss) {
            f32x4 p = *(const f32x4*)&pks[ss][tm];
            f32x4 w = *(const f32x4*)&vs[ss][tdh];
            #pragma unroll
            for (int i = 0; i < 4; ++i)
                #pragma unroll
                for (int j = 0; j < 4; ++j)
                    acc[i][j] += p[i] * w[j];
            if ((tid >> 4) == 0) {
                #pragma unroll
                for (int i = 0; i < 4; ++i) zacc[i] += p[i];
            }
        }
    }
    #pragma unroll
    for (int i = 0; i < 4; ++i)
        #pragma unroll
        for (int j = 0; j < 4; ++j)
            atomicAdd(&kv[(((size_t)b * 2 + kh) * 64 + tm + i) * 64 + tdh + j], acc[i][j]);
    if ((tid >> 4) == 0) {
        #pragma unroll
        for (int i = 0; i < 4; ++i)
            atomicAdd(&z[((size_t)b * 2 + kh) * 64 + tm + i], zacc[i]);
    }
}

// ---------------- attention mix (MFMA): attn = (pq @ kv) / (pq @ z + eps) ----------------
__global__ __launch_bounds__(256) void attn_mix_kernel(
    const __hip_bfloat16* __restrict__ pq, const float* __restrict__ kvf,
    const float* __restrict__ zf, __hip_bfloat16* __restrict__ attn, int gbase)
{
    __shared__ __align__(16) __hip_bfloat16 kvT[80][72];
    const int kh = blockIdx.y;
    const int row0b = blockIdx.x * 128;
    const int b = (gbase + row0b) >> 13;
    const int tid = threadIdx.x;

    const float* kvsrc = kvf + ((size_t)b * 2 + kh) * 4096;
    for (int i = tid; i < 4096; i += 256) {
        const int m = i >> 6, dh = i & 63;
        kvT[dh][m] = f2bf(kvsrc[i]);
    }
    if (tid < 64) kvT[64][tid] = f2bf(zf[((size_t)b * 2 + kh) * 64 + tid]);
    for (int i = tid; i < 15 * 64; i += 256) {
        const int rr = 65 + (i >> 6), m = i & 63;
        kvT[rr][m] = f2bf(0.0f);
    }
    __syncthreads();

    const int wave = tid >> 6, lane = tid & 63;
    const int quad = lane >> 4, lr = lane & 15;
    const int wm = (wave >> 1) << 6;
    const int whead = (wave & 1) << 1;

    #pragma unroll
    for (int g2 = 0; g2 < 2; ++g2) {
        const int hh = kh * 4 + whead + g2;
        f32x4 acc[4][5];
        #pragma unroll
        for (int i = 0; i < 4; ++i)
            #pragma unroll
            for (int j = 0; j < 5; ++j)
                #pragma unroll
                for (int r = 0; r < 4; ++r) acc[i][j][r] = 0.0f;

        #pragma unroll
        for (int kk = 0; kk < 2; ++kk) {
            const int kofs = kk * 32 + quad * 8;
            bf16x8 af[4], bfr[5];
            #pragma unroll
            for (int i = 0; i < 4; ++i)
                af[i] = *(const bf16x8*)(pq + (size_t)(row0b + wm + i * 16 + lr) * 512
                                            + hh * 64 + kofs);
            #pragma unroll
            for (int j = 0; j < 5; ++j)
                bfr[j] = *(const bf16x8*)&kvT[j * 16 + lr][kofs];
            #pragma unroll
            for (int i = 0; i < 4; ++i)
                #pragma unroll
                for (int j = 0; j < 5; ++j)
                    acc[i][j] = __builtin_amdgcn_mfma_f32_16x16x32_bf16(af[i], bfr[j], acc[i][j], 0, 0, 0);
        }

        const int colb = hh * 64;
        #pragma unroll
        for (int i = 0; i < 4; ++i) {
            const int rowb = row0b + wm + i * 16 + quad * 4;
            #pragma unroll
            for (int r = 0; r < 4; ++r) {
                const float den = __shfl(acc[i][4][r], lane & 48, 64);
                const float inv = 1.0f / (den + 1e-6f);
                const size_t base = (size_t)(rowb + r) * 512 + colb;
                #pragma unroll
                for (int j = 0; j < 4; ++j)
                    attn[base + j * 16 + lr] = f2bf(acc[i][j][r] * inv);
            }
        }
    }
}

// ---------------- classifier head ----------------
__global__ __launch_bounds__(256) void head_kernel(
    const float* __restrict__ pooled, const void* __restrict__ Wc,
    const void* __restrict__ bc, void* __restrict__ out, const int* __restrict__ flag)
{
    const int f = *flag;
    const int t = threadIdx.x;
    const int grp = t >> 4, ln = t & 15;
    const int b = grp >> 1, c = grp & 1;
    float p = 0.f;
    for (int d = ln; d < 512; d += 16)
        p += pooled[b * 512 + d] * loadElem(Wc, (size_t)d * 2 + c, f);
    #pragma unroll
    for (int off = 8; off; off >>= 1) p += __shfl_xor(p, off, 64);
    if (ln == 0) {
        const float val = p * (1.0f / 8192.0f) + loadElem(bc, c, f);
        if (f) ((float*)out)[b * 2 + c] = val;
        else   ((__hip_bfloat16*)out)[b * 2 + c] = f2bf(val);
    }
}

// ---------------- launch ----------------
extern "C" void kernel_launch(void* const* d_in, const int* in_sizes, int n_in,
                              void* d_out, int out_size, void* d_ws, size_t ws_size,
                              hipStream_t stream)
{
    const int* ids   = (const int*)d_in[0];
    const void* emb  = d_in[1];
    const void* Wq   = d_in[2];
    const void* Wk   = d_in[3];
    const void* Wv   = d_in[4];
    const void* Wph  = d_in[5];
    const void* Wo   = d_in[6];
    const void* g1   = d_in[7];
    const void* g2   = d_in[8];
    const void* Wg   = d_in[9];
    const void* Wu   = d_in[10];
    const void* Wd   = d_in[11];
    const void* Wc   = d_in[12];
    const void* bc   = d_in[13];

    char* ws = (char*)d_ws;
    __hip_bfloat16* WQPt  = (__hip_bfloat16*)(ws + OFF_WQPT);  // [WQPt|WKPt|WvT] = [768][512]
    __hip_bfloat16* WKPt  = (__hip_bfloat16*)(ws + OFF_WKPT);
    __hip_bfloat16* WvT   = (__hip_bfloat16*)(ws + OFF_WVT);
    __hip_bfloat16* WoT   = (__hip_bfloat16*)(ws + OFF_WOT);
    __hip_bfloat16* WgT   = (__hip_bfloat16*)(ws + OFF_WGT);
    __hip_bfloat16* WuT   = (__hip_bfloat16*)(ws + OFF_WUT);
    float*          kv    = (float*)(ws + OFF_KV);
    float*          z     = (float*)(ws + OFF_Z);
    float*          pooled= (float*)(ws + OFF_POOL);
    float*          tsum  = (float*)(ws + OFF_TSUM);
    int*            flag  = (int*)(ws + OFF_FLAG);
    __hip_bfloat16* pqall = (__hip_bfloat16*)(ws + OFF_PQALL); // bf16 [NTOK][512]

    // ---- adaptive chunk: largest power-of-2 C in [256, 32768] that fits ws ----
    int C = 32768;
    while (C > 256 && CHUNKBASE + PERTOK * (size_t)C > ws_size) C >>= 1;
    const int NC = NTOK / C;

    char* cb = ws + CHUNKBASE;
    float*          xf   = (float*)cb;                                  // f32  [C][512]
    __hip_bfloat16* h    = (__hip_bfloat16*)(cb + (size_t)C * 2048);    // bf16 [C][512]
    __hip_bfloat16* attn = (__hip_bfloat16*)(cb + (size_t)C * 3072);    // bf16 [C][512]
    __hip_bfloat16* pkv  = (__hip_bfloat16*)(cb + (size_t)C * 4096);    // bf16 [C][256]  pk|v

    detect_kernel<<<1, 128, 0, stream>>>((const unsigned int*)Wph, flag);
    zero_kernel<<<(ZERO_FLOATS + 255) / 256, 256, 0, stream>>>(kv, ZERO_FLOATS);

    // weight prep
    fuse_phi_kernel<<<1024, 256, 0, stream>>>(Wq, Wph, WQPt, 512, flag);
    fuse_phi_kernel<<<256, 256, 0, stream>>>(Wk, Wph, WKPt, 128, flag);
    transpose_kernel<<<dim3(128 / 32, 512 / 32), 256, 0, stream>>>(Wv, WvT, 512, 128, flag);
    transpose_kernel<<<dim3(512 / 32, 512 / 32), 256, 0, stream>>>(Wo, WoT, 512, 512, flag);
    transpose_kernel<<<dim3(2048 / 32, 512 / 32), 256, 0, stream>>>(Wg, WgT, 512, 2048, flag);
    transpose_kernel<<<dim3(2048 / 32, 512 / 32), 256, 0, stream>>>(Wu, WuT, 512, 2048, flag);

    // ---- pass A: pq (all tokens) + per-chunk pk|v -> accumulate global kv / z ----
    for (int c = 0; c < NC; ++c) {
        const int g0 = c * C;
        embed_rms_kernel<<<C / 4, 256, 0, stream>>>(ids + g0, emb, g1, xf, h, flag, 0, 1);
        // combined [pq | pk | v] GEMM: B = [WQPt;WKPt;WvT] rows 0..767
        gemm128_kernel<5><<<dim3(C / 128, 6), 256, 0, stream>>>(
            h, WQPt, pqall + (size_t)g0 * 512, pkv, nullptr, 0, 512, 512);
        kv_z_kernel<<<dim3(C / 128, 2), 256, 0, stream>>>(pkv, kv, z, g0, 128);
    }

    // ---- pass B: per chunk -> mix, +Wo(+pool fused), rms, fused SwiGLU -> tsum ----
    for (int c = 0; c < NC; ++c) {
        const int g0 = c * C;
        embed_rms_kernel<<<C / 4, 256, 0, stream>>>(ids + g0, emb, g1, xf, h, flag, 1, 0);
        attn_mix_kernel<<<dim3(C / 128, 2), 256, 0, stream>>>(
            pqall + (size_t)g0 * 512, kv, z, attn, g0);
        // Wo GEMM with fused x1 mean-pool contribution (MODE 7)
        gemm128_kernel<7><<<dim3(C / 128, 4), 256, 0, stream>>>(
            attn, WoT, xf, nullptr, pooled, g0, 512, 512);
        rms2_kernel<<<C / 4, 256, 0, stream>>>(xf, g2, h, flag);
        dim3 gg(C / 128, 16);
        gemm_ffn_kernel<<<gg, 256, 0, stream>>>(h, WgT, WuT, tsum, g0, 512);
    }

    // pooled += tsum @ Wd  (exact: pooling is linear; k-split parallel)
    ffn_pool_kernel<<<32, 256, 0, stream>>>(tsum, Wd, pooled, flag);

    head_kernel<<<1, 256, 0, stream>>>(pooled, Wc, bc, d_out, flag);
}

// Round 12
// 964.689 us; speedup vs baseline: 3.2357x; 1.0680x over previous
//
#include <hip/hip_runtime.h>
#include <hip/hip_bf16.h>
#include <math.h>

// ---------------- types / helpers ----------------
typedef __attribute__((ext_vector_type(8))) short bf16x8;
typedef __attribute__((ext_vector_type(4))) float f32x4;

#define DEV static __device__ __forceinline__
#define AS1 __attribute__((address_space(1)))
#define AS3 __attribute__((address_space(3)))

DEV float bf2f(__hip_bfloat16 v) { return __bfloat162float(v); }
DEV __hip_bfloat16 f2bf(float f) { return __float2bfloat16(f); }
DEV float us2f(unsigned short u) { return __uint_as_float(((unsigned int)u) << 16); }
DEV unsigned short f2us(float f) {
    __hip_bfloat16 b = __float2bfloat16(f);
    return *(unsigned short*)&b;
}

// async global->LDS, 16 B per lane (LDS dst = wave-uniform base + lane*16)
DEV void gload_lds16(const void* g, void* l) {
    __builtin_amdgcn_global_load_lds((const AS1 unsigned int*)g,
                                     (AS3 unsigned int*)l, 16, 0, 0);
}

// load 8 consecutive floats from an input tensor that is either f32 or bf16
DEV void load8(const void* p, size_t off, int f32m, float* o) {
    if (f32m) {
        const float4* r = (const float4*)((const float*)p + off);
        float4 A = r[0], B = r[1];
        o[0] = A.x; o[1] = A.y; o[2] = A.z; o[3] = A.w;
        o[4] = B.x; o[5] = B.y; o[6] = B.z; o[7] = B.w;
    } else {
        const ushort4* r = (const ushort4*)((const __hip_bfloat16*)p + off);
        ushort4 A = r[0], B = r[1];
        o[0] = us2f(A.x); o[1] = us2f(A.y); o[2] = us2f(A.z); o[3] = us2f(A.w);
        o[4] = us2f(B.x); o[5] = us2f(B.y); o[6] = us2f(B.z); o[7] = us2f(B.w);
    }
}

DEV float loadElem(const void* p, size_t idx, int f32m) {
    return f32m ? ((const float*)p)[idx] : bf2f(((const __hip_bfloat16*)p)[idx]);
}

// ---------------- problem constants ----------------
// B=8 S=8192 D=512 H=8 HK=2 DH=64 M=64 DFF=2048 NCLS=2 G=4
constexpr int NTOK = 65536;   // 8*8192

// ---------------- persistent ws layout (bytes) ----------------
constexpr size_t OFF_WQPT = 0;                       // bf16 [512][512]  (Wq@Wphi)^T
constexpr size_t OFF_WKPT = OFF_WQPT + 524288ull;    // bf16 [128][512]  (Wk@Wphi)^T   } contiguous:
constexpr size_t OFF_WVT  = OFF_WKPT + 131072ull;    // bf16 [128][512]  Wv^T          } [256][512]
constexpr size_t OFF_WOT  = OFF_WVT  + 131072ull;    // bf16 [512][512]  Wo^T
constexpr size_t OFF_WGT  = OFF_WOT  + 524288ull;    // bf16 [2048][512] Wg^T
constexpr size_t OFF_WUT  = OFF_WGT  + 2097152ull;   // bf16 [2048][512] Wu^T
constexpr size_t OFF_KV   = OFF_WUT  + 2097152ull;   // f32  [8][2][64][64]
constexpr size_t OFF_Z    = OFF_KV   + 262144ull;    // f32  [8][2][64]
constexpr size_t OFF_POOL = OFF_Z    + 4096ull;      // f32  [8][512]
constexpr size_t OFF_TSUM = OFF_POOL + 16384ull;     // f32  [8][2048]  col-sums of FFN t
constexpr size_t OFF_FLAG = OFF_TSUM + 65536ull;     // int  dtype flag (1 = f32 inputs)
constexpr size_t PERSIST  = OFF_FLAG + 256ull;
constexpr size_t CHUNKBASE = PERSIST;                // pqall eliminated (pq fused w/ mix)
constexpr int    ZERO_FLOATS = (262144 + 4096 + 16384 + 65536) / 4;  // kv+z+pooled+tsum
// per-token chunk bytes: xf 2048 + h 1024 + attn 1024 + pkv 512 = 4608
constexpr size_t PERTOK = 4608ull;
// ws >= 234.4 MB proven (rounds 3-6). C=32768 needs 8 MB + 151 MB = 159 MB -> fits.

// ---------------- dtype detection ----------------
__global__ __launch_bounds__(128) void detect_kernel(
    const unsigned int* __restrict__ w, int* __restrict__ flag)
{
    __shared__ int cnt;
    if (threadIdx.x == 0) cnt = 0;
    __syncthreads();
    unsigned int v = w[threadIdx.x];
    float a = fabsf(us2f((unsigned short)(v & 0xFFFFu)));
    if (a >= 0.0625f && a <= 8.0f) atomicAdd(&cnt, 1);
    __syncthreads();
    if (threadIdx.x == 0) *flag = (cnt < 64) ? 1 : 0;
}

// ---------------- tiny init ----------------
__global__ __launch_bounds__(256) void zero_kernel(float* __restrict__ p, int n)
{
    int i = blockIdx.x * 256 + threadIdx.x;
    if (i < n) p[i] = 0.0f;
}

// ---------------- weight prep ----------------
// outT[hm][d] = sum_dh W[d][h*64+dh] * Wphi[dh][m]   (hm = h*64+m), row-major [nh*64][512]
__global__ __launch_bounds__(256) void fuse_phi_kernel(
    const void* __restrict__ W, const void* __restrict__ Wphi,
    __hip_bfloat16* __restrict__ outT, int wld, const int* __restrict__ flag)
{
    const int f = *flag;
    int o = blockIdx.x * 256 + threadIdx.x;   // o = hm*512 + d
    int hm = o >> 9, d = o & 511;
    int h = hm >> 6, m = hm & 63;
    float acc = 0.f;
    if (f) {
        const float* Wf = (const float*)W;
        const float* Pf = (const float*)Wphi;
        #pragma unroll 8
        for (int dh = 0; dh < 64; ++dh)
            acc += Wf[(size_t)d * wld + h * 64 + dh] * Pf[dh * 64 + m];
    } else {
        const __hip_bfloat16* Wb = (const __hip_bfloat16*)W;
        const __hip_bfloat16* Pb = (const __hip_bfloat16*)Wphi;
        #pragma unroll 8
        for (int dh = 0; dh < 64; ++dh)
            acc += bf2f(Wb[(size_t)d * wld + h * 64 + dh]) * bf2f(Pb[dh * 64 + m]);
    }
    outT[o] = f2bf(acc);
}

// dst[Ccols][R] = src[R][Ccols]^T, LDS-tiled 32x32
__global__ __launch_bounds__(256) void transpose_kernel(
    const void* __restrict__ src, __hip_bfloat16* __restrict__ dst, int R, int Ccols,
    const int* __restrict__ flag)
{
    __shared__ float tile[32][33];
    const int f = *flag;
    const int tx = threadIdx.x & 31, ty = threadIdx.x >> 5;   // 32 x 8
    const int c0 = blockIdx.x * 32, r0 = blockIdx.y * 32;
    #pragma unroll
    for (int k = 0; k < 4; ++k) {
        const int rl = ty + k * 8;
        tile[rl][tx] = loadElem(src, (size_t)(r0 + rl) * Ccols + c0 + tx, f);
    }
    __syncthreads();
    #pragma unroll
    for (int k = 0; k < 4; ++k) {
        const int cl = ty + k * 8;
        dst[(size_t)(c0 + cl) * R + r0 + tx] = f2bf(tile[tx][cl]);
    }
}

// ---------------- embedding gather + rmsnorm -> h (wave per row) ----------------
__global__ __launch_bounds__(256) void embed_rms_kernel(
    const int* __restrict__ ids, const void* __restrict__ emb,
    const void* __restrict__ g1, __hip_bfloat16* __restrict__ h,
    const int* __restrict__ flag)
{
    const int f = *flag;
    const int n = blockIdx.x * 4 + (threadIdx.x >> 6);   // local row in chunk
    const int lane = threadIdx.x & 63;
    const int id = ids[n];
    float x[8];
    load8(emb, (size_t)id * 512 + lane * 8, f, x);
    float ss = 0.f;
    #pragma unroll
    for (int i = 0; i < 8; ++i) ss += x[i] * x[i];
    #pragma unroll
    for (int off = 32; off; off >>= 1) ss += __shfl_xor(ss, off, 64);
    const float scale = rsqrtf(ss * (1.0f / 512.0f) + 1e-6f);
    float gv[8];
    load8(g1, (size_t)lane * 8, f, gv);
    ushort4 h0, h1;
    h0.x = f2us(x[0] * scale * gv[0]); h0.y = f2us(x[1] * scale * gv[1]);
    h0.z = f2us(x[2] * scale * gv[2]); h0.w = f2us(x[3] * scale * gv[3]);
    h1.x = f2us(x[4] * scale * gv[4]); h1.y = f2us(x[5] * scale * gv[5]);
    h1.z = f2us(x[6] * scale * gv[6]); h1.w = f2us(x[7] * scale * gv[7]);
    ushort4* ho = (ushort4*)(h + (size_t)n * 512 + lane * 8);
    ho[0] = h0; ho[1] = h1;
}

// ---------------- rmsnorm from f32 residual (chunk-local) ----------------
__global__ __launch_bounds__(256) void rms2_kernel(
    const float* __restrict__ xf, const void* __restrict__ g2,
    __hip_bfloat16* __restrict__ h, const int* __restrict__ flag)
{
    const int f = *flag;
    const int n = blockIdx.x * 4 + (threadIdx.x >> 6);
    const int lane = threadIdx.x & 63;
    const float4* xr = (const float4*)(xf + (size_t)n * 512);
    float4 a = xr[lane * 2], b = xr[lane * 2 + 1];
    float x[8] = { a.x, a.y, a.z, a.w, b.x, b.y, b.z, b.w };
    float ss = 0.f;
    #pragma unroll
    for (int i = 0; i < 8; ++i) ss += x[i] * x[i];
    #pragma unroll
    for (int off = 32; off; off >>= 1) ss += __shfl_xor(ss, off, 64);
    const float scale = rsqrtf(ss * (1.0f / 512.0f) + 1e-6f);
    float gv[8];
    load8(g2, (size_t)lane * 8, f, gv);
    ushort4 h0, h1;
    h0.x = f2us(x[0] * scale * gv[0]); h0.y = f2us(x[1] * scale * gv[1]);
    h0.z = f2us(x[2] * scale * gv[2]); h0.w = f2us(x[3] * scale * gv[3]);
    h1.x = f2us(x[4] * scale * gv[4]); h1.y = f2us(x[5] * scale * gv[5]);
    h1.z = f2us(x[6] * scale * gv[6]); h1.w = f2us(x[7] * scale * gv[7]);
    ushort4* ho = (ushort4*)(h + (size_t)n * 512 + lane * 8);
    ho[0] = h0; ho[1] = h1;
}

// ---------------- MFMA GEMM: C[M,N] = A[M,K] @ Bt[N,K]^T ----------------
// m97 structure: 128x128 tile, BK=32, global_load_lds width-16 staging, XOR swizzle.
// MODE 7: xf[row][col] = emb[ids[row]][col] + acc  (residual built in-epilogue),
//         plus column sums of the result -> pooled[b][col]  (Wo GEMM)
// MODE 8: pk|v epilogue: bn==0 -> pkv cols 0..127 = exp(-|acc|); bn==1 -> cols 128..255 = acc
template<int MODE>
__global__ __launch_bounds__(256) void gemm128_kernel(
    const __hip_bfloat16* __restrict__ A, const __hip_bfloat16* __restrict__ Bt,
    float* __restrict__ xf, __hip_bfloat16* __restrict__ Cout2,
    float* __restrict__ pooled, const int* __restrict__ ids,
    const void* __restrict__ emb, const int* __restrict__ flag, int gbase, int K)
{
    __shared__ __align__(16) char As[8192];   // bf16 [128 rows][32 k], swizzled chunks
    __shared__ __align__(16) char Bs[8192];
    __shared__ int idsL[128];

    const int tid = threadIdx.x;
    const int bm = blockIdx.x, bn = blockIdx.y;
    const int wave = tid >> 6, lane = tid & 63;
    const int quad = lane >> 4, lr = lane & 15;
    const int wm = (wave >> 1) << 6, wn = (wave & 1) << 6;

    if (MODE == 7 && tid < 128) idsL[tid] = ids[bm * 128 + tid];

    const int srow = (wave << 5) + (lane >> 2);
    const int scol = lane & 3;
    const int sfr  = (srow + (srow >> 2)) & 3;
    const int sofs = ((scol ^ sfr) << 3);

    const __hip_bfloat16* ga0 = A  + (size_t)(bm * 128 + srow) * K + sofs;
    const __hip_bfloat16* gb0 = Bt + (size_t)(bn * 128 + srow) * K + sofs;
    const __hip_bfloat16* ga1 = ga0 + (size_t)16 * K;
    const __hip_bfloat16* gb1 = gb0 + (size_t)16 * K;
    char* lA0 = As + (wave << 11);
    char* lA1 = lA0 + 1024;
    char* lB0 = Bs + (wave << 11);
    char* lB1 = lB0 + 1024;

    const int fl  = (lr + (lr >> 2)) & 3;
    const int ac  = (quad ^ fl) << 4;
    const char* arp = As + ((wm + lr) << 6) + ac;
    const char* brp = Bs + ((wn + lr) << 6) + ac;

    f32x4 acc[4][4];
    #pragma unroll
    for (int i = 0; i < 4; ++i)
        #pragma unroll
        for (int j = 0; j < 4; ++j)
            #pragma unroll
            for (int r = 0; r < 4; ++r) acc[i][j][r] = 0.0f;

    for (int k0 = 0; k0 < K; k0 += 32) {
        __syncthreads();
        gload_lds16(ga0 + k0, lA0);
        gload_lds16(ga1 + k0, lA1);
        gload_lds16(gb0 + k0, lB0);
        gload_lds16(gb1 + k0, lB1);
        __syncthreads();

        bf16x8 af[4], bfr[4];
        #pragma unroll
        for (int i = 0; i < 4; ++i)
            af[i] = *(const bf16x8*)(arp + i * 1024);
        #pragma unroll
        for (int j = 0; j < 4; ++j)
            bfr[j] = *(const bf16x8*)(brp + j * 1024);
        #pragma unroll
        for (int i = 0; i < 4; ++i)
            #pragma unroll
            for (int j = 0; j < 4; ++j)
                acc[i][j] = __builtin_amdgcn_mfma_f32_16x16x32_bf16(af[i], bfr[j], acc[i][j], 0, 0, 0);
    }

    // C/D layout: col = lane&15, row = quad*4 + reg  [m89/m91]
    const int col0 = bn * 128 + wn + lr;

    if (MODE == 7) {
        const int f = *flag;
        const int b = (gbase + bm * 128) >> 13;   // 128 | 8192 -> uniform per block
        #pragma unroll
        for (int j = 0; j < 4; ++j) {
            const int col = col0 + j * 16;
            float s = 0.f;
            #pragma unroll
            for (int i = 0; i < 4; ++i)
                #pragma unroll
                for (int r = 0; r < 4; ++r) {
                    const int rl = wm + i * 16 + quad * 4 + r;   // local row 0..127
                    const float e = loadElem(emb, (size_t)idsL[rl] * 512 + col, f);
                    const float w = e + acc[i][j][r];
                    xf[(size_t)(bm * 128 + rl) * 512 + col] = w;
                    s += w;
                }
            s += __shfl_xor(s, 16, 64);
            s += __shfl_xor(s, 32, 64);
            if (quad == 0) atomicAdd(&pooled[b * 512 + col], s);
        }
        return;
    }

    // MODE 8: pk|v
    const int row0 = bm * 128 + wm + quad * 4;
    #pragma unroll
    for (int i = 0; i < 4; ++i)
        #pragma unroll
        for (int j = 0; j < 4; ++j) {
            const int col = col0 + j * 16;   // 0..255
            #pragma unroll
            for (int r = 0; r < 4; ++r) {
                const int row = row0 + i * 16 + r;
                const float v = acc[i][j][r];
                Cout2[(size_t)row * 256 + col] = f2bf(bn == 0 ? expf(-fabsf(v)) : v);
            }
        }
}

// ---------------- fused pq-GEMM + attention mix ----------------
// Block (bm, bn): rows bm*128..+127, heads {2bn, 2bn+1} (kh = bn>>1).
// Stage 1: P = exp(-|h @ WQPt^T|) tile 128x128 (m97 K-loop) -> LDS (bf16).
// Stage 2: attn = (P @ kvT) / (P @ z + eps)  (m120 layout round-trip).
__global__ __launch_bounds__(256, 2) void pq_mix_kernel(
    const __hip_bfloat16* __restrict__ h, const __hip_bfloat16* __restrict__ WQPt,
    const float* __restrict__ kvf, const float* __restrict__ zf,
    __hip_bfloat16* __restrict__ attn, int gbase, int K)
{
    __shared__ __align__(16) char As[8192];
    __shared__ __align__(16) char Bs[8192];
    __shared__ __align__(16) char Pl[128 * 272];          // bf16 [128][136] (8-col pad)
    __shared__ __align__(16) __hip_bfloat16 kvT[80][72];

    const int tid = threadIdx.x;
    const int bm = blockIdx.x, bn = blockIdx.y;
    const int kh = bn >> 1;
    const int wave = tid >> 6, lane = tid & 63;
    const int quad = lane >> 4, lr = lane & 15;
    const int wm = (wave >> 1) << 6, wn = (wave & 1) << 6;
    const int b = (gbase + bm * 128) >> 13;               // uniform per block

    // stage kv^T + z (rows 65..79 zero) — ordered by the K-loop's first barrier
    {
        const float* kvsrc = kvf + ((size_t)b * 2 + kh) * 4096;
        for (int i = tid; i < 4096; i += 256) {
            const int m = i >> 6, dh = i & 63;
            kvT[dh][m] = f2bf(kvsrc[i]);
        }
        if (tid < 64) kvT[64][tid] = f2bf(zf[((size_t)b * 2 + kh) * 64 + tid]);
        for (int i = tid; i < 15 * 64; i += 256)
            kvT[65 + (i >> 6)][i & 63] = f2bf(0.0f);
    }

    // ---- stage 1: pq tile ----
    const int srow = (wave << 5) + (lane >> 2);
    const int scol = lane & 3;
    const int sfr  = (srow + (srow >> 2)) & 3;
    const int sofs = ((scol ^ sfr) << 3);

    const __hip_bfloat16* ga0 = h    + (size_t)(bm * 128 + srow) * K + sofs;
    const __hip_bfloat16* gb0 = WQPt + (size_t)(bn * 128 + srow) * K + sofs;
    const __hip_bfloat16* ga1 = ga0 + (size_t)16 * K;
    const __hip_bfloat16* gb1 = gb0 + (size_t)16 * K;
    char* lA0 = As + (wave << 11);
    char* lA1 = lA0 + 1024;
    char* lB0 = Bs + (wave << 11);
    char* lB1 = lB0 + 1024;

    const int fl  = (lr + (lr >> 2)) & 3;
    const int ac  = (quad ^ fl) << 4;
    const char* arp = As + ((wm + lr) << 6) + ac;
    const char* brp = Bs + ((wn + lr) << 6) + ac;

    f32x4 acc[4][4];
    #pragma unroll
    for (int i = 0; i < 4; ++i)
        #pragma unroll
        for (int j = 0; j < 4; ++j)
            #pragma unroll
            for (int r = 0; r < 4; ++r) acc[i][j][r] = 0.0f;

    for (int k0 = 0; k0 < K; k0 += 32) {
        __syncthreads();
        gload_lds16(ga0 + k0, lA0);
        gload_lds16(ga1 + k0, lA1);
        gload_lds16(gb0 + k0, lB0);
        gload_lds16(gb1 + k0, lB1);
        __syncthreads();

        bf16x8 af[4], bfr[4];
        #pragma unroll
        for (int i = 0; i < 4; ++i)
            af[i] = *(const bf16x8*)(arp + i * 1024);
        #pragma unroll
        for (int j = 0; j < 4; ++j)
            bfr[j] = *(const bf16x8*)(brp + j * 1024);
        #pragma unroll
        for (int i = 0; i < 4; ++i)
            #pragma unroll
            for (int j = 0; j < 4; ++j)
                acc[i][j] = __builtin_amdgcn_mfma_f32_16x16x32_bf16(af[i], bfr[j], acc[i][j], 0, 0, 0);
    }

    // P = exp(-|acc|) -> LDS (C-layout write: row = wm+i*16+quad*4+r, col = wn+j*16+lr)
    #pragma unroll
    for (int i = 0; i < 4; ++i)
        #pragma unroll
        for (int j = 0; j < 4; ++j)
            #pragma unroll
            for (int r = 0; r < 4; ++r) {
                const int rl = wm + i * 16 + quad * 4 + r;
                const int cl = wn + j * 16 + lr;
                *(__hip_bfloat16*)(Pl + rl * 272 + cl * 2) = f2bf(expf(-fabsf(acc[i][j][r])));
            }
    __syncthreads();

    // ---- stage 2: attn = (P @ kvT) / (P @ z + eps) ----
    // wave w: rows wm (same), head-local hl = wave&1 (P cols wn..wn+63).
    const int hl = wave & 1;
    f32x4 acc2[4][5];
    #pragma unroll
    for (int i = 0; i < 4; ++i)
        #pragma unroll
        for (int j = 0; j < 5; ++j)
            #pragma unroll
            for (int r = 0; r < 4; ++r) acc2[i][j][r] = 0.0f;

    #pragma unroll
    for (int kk = 0; kk < 2; ++kk) {
        const int kofs = kk * 32 + quad * 8;              // m-offset within head
        bf16x8 af[4], bfr[5];
        #pragma unroll
        for (int i = 0; i < 4; ++i)
            af[i] = *(const bf16x8*)(Pl + (wm + i * 16 + lr) * 272 + (wn + kofs) * 2);
        #pragma unroll
        for (int j = 0; j < 5; ++j)
            bfr[j] = *(const bf16x8*)&kvT[j * 16 + lr][kofs];
        #pragma unroll
        for (int i = 0; i < 4; ++i)
            #pragma unroll
            for (int j = 0; j < 5; ++j)
                acc2[i][j] = __builtin_amdgcn_mfma_f32_16x16x32_bf16(af[i], bfr[j], acc2[i][j], 0, 0, 0);
    }

    const int colb = (bn * 2 + hl) * 64;                  // global head col base
    #pragma unroll
    for (int i = 0; i < 4; ++i) {
        const int rowb = bm * 128 + wm + i * 16 + quad * 4;
        #pragma unroll
        for (int r = 0; r < 4; ++r) {
            const float den = __shfl(acc2[i][4][r], lane & 48, 64);
            const float inv = 1.0f / (den + 1e-6f);
            const size_t base = (size_t)(rowb + r) * 512 + colb;
            #pragma unroll
            for (int j = 0; j < 4; ++j)
                attn[base + j * 16 + lr] = f2bf(acc2[i][j][r] * inv);
        }
    }
}

// ---------------- fused SwiGLU up-GEMM + column-sum (BK=64) ----------------
__global__ __launch_bounds__(256, 2) void gemm_ffn_kernel(
    const __hip_bfloat16* __restrict__ A, const __hip_bfloat16* __restrict__ Bg,
    const __hip_bfloat16* __restrict__ Bu, float* __restrict__ tsum,
    int gbase, int K)
{
    __shared__ __align__(16) char As[16384];
    __shared__ __align__(16) char Gs[16384];
    __shared__ __align__(16) char Us[16384];

    const int tid = threadIdx.x;
    const int bm = blockIdx.x, bn = blockIdx.y;
    const int wave = tid >> 6, lane = tid & 63;
    const int quad = lane >> 4, lr = lane & 15;
    const int wm = (wave >> 1) << 6, wn = (wave & 1) << 6;

    const int srow = (wave << 5) + (lane >> 2);
    const int scol = lane & 3;
    const int sfr  = (srow + (srow >> 2)) & 3;
    const int sofs = ((scol ^ sfr) << 3);

    const __hip_bfloat16* ga0 = A  + (size_t)(bm * 128 + srow) * K + sofs;
    const __hip_bfloat16* gg0 = Bg + (size_t)(bn * 128 + srow) * K + sofs;
    const __hip_bfloat16* gu0 = Bu + (size_t)(bn * 128 + srow) * K + sofs;
    const __hip_bfloat16* ga1 = ga0 + (size_t)16 * K;
    const __hip_bfloat16* gg1 = gg0 + (size_t)16 * K;
    const __hip_bfloat16* gu1 = gu0 + (size_t)16 * K;
    char* lA0 = As + (wave << 11);
    char* lG0 = Gs + (wave << 11);
    char* lU0 = Us + (wave << 11);

    const int fl  = (lr + (lr >> 2)) & 3;
    const int ac  = (quad ^ fl) << 4;
    const char* arp = As + ((wm + lr) << 6) + ac;
    const char* grp = Gs + ((wn + lr) << 6) + ac;
    const char* urp = Us + ((wn + lr) << 6) + ac;

    f32x4 accG[4][4], accU[4][4];
    #pragma unroll
    for (int i = 0; i < 4; ++i)
        #pragma unroll
        for (int j = 0; j < 4; ++j)
            #pragma unroll
            for (int r = 0; r < 4; ++r) { accG[i][j][r] = 0.0f; accU[i][j][r] = 0.0f; }

    for (int k0 = 0; k0 < K; k0 += 64) {
        __syncthreads();
        gload_lds16(ga0 + k0,      lA0);
        gload_lds16(ga1 + k0,      lA0 + 1024);
        gload_lds16(ga0 + k0 + 32, lA0 + 8192);
        gload_lds16(ga1 + k0 + 32, lA0 + 8192 + 1024);
        gload_lds16(gg0 + k0,      lG0);
        gload_lds16(gg1 + k0,      lG0 + 1024);
        gload_lds16(gg0 + k0 + 32, lG0 + 8192);
        gload_lds16(gg1 + k0 + 32, lG0 + 8192 + 1024);
        gload_lds16(gu0 + k0,      lU0);
        gload_lds16(gu1 + k0,      lU0 + 1024);
        gload_lds16(gu0 + k0 + 32, lU0 + 8192);
        gload_lds16(gu1 + k0 + 32, lU0 + 8192 + 1024);
        __syncthreads();

        #pragma unroll
        for (int kk = 0; kk < 2; ++kk) {
            const int so = kk * 8192;
            bf16x8 af[4], bgf[4], buf_[4];
            #pragma unroll
            for (int i = 0; i < 4; ++i)
                af[i] = *(const bf16x8*)(arp + so + i * 1024);
            #pragma unroll
            for (int j = 0; j < 4; ++j) {
                bgf[j]  = *(const bf16x8*)(grp + so + j * 1024);
                buf_[j] = *(const bf16x8*)(urp + so + j * 1024);
            }
            #pragma unroll
            for (int i = 0; i < 4; ++i)
                #pragma unroll
                for (int j = 0; j < 4; ++j) {
                    accG[i][j] = __builtin_amdgcn_mfma_f32_16x16x32_bf16(af[i], bgf[j],  accG[i][j], 0, 0, 0);
                    accU[i][j] = __builtin_amdgcn_mfma_f32_16x16x32_bf16(af[i], buf_[j], accU[i][j], 0, 0, 0);
                }
        }
    }

    const int b = (gbase + bm * 128) >> 13;
    #pragma unroll
    for (int j = 0; j < 4; ++j) {
        float s = 0.f;
        #pragma unroll
        for (int i = 0; i < 4; ++i)
            #pragma unroll
            for (int r = 0; r < 4; ++r) {
                const float g = accG[i][j][r];
                s += (g / (1.0f + expf(-g))) * accU[i][j][r];
            }
        s += __shfl_xor(s, 16, 64);
        s += __shfl_xor(s, 32, 64);
        if (quad == 0)
            atomicAdd(&tsum[b * 2048 + bn * 128 + wn + lr + j * 16], s);
    }
}

// ---------------- pooled[b][:] += tsum[b][:] @ Wd  (k-split parallel) ----------------
__global__ __launch_bounds__(256) void ffn_pool_kernel(
    const float* __restrict__ tsum, const void* __restrict__ Wd,
    float* __restrict__ pooled, const int* __restrict__ flag)
{
    __shared__ float ts[8][64];
    const int f = *flag;
    const int k0 = blockIdx.x * 64;
    const int t = threadIdx.x;
    for (int i = t; i < 512; i += 256)
        ts[i >> 6][i & 63] = tsum[(i >> 6) * 2048 + k0 + (i & 63)];
    __syncthreads();

    float acc0[8] = {}, acc1[8] = {};
    for (int kk = 0; kk < 64; ++kk) {
        const size_t krow = (size_t)(k0 + kk) * 512;
        const float w0 = loadElem(Wd, krow + t, f);
        const float w1 = loadElem(Wd, krow + t + 256, f);
        #pragma unroll
        for (int b = 0; b < 8; ++b) {
            acc0[b] += ts[b][kk] * w0;
            acc1[b] += ts[b][kk] * w1;
        }
    }
    #pragma unroll
    for (int b = 0; b < 8; ++b) {
        atomicAdd(&pooled[b * 512 + t], acc0[b]);
        atomicAdd(&pooled[b * 512 + t + 256], acc1[b]);
    }
}

// ---------------- kv / z global-state reduction (pkv [C][256] input) ----------------
__global__ __launch_bounds__(256) void kv_z_kernel(
    const __hip_bfloat16* __restrict__ pkv,
    float* __restrict__ kv, float* __restrict__ z, int gbase, int nrows)
{
    __shared__ float pks[8][64], vs[8][64];
    const int slab = blockIdx.x, kh = blockIdx.y;
    const int b = (gbase + slab * nrows) >> 13;
    const int tid = threadIdx.x;
    const int tm = (tid & 15) << 2, tdh = (tid >> 4) << 2;
    const int lss = tid >> 5, lmm = (tid & 31) << 1;

    float acc[4][4] = {};
    float zacc[4] = {};
    for (int sb = 0; sb < nrows; sb += 8) {
        __syncthreads();
        {
            const size_t n = (size_t)slab * nrows + sb + lss;
            const __hip_bfloat16* pr = pkv + n * 256 + kh * 64 + lmm;
            const __hip_bfloat16* vr = pkv + n * 256 + 128 + kh * 64 + lmm;
            pks[lss][lmm]     = bf2f(pr[0]);
            pks[lss][lmm + 1] = bf2f(pr[1]);
            vs[lss][lmm]      = bf2f(vr[0]);
            vs[lss][lmm + 1]  = bf2f(vr[1]);
        }
        __syncthreads();
        #pragma unroll
        for (int ss = 0; ss < 8; ++ss) {
            f32x4 p = *(const f32x4*)&pks[ss][tm];
            f32x4 w = *(const f32x4*)&vs[ss][tdh];
            #pragma unroll
            for (int i = 0; i < 4; ++i)
                #pragma unroll
                for (int j = 0; j < 4; ++j)
                    acc[i][j] += p[i] * w[j];
            if ((tid >> 4) == 0) {
                #pragma unroll
                for (int i = 0; i < 4; ++i) zacc[i] += p[i];
            }
        }
    }
    #pragma unroll
    for (int i = 0; i < 4; ++i)
        #pragma unroll
        for (int j = 0; j < 4; ++j)
            atomicAdd(&kv[(((size_t)b * 2 + kh) * 64 + tm + i) * 64 + tdh + j], acc[i][j]);
    if ((tid >> 4) == 0) {
        #pragma unroll
        for (int i = 0; i < 4; ++i)
            atomicAdd(&z[((size_t)b * 2 + kh) * 64 + tm + i], zacc[i]);
    }
}

// ---------------- classifier head ----------------
__global__ __launch_bounds__(256) void head_kernel(
    const float* __restrict__ pooled, const void* __restrict__ Wc,
    const void* __restrict__ bc, void* __restrict__ out, const int* __restrict__ flag)
{
    const int f = *flag;
    const int t = threadIdx.x;
    const int grp = t >> 4, ln = t & 15;
    const int b = grp >> 1, c = grp & 1;
    float p = 0.f;
    for (int d = ln; d < 512; d += 16)
        p += pooled[b * 512 + d] * loadElem(Wc, (size_t)d * 2 + c, f);
    #pragma unroll
    for (int off = 8; off; off >>= 1) p += __shfl_xor(p, off, 64);
    if (ln == 0) {
        const float val = p * (1.0f / 8192.0f) + loadElem(bc, c, f);
        if (f) ((float*)out)[b * 2 + c] = val;
        else   ((__hip_bfloat16*)out)[b * 2 + c] = f2bf(val);
    }
}

// ---------------- launch ----------------
extern "C" void kernel_launch(void* const* d_in, const int* in_sizes, int n_in,
                              void* d_out, int out_size, void* d_ws, size_t ws_size,
                              hipStream_t stream)
{
    const int* ids   = (const int*)d_in[0];
    const void* emb  = d_in[1];
    const void* Wq   = d_in[2];
    const void* Wk   = d_in[3];
    const void* Wv   = d_in[4];
    const void* Wph  = d_in[5];
    const void* Wo   = d_in[6];
    const void* g1   = d_in[7];
    const void* g2   = d_in[8];
    const void* Wg   = d_in[9];
    const void* Wu   = d_in[10];
    const void* Wd   = d_in[11];
    const void* Wc   = d_in[12];
    const void* bc   = d_in[13];

    char* ws = (char*)d_ws;
    __hip_bfloat16* WQPt  = (__hip_bfloat16*)(ws + OFF_WQPT);
    __hip_bfloat16* WKPt  = (__hip_bfloat16*)(ws + OFF_WKPT);  // [WKPt|WvT] = [256][512]
    __hip_bfloat16* WvT   = (__hip_bfloat16*)(ws + OFF_WVT);
    __hip_bfloat16* WoT   = (__hip_bfloat16*)(ws + OFF_WOT);
    __hip_bfloat16* WgT   = (__hip_bfloat16*)(ws + OFF_WGT);
    __hip_bfloat16* WuT   = (__hip_bfloat16*)(ws + OFF_WUT);
    float*          kv    = (float*)(ws + OFF_KV);
    float*          z     = (float*)(ws + OFF_Z);
    float*          pooled= (float*)(ws + OFF_POOL);
    float*          tsum  = (float*)(ws + OFF_TSUM);
    int*            flag  = (int*)(ws + OFF_FLAG);

    // ---- adaptive chunk: largest power-of-2 C in [256, 32768] that fits ws ----
    int C = 32768;
    while (C > 256 && CHUNKBASE + PERTOK * (size_t)C > ws_size) C >>= 1;
    const int NC = NTOK / C;

    char* cb = ws + CHUNKBASE;
    float*          xf   = (float*)cb;                                  // f32  [C][512]
    __hip_bfloat16* h    = (__hip_bfloat16*)(cb + (size_t)C * 2048);    // bf16 [C][512]
    __hip_bfloat16* attn = (__hip_bfloat16*)(cb + (size_t)C * 3072);    // bf16 [C][512]
    __hip_bfloat16* pkv  = (__hip_bfloat16*)(cb + (size_t)C * 4096);    // bf16 [C][256]

    detect_kernel<<<1, 128, 0, stream>>>((const unsigned int*)Wph, flag);
    zero_kernel<<<(ZERO_FLOATS + 255) / 256, 256, 0, stream>>>(kv, ZERO_FLOATS);

    // weight prep
    fuse_phi_kernel<<<1024, 256, 0, stream>>>(Wq, Wph, WQPt, 512, flag);
    fuse_phi_kernel<<<256, 256, 0, stream>>>(Wk, Wph, WKPt, 128, flag);
    transpose_kernel<<<dim3(128 / 32, 512 / 32), 256, 0, stream>>>(Wv, WvT, 512, 128, flag);
    transpose_kernel<<<dim3(512 / 32, 512 / 32), 256, 0, stream>>>(Wo, WoT, 512, 512, flag);
    transpose_kernel<<<dim3(2048 / 32, 512 / 32), 256, 0, stream>>>(Wg, WgT, 512, 2048, flag);
    transpose_kernel<<<dim3(2048 / 32, 512 / 32), 256, 0, stream>>>(Wu, WuT, 512, 2048, flag);

    // ---- pass A: per chunk h -> pk|v -> accumulate global kv / z ----
    for (int c = 0; c < NC; ++c) {
        const int g0 = c * C;
        embed_rms_kernel<<<C / 4, 256, 0, stream>>>(ids + g0, emb, g1, h, flag);
        gemm128_kernel<8><<<dim3(C / 128, 2), 256, 0, stream>>>(
            h, WKPt, nullptr, pkv, nullptr, nullptr, nullptr, flag, g0, 512);
        kv_z_kernel<<<dim3(C / 128, 2), 256, 0, stream>>>(pkv, kv, z, g0, 128);
    }

    // ---- pass B: per chunk h -> fused pq+mix -> Wo(+emb residual,+pool) -> rms -> ffn ----
    for (int c = 0; c < NC; ++c) {
        const int g0 = c * C;
        embed_rms_kernel<<<C / 4, 256, 0, stream>>>(ids + g0, emb, g1, h, flag);
        pq_mix_kernel<<<dim3(C / 128, 4), 256, 0, stream>>>(
            h, WQPt, kv, z, attn, g0, 512);
        gemm128_kernel<7><<<dim3(C / 128, 4), 256, 0, stream>>>(
            attn, WoT, xf, nullptr, pooled, ids + g0, emb, flag, g0, 512);
        rms2_kernel<<<C / 4, 256, 0, stream>>>(xf, g2, h, flag);
        dim3 gg(C / 128, 16);
        gemm_ffn_kernel<<<gg, 256, 0, stream>>>(h, WgT, WuT, tsum, g0, 512);
    }

    // pooled += tsum @ Wd  (exact: pooling is linear; k-split parallel)
    ffn_pool_kernel<<<32, 256, 0, stream>>>(tsum, Wd, pooled, flag);

    head_kernel<<<1, 256, 0, stream>>>(pooled, Wc, bc, d_out, flag);
}